// Round 1
// 641.418 us; speedup vs baseline: 1.0107x; 1.0107x over previous
//
#include <hip/hip_runtime.h>

typedef __attribute__((ext_vector_type(8))) short short8;
typedef __attribute__((ext_vector_type(8))) unsigned short ushort8;
typedef __attribute__((ext_vector_type(4))) float floatx4;

#define NBQ  1024     // max buckets (N <= 131072 @ 128 nodes/bucket; packing needs N <= 2^17)
#define NBLK 128      // sort blocks

__device__ __forceinline__ float bf2f(unsigned short u) {
    union { unsigned u; float f; } v; v.u = ((unsigned)u) << 16; return v.f;
}
__device__ __forceinline__ float bflo(unsigned u) {
    union { unsigned u; float f; } v; v.u = u << 16; return v.f;
}
__device__ __forceinline__ float bfhi(unsigned u) {
    union { unsigned u; float f; } v; v.u = u & 0xFFFF0000u; return v.f;
}
__device__ __forceinline__ unsigned short f2bf(float f) {
    union { float f; unsigned u; } v; v.f = f;
    unsigned r = v.u + 0x7FFFu + ((v.u >> 16) & 1u);
    return (unsigned short)(r >> 16);
}
__device__ __forceinline__ unsigned pack2bf(float a, float b) {
    return (unsigned)f2bf(a) | ((unsigned)f2bf(b) << 16);
}
__device__ __forceinline__ float lrelu(float x, float s) { return x >= 0.f ? x : s * x; }

// fp32 -> bf16 pairs, pre-scaled by dinv[node] (D^-1/2 absorbed into features)
__global__ __launch_bounds__(256) void cast_scale(const float* __restrict__ in, const float* __restrict__ dinv,
                                                  unsigned* __restrict__ outp, int npairs) {
    int i = blockIdx.x * 256 + threadIdx.x;
    if (i < npairs) {
        float s = dinv[i >> 6];
        float2 v = *(const float2*)(in + 2 * (size_t)i);
        outp[i] = pack2bf(v.x * s, v.y * s);
    }
}

// one-shot fp32 -> bf16 cast of 5 weight matrices into one packed buffer
__global__ __launch_bounds__(256) void wcast(const float* __restrict__ w0, const float* __restrict__ w1,
                                             const float* __restrict__ w2, const float* __restrict__ w3,
                                             const float* __restrict__ w4, unsigned* __restrict__ outp,
                                             int c0, int c1, int c2, int c3, int c4) {
    int i = blockIdx.x * 256 + threadIdx.x;
    if (i >= c4) return;
    const float* src; int base;
    if      (i < c0) { src = w0; base = 0;  }
    else if (i < c1) { src = w1; base = c0; }
    else if (i < c2) { src = w2; base = c1; }
    else if (i < c3) { src = w3; base = c2; }
    else             { src = w4; base = c3; }
    float2 v = *(const float2*)(src + 2 * (size_t)(i - base));
    outp[i] = pack2bf(v.x, v.y);
}

// ---- CSR build: two-phase counting sort (bucket = 128 dst nodes), no global atomics ----
__global__ __launch_bounds__(256) void hist_k(const int* __restrict__ dst, int* __restrict__ cnt,
                                              int e, int et, int nb) {
    __shared__ int h[NBQ];
    for (int i = threadIdx.x; i < nb; i += 256) h[i] = 0;
    __syncthreads();
    int chunk = (et + NBLK - 1) / NBLK;
    int c0 = blockIdx.x * chunk;
    int c1 = c0 + chunk < et ? c0 + chunk : et;
    for (int i = c0 + (int)threadIdx.x; i < c1; i += 256) {
        int d = (i < e) ? dst[i] : (i - e);
        atomicAdd(&h[d >> 7], 1);
    }
    __syncthreads();
    for (int i = threadIdx.x; i < nb; i += 256) cnt[blockIdx.x * NBQ + i] = h[i];
}

__global__ __launch_bounds__(256) void btot_k(const int* __restrict__ cnt, int* __restrict__ btot, int nb) {
    int b = blockIdx.x * 256 + threadIdx.x;
    if (b >= nb) return;
    int s = 0;
    for (int blk = 0; blk < NBLK; ++blk) s += cnt[blk * NBQ + b];
    btot[b] = s;
}

__global__ __launch_bounds__(256) void bscan_k(const int* __restrict__ btot, int* __restrict__ bbase,
                                               int nb, int et) {
    __shared__ int sd[256];
    int t = threadIdx.x;
    int i0 = t * 4;
    int loc[4]; int s = 0;
    for (int j = 0; j < 4; ++j) { int i = i0 + j; loc[j] = (i < nb) ? btot[i] : 0; s += loc[j]; }
    sd[t] = s; __syncthreads();
    for (int off = 1; off < 256; off <<= 1) {
        int v = (t >= off) ? sd[t - off] : 0;
        __syncthreads();
        sd[t] += v;
        __syncthreads();
    }
    int run = sd[t] - s;
    for (int j = 0; j < 4; ++j) {
        int i = i0 + j;
        if (i < nb) { bbase[i] = run; run += loc[j]; }
    }
    if (t == 255) bbase[nb] = et;
}

__global__ __launch_bounds__(256) void scan_cnt(int* __restrict__ cnt, const int* __restrict__ bbase,
                                                int nb) {
    int b = blockIdx.x * 256 + threadIdx.x;
    if (b >= nb) return;
    int base = bbase[b];
    for (int blk = 0; blk < NBLK; ++blk) {
        int* p = &cnt[blk * NBQ + b];
        int t = *p; *p = base; base += t;
    }
}

// scatter packed entries: s (17 bits, N <= 131072) | (d&127) << 17 — 4B/edge
__global__ __launch_bounds__(256) void scatter_k(const int* __restrict__ src, const int* __restrict__ dst,
                                                 const int* __restrict__ cnt,
                                                 int* __restrict__ ebuf, int e, int et, int nb) {
    __shared__ int cur[NBQ];
    for (int i = threadIdx.x; i < nb; i += 256) cur[i] = cnt[blockIdx.x * NBQ + i];
    __syncthreads();
    int chunk = (et + NBLK - 1) / NBLK;
    int c0 = blockIdx.x * chunk;
    int c1 = c0 + chunk < et ? c0 + chunk : et;
    for (int i = c0 + (int)threadIdx.x; i < c1; i += 256) {
        int s, d;
        if (i < e) { s = src[i]; d = dst[i]; }
        else       { s = d = i - e; }            // self loop
        int pos = atomicAdd(&cur[d >> 7], 1);
        ebuf[pos] = s | ((d & 127) << 17);
    }
}

// fused: per-bucket degree count + scan -> offsets/dinv, then node-granular CSR
// placement with LDS cursors (ebuf segment stays L2-hot between the two passes)
__global__ __launch_bounds__(256) void finalize_k(const int* __restrict__ ebuf, const int* __restrict__ bbase,
                                                  int* __restrict__ offsets, float* __restrict__ dinv,
                                                  int* __restrict__ csr_s, int n, int et) {
    __shared__ int ldeg[128];
    __shared__ int lscan[128];
    __shared__ int cur[128];
    int b = blockIdx.x;
    int n0 = b << 7;
    if (threadIdx.x < 128) ldeg[threadIdx.x] = 0;
    __syncthreads();
    int e0 = bbase[b], e1 = bbase[b + 1];
    for (int i = e0 + (int)threadIdx.x; i < e1; i += 256)
        atomicAdd(&ldeg[(ebuf[i] >> 17) & 127], 1);
    __syncthreads();
    if (threadIdx.x < 128) lscan[threadIdx.x] = ldeg[threadIdx.x];
    __syncthreads();
    for (int off = 1; off < 128; off <<= 1) {
        int v = 0;
        if (threadIdx.x < 128 && (int)threadIdx.x >= off) v = lscan[threadIdx.x - off];
        __syncthreads();
        if (threadIdx.x < 128) lscan[threadIdx.x] += v;
        __syncthreads();
    }
    if (threadIdx.x < 128) {
        int base = e0 + lscan[threadIdx.x] - ldeg[threadIdx.x];   // exclusive
        cur[threadIdx.x] = base;
        int node = n0 + threadIdx.x;
        if (node < n) {
            offsets[node] = base;
            dinv[node] = rsqrtf((float)ldeg[threadIdx.x]);         // deg >= 1 (self loop)
        }
    }
    if (b == 0 && threadIdx.x == 0) offsets[n] = et;
    __syncthreads();
    for (int i = e0 + (int)threadIdx.x; i < e1; i += 256) {
        int ent = ebuf[i];
        int pos = atomicAdd(&cur[(ent >> 17) & 127], 1);
        csr_s[pos] = ent & 0x1FFFF;
    }
}

// ---------------- propagation: out[d] = scale(d) * sum_{s in N(d)} x[s], 128 bf16 feats ----------------
// Unweighted neighbor sum (P = D^-1/2 A D^-1/2 decomposed); 4 slots x 16 lanes, uint4/lane.
// sq: scale = dinv^2 (first hop, absorbs D^-1); else scale = dinv (second hop, D^-1/2).
// Latency-hiding version: each slot strides its edge list 4-deep so a wave keeps
// 16 gather uint4 loads in flight (old code: 1). Source indices are loaded
// directly (uniform within each 16-lane slot group, consecutive across slots ->
// one coalesced 64B transaction, L1-hot) instead of the ds_bpermute __shfl chain.

#define ACC8(u) { a0 += bflo((u).x); a1 += bfhi((u).x); a2 += bflo((u).y); a3 += bfhi((u).y); \
                  a4 += bflo((u).z); a5 += bfhi((u).z); a6 += bflo((u).w); a7 += bfhi((u).w); }

__global__ __launch_bounds__(256) void prop_kernel(const uint4* __restrict__ xin, const int* __restrict__ offs,
                                                   const int* __restrict__ csr_s, const float* __restrict__ dinv,
                                                   int sq, uint4* __restrict__ out, int n) {
    int node = blockIdx.x * 4 + (threadIdx.x >> 6);
    if (node >= n) return;
    int lane = threadIdx.x & 63;
    int slot = lane >> 4;      // 0..3 (edge phase)
    int li   = lane & 15;      // uint4 index within 16-uint4 row
    int beg = offs[node], end = offs[node + 1];
    float a0=0.f,a1=0.f,a2=0.f,a3=0.f,a4=0.f,a5=0.f,a6=0.f,a7=0.f;
    int i = beg + slot;
    // main: 4 edges per slot per iteration -> 16 rows in flight per wave
    for (; i + 12 < end; i += 16) {
        int s0 = csr_s[i];
        int s1 = csr_s[i + 4];
        int s2 = csr_s[i + 8];
        int s3 = csr_s[i + 12];
        uint4 u0 = xin[(size_t)s0 * 16 + li];
        uint4 u1 = xin[(size_t)s1 * 16 + li];
        uint4 u2 = xin[(size_t)s2 * 16 + li];
        uint4 u3 = xin[(size_t)s3 * 16 + li];
        ACC8(u0); ACC8(u1); ACC8(u2); ACC8(u3);
    }
    // remainder: one edge per slot at a time
    for (; i < end; i += 4) {
        int s = csr_s[i];
        uint4 u = xin[(size_t)s * 16 + li];
        ACC8(u);
    }
    // combine the 4 slot partials (lanes differing in bits 4,5 hold same features)
    a0 += __shfl_xor(a0, 16, 64); a0 += __shfl_xor(a0, 32, 64);
    a1 += __shfl_xor(a1, 16, 64); a1 += __shfl_xor(a1, 32, 64);
    a2 += __shfl_xor(a2, 16, 64); a2 += __shfl_xor(a2, 32, 64);
    a3 += __shfl_xor(a3, 16, 64); a3 += __shfl_xor(a3, 32, 64);
    a4 += __shfl_xor(a4, 16, 64); a4 += __shfl_xor(a4, 32, 64);
    a5 += __shfl_xor(a5, 16, 64); a5 += __shfl_xor(a5, 32, 64);
    a6 += __shfl_xor(a6, 16, 64); a6 += __shfl_xor(a6, 32, 64);
    a7 += __shfl_xor(a7, 16, 64); a7 += __shfl_xor(a7, 32, 64);
    if (slot == 0) {
        float f = dinv[node];
        if (sq) f *= f;
        uint4 o;
        o.x = pack2bf(a0 * f, a1 * f); o.y = pack2bf(a2 * f, a3 * f);
        o.z = pack2bf(a4 * f, a5 * f); o.w = pack2bf(a6 * f, a7 * f);
        out[(size_t)node * 16 + li] = o;
    }
}

// ---------------- MFMA GEMM: C[M,Nc] = act(A[M,K] @ B[K,Nc] + bias) [* oscale] ----------------
// Proven 64x64 tile, blockIdx.y = 64-col B tile. A bf16, B bf16 (pre-cast weights),
// bias fp32, C bf16. K%32==0, Nc%64==0.
// Optional fused per-row dots (attS/attD non-null, requires Nc==64, gridDim.y==1, act=0):
// oas[m] = sum_n C[m][n]*attS[n], oad likewise — replaces the separate gat_dots pass.

__global__ __launch_bounds__(256) void gemm_mfma(const unsigned short* __restrict__ A,
                                                 const unsigned short* __restrict__ Bw,
                                                 const float* __restrict__ bias, unsigned short* __restrict__ C,
                                                 const float* __restrict__ oscale,
                                                 const float* __restrict__ attS, const float* __restrict__ attD,
                                                 float* __restrict__ oas, float* __restrict__ oad,
                                                 int M, int K, int Nc, float slope, int act) {
    __shared__ __align__(16) unsigned short As[64 * 40];
    __shared__ __align__(16) unsigned short Bs[64 * 40];
    const int tid  = threadIdx.x;
    const int wave = tid >> 6;
    const int lane = tid & 63;
    const int q    = lane >> 4;
    const int r16  = lane & 15;
    const int m0 = blockIdx.x * 64;
    const int n0 = blockIdx.y * 64;

    floatx4 acc0 = {0.f,0.f,0.f,0.f}, acc1 = acc0, acc2 = acc0, acc3 = acc0;

    const int am = tid >> 2;         // 0..63 (tile row)
    const int ak = (tid & 3) * 8;    // 0..24
    const int bk = tid >> 3;         // 0..31 (k within step)
    const int bn = (tid & 7) * 8;    // 0..56

    for (int k0 = 0; k0 < K; k0 += 32) {
        // stage A tile [64][32] bf16 (straight 16B copy), row stride 40
        {
            int gm = m0 + am;
            ushort8 sv;
            if (gm < M) {
                sv = *(const ushort8*)(A + (size_t)gm * K + k0 + ak);
            } else {
                for (int j = 0; j < 8; ++j) sv[j] = 0;
            }
            *(ushort8*)(&As[am * 40 + ak]) = sv;
        }
        // stage B tile [32][64] transposed -> Bs[n][k] (bf16 source, straight copy)
        {
            ushort8 bv = *(const ushort8*)(Bw + (size_t)(k0 + bk) * Nc + n0 + bn);
            for (int j = 0; j < 8; ++j) Bs[(bn + j) * 40 + bk] = bv[j];
        }
        __syncthreads();
        short8 bfrag = *(const short8*)(&Bs[(wave * 16 + r16) * 40 + q * 8]);
        short8 a0 = *(const short8*)(&As[(r16) * 40 + q * 8]);
        short8 a1 = *(const short8*)(&As[(16 + r16) * 40 + q * 8]);
        short8 a2 = *(const short8*)(&As[(32 + r16) * 40 + q * 8]);
        short8 a3 = *(const short8*)(&As[(48 + r16) * 40 + q * 8]);
        acc0 = __builtin_amdgcn_mfma_f32_16x16x32_bf16(a0, bfrag, acc0, 0, 0, 0);
        acc1 = __builtin_amdgcn_mfma_f32_16x16x32_bf16(a1, bfrag, acc1, 0, 0, 0);
        acc2 = __builtin_amdgcn_mfma_f32_16x16x32_bf16(a2, bfrag, acc2, 0, 0, 0);
        acc3 = __builtin_amdgcn_mfma_f32_16x16x32_bf16(a3, bfrag, acc3, 0, 0, 0);
        __syncthreads();
    }
    // epilogue: C/D layout col=lane&15, row=(lane>>4)*4+reg
    int cn = n0 + wave * 16 + r16;
    float bv = bias ? bias[cn] : 0.f;
    floatx4 aa[4] = {acc0, acc1, acc2, acc3};
    float ps[16], pd[16];
    float avs = attS ? attS[cn] : 0.f;
    float avd = attS ? attD[cn] : 0.f;
    for (int ms = 0; ms < 4; ++ms)
        for (int rr = 0; rr < 4; ++rr) {
            int cm = m0 + ms * 16 + q * 4 + rr;
            float v = aa[ms][rr] + bv;
            if (act) v = lrelu(v, slope);
            if (oscale && cm < M) v *= oscale[cm];
            if (cm < M) C[(size_t)cm * Nc + cn] = f2bf(v);
            ps[ms * 4 + rr] = v * avs;
            pd[ms * 4 + rr] = v * avd;
        }
    if (attS) {
        // reduce over the 16 cols held by this wave's q-group (lanes aligned 16)
        for (int off = 1; off < 16; off <<= 1)
#pragma unroll
            for (int i = 0; i < 16; ++i) {
                ps[i] += __shfl_xor(ps[i], off, 64);
                pd[i] += __shfl_xor(pd[i], off, 64);
            }
        // cross-wave combine in LDS (reuse As; all LDS reads done before last barrier)
        float* sd = (float*)As;
        if (tid < 128) sd[tid] = 0.f;
        __syncthreads();
        if (r16 == 0) {
#pragma unroll
            for (int i = 0; i < 16; ++i) {
                int row = (i >> 2) * 16 + q * 4 + (i & 3);
                atomicAdd(&sd[row], ps[i]);
                atomicAdd(&sd[64 + row], pd[i]);
            }
        }
        __syncthreads();
        if (tid < 64 && m0 + tid < M) {
            oas[m0 + tid] = sd[tid];
            oad[m0 + tid] = sd[64 + tid];
        }
    }
}

// ---------------- GAT ----------------
// 8 edges in flight per t-step x 2-deep unroll = 16 gather loads in flight/wave.
// No segment-max pass: e = lrelu(a_s+a_d) is O(1..10) << 88, exp(e) fp32-safe; shift cancels.
__global__ __launch_bounds__(256) void gat_agg(const uint4* __restrict__ hg, const float* __restrict__ a_s,
                                               const float* __restrict__ a_d, const int* __restrict__ offs,
                                               const int* __restrict__ csr_s, const float* __restrict__ bg,
                                               uint4* __restrict__ out, int n) {
    int node = blockIdx.x * 4 + (threadIdx.x >> 6);
    if (node >= n) return;
    int lane = threadIdx.x & 63;
    int slot = lane >> 3;      // 0..7
    int li   = lane & 7;       // uint4 index within row
    int beg = offs[node], end = offs[node + 1];
    float ad = a_d[node];
    float a0=0.f,a1=0.f,a2=0.f,a3=0.f,a4=0.f,a5=0.f,a6=0.f,a7=0.f, ssum=0.f;
    for (int base = beg; base < end; base += 64) {
        int cnt = end - base; if (cnt > 64) cnt = 64;
        int sj = 0; float wj = 0.f;
        if (lane < cnt) {
            sj = csr_s[base + lane];
            float e = a_s[sj] + ad;
            e = e < 0.f ? 0.2f * e : e;
            wj = __expf(e);
        }
        for (int t = 0; t < cnt; t += 16) {
            int idx0 = t + slot, idx1 = t + 8 + slot;
            int c0 = idx0 < cnt ? idx0 : 0;
            int c1 = idx1 < cnt ? idx1 : 0;
            int   s0 = __shfl(sj, c0, 64);
            float w0 = __shfl(wj, c0, 64);
            int   s1 = __shfl(sj, c1, 64);
            float w1 = __shfl(wj, c1, 64);
            if (idx0 >= cnt) w0 = 0.f;
            if (idx1 >= cnt) w1 = 0.f;
            uint4 u0 = hg[(size_t)s0 * 8 + li];
            uint4 u1 = hg[(size_t)s1 * 8 + li];
            ssum += w0 + w1;
            a0 = fmaf(w0, bflo(u0.x), a0); a1 = fmaf(w0, bfhi(u0.x), a1);
            a2 = fmaf(w0, bflo(u0.y), a2); a3 = fmaf(w0, bfhi(u0.y), a3);
            a4 = fmaf(w0, bflo(u0.z), a4); a5 = fmaf(w0, bfhi(u0.z), a5);
            a6 = fmaf(w0, bflo(u0.w), a6); a7 = fmaf(w0, bfhi(u0.w), a7);
            a0 = fmaf(w1, bflo(u1.x), a0); a1 = fmaf(w1, bfhi(u1.x), a1);
            a2 = fmaf(w1, bflo(u1.y), a2); a3 = fmaf(w1, bfhi(u1.y), a3);
            a4 = fmaf(w1, bflo(u1.z), a4); a5 = fmaf(w1, bfhi(u1.z), a5);
            a6 = fmaf(w1, bflo(u1.w), a6); a7 = fmaf(w1, bfhi(u1.w), a7);
        }
    }
    for (int off = 8; off <= 32; off <<= 1) {
        a0 += __shfl_xor(a0, off, 64); a1 += __shfl_xor(a1, off, 64);
        a2 += __shfl_xor(a2, off, 64); a3 += __shfl_xor(a3, off, 64);
        a4 += __shfl_xor(a4, off, 64); a5 += __shfl_xor(a5, off, 64);
        a6 += __shfl_xor(a6, off, 64); a7 += __shfl_xor(a7, off, 64);
        ssum += __shfl_xor(ssum, off, 64);
    }
    if (slot == 0) {
        float inv = 1.0f / ssum;
        int f0 = li * 8;
        uint4 o;
        o.x = pack2bf(lrelu(a0 * inv + bg[f0 + 0], 0.1f), lrelu(a1 * inv + bg[f0 + 1], 0.1f));
        o.y = pack2bf(lrelu(a2 * inv + bg[f0 + 2], 0.1f), lrelu(a3 * inv + bg[f0 + 3], 0.1f));
        o.z = pack2bf(lrelu(a4 * inv + bg[f0 + 4], 0.1f), lrelu(a5 * inv + bg[f0 + 5], 0.1f));
        o.w = pack2bf(lrelu(a6 * inv + bg[f0 + 6], 0.1f), lrelu(a7 * inv + bg[f0 + 7], 0.1f));
        out[(size_t)node * 8 + li] = o;
    }
}

// ---------------- final small GEMM [Ng,256]@[256,8] + bias -> fp32 ----------------

__global__ __launch_bounds__(256) void final_gemm(const unsigned short* __restrict__ m2, const float* __restrict__ W3,
                                                  const float* __restrict__ b3,
                                                  float* __restrict__ out, int ng) {
    int idx = blockIdx.x * 256 + threadIdx.x;
    if (idx >= ng * 8) return;
    int r = idx >> 3, c = idx & 7;
    float acc = b3[c];
    const unsigned short* row = m2 + (size_t)r * 256;
    for (int k = 0; k < 256; ++k) acc = fmaf(bf2f(row[k]), W3[k * 8 + c], acc);
    out[idx] = acc;
}

// ---------------- launch ----------------

extern "C" void kernel_launch(void* const* d_in, const int* in_sizes, int n_in,
                              void* d_out, int out_size, void* d_ws, size_t ws_size,
                              hipStream_t stream) {
    const int N  = in_sizes[0] / 128;
    const int E  = in_sizes[1] / 2;
    const int ET = E + N;
    const int Ng = N / 10;
    const int NB = (N + 127) / 128;   // dst buckets (<= NBQ)

    const float* x    = (const float*)d_in[0];
    const int*   src  = (const int*)d_in[1];
    const int*   dst  = src + E;
    const float* W1   = (const float*)d_in[2];
    const float* b1   = (const float*)d_in[3];
    const float* W2   = (const float*)d_in[4];
    const float* b2   = (const float*)d_in[5];
    const float* Wg   = (const float*)d_in[6];
    const float* atts = (const float*)d_in[7];
    const float* attd = (const float*)d_in[8];
    const float* bg   = (const float*)d_in[9];
    const float* Wl1  = (const float*)d_in[10];
    const float* bl1  = (const float*)d_in[11];
    const float* Wl2  = (const float*)d_in[12];
    const float* bl2  = (const float*)d_in[13];
    const float* Wl3  = (const float*)d_in[14];
    const float* bl3  = (const float*)d_in[15];
    float* out = (float*)d_out;

    // bf16 weight buffer segment sizes (pairs)
    const int p1 = in_sizes[2] / 2;    // W1
    const int p2 = in_sizes[4] / 2;    // W2
    const int p3 = in_sizes[6] / 2;    // Wg
    const int p4 = in_sizes[10] / 2;   // Wl1
    const int p5 = in_sizes[12] / 2;   // Wl2
    const int c0 = p1, c1 = c0 + p2, c2 = c1 + p3, c3 = c2 + p4, c4 = c3 + p5;

    // workspace carve (all feature buffers bf16, 16B-aligned rows)
    char* p = (char*)d_ws;
    auto alloc = [&](size_t bytes) { char* r = p; p += (bytes + 255) & ~(size_t)255; return r; };
    unsigned short* xb = (unsigned short*)alloc((size_t)N * 128 * 2);
    unsigned short* A  = (unsigned short*)alloc((size_t)N * 128 * 2);
    unsigned short* Bb = (unsigned short*)alloc((size_t)N * 128 * 2);
    int*   csr_s   = (int*)  alloc((size_t)ET * 4);
    int*   cnt     = (int*)  alloc((size_t)NBLK * NBQ * 4);
    int*   btot    = (int*)  alloc((size_t)(NBQ + 1) * 4);
    int*   bbase   = (int*)  alloc((size_t)(NBQ + 1) * 4);
    float* dinv    = (float*)alloc((size_t)N * 4);
    int*   offsets = (int*)  alloc((size_t)(N + 1) * 4);
    float* a_s     = (float*)alloc((size_t)N * 4);
    float* a_d     = (float*)alloc((size_t)N * 4);
    unsigned short* wb = (unsigned short*)alloc((size_t)c4 * 4);  // packed bf16 weights
    // ebuf (packed src|dlow, ET*4 bytes) aliases Bb; lifetime ends before Bb's first write.
    int*   ebuf    = (int*)Bb;

    const unsigned short* W1b  = wb;
    const unsigned short* W2b  = wb + 2 * (size_t)c0;
    const unsigned short* Wgb  = wb + 2 * (size_t)c1;
    const unsigned short* Wl1b = wb + 2 * (size_t)c2;
    const unsigned short* Wl2b = wb + 2 * (size_t)c3;

    const int pg = (N + 3) / 4;

    hist_k    <<<NBLK, 256, 0, stream>>>(dst, cnt, E, ET, NB);
    btot_k    <<<(NB + 255) / 256, 256, 0, stream>>>(cnt, btot, NB);
    bscan_k   <<<1, 256, 0, stream>>>(btot, bbase, NB, ET);
    scan_cnt  <<<(NB + 255) / 256, 256, 0, stream>>>(cnt, bbase, NB);
    scatter_k <<<NBLK, 256, 0, stream>>>(src, dst, cnt, ebuf, E, ET, NB);
    finalize_k<<<NB, 256, 0, stream>>>(ebuf, bbase, offsets, dinv, csr_s, N, ET);
    wcast     <<<(c4 + 255) / 256, 256, 0, stream>>>(W1, W2, Wg, Wl1, Wl2, (unsigned*)wb, c0, c1, c2, c3, c4);
    cast_scale<<<(N * 64 + 255) / 256, 256, 0, stream>>>(x, dinv, (unsigned*)xb, N * 64);

    // conv1: u = D^-1/2 x (cast) ; A = D^-1 A u ; Bb = D^-1/2 A A' = P^2 x ; h1' = lrelu(...)*dinv
    prop_kernel<<<pg, 256, 0, stream>>>((const uint4*)xb, offsets, csr_s, dinv, 1, (uint4*)A,  N);
    prop_kernel<<<pg, 256, 0, stream>>>((const uint4*)A,  offsets, csr_s, dinv, 0, (uint4*)Bb, N);
    dim3 g1((N + 63) / 64, 2);
    gemm_mfma<<<g1, 256, 0, stream>>>(Bb, W1b, b1, A, dinv, nullptr, nullptr, nullptr, nullptr,
                                      N, 128, 128, 0.1f, 1);
    // conv2 (input already dinv-prescaled by gemm1 epilogue)
    prop_kernel<<<pg, 256, 0, stream>>>((const uint4*)A,  offsets, csr_s, dinv, 1, (uint4*)Bb, N);
    prop_kernel<<<pg, 256, 0, stream>>>((const uint4*)Bb, offsets, csr_s, dinv, 0, (uint4*)A,  N);
    gemm_mfma<<<g1, 256, 0, stream>>>(A, W2b, b2, Bb, nullptr, nullptr, nullptr, nullptr, nullptr,
                                      N, 128, 128, 0.1f, 1);
    // GAT: hg = h2 @ Wg with fused a_s/a_d row-dots, then attention aggregate
    dim3 g2((N + 63) / 64, 1);
    gemm_mfma<<<g2, 256, 0, stream>>>(Bb, Wgb, nullptr, A, nullptr, atts, attd, a_s, a_d,
                                      N, 128, 64, 0.f, 0);
    gat_agg <<<pg, 256, 0, stream>>>((const uint4*)A, a_s, a_d, offsets, csr_s, bg, (uint4*)Bb, N);
    // MLP: Bb viewed as [Ng, 640] bf16
    dim3 g3((Ng + 63) / 64, 8);
    gemm_mfma<<<g3, 256, 0, stream>>>(Bb, Wl1b, bl1, A, nullptr, nullptr, nullptr, nullptr, nullptr,
                                      Ng, 640, 512, 0.1f, 1);
    dim3 g4((Ng + 63) / 64, 4);
    gemm_mfma<<<g4, 256, 0, stream>>>(A, Wl2b, bl2, Bb, nullptr, nullptr, nullptr, nullptr, nullptr,
                                      Ng, 512, 256, 0.1f, 1);
    final_gemm<<<(Ng * 8 + 255) / 256, 256, 0, stream>>>(Bb, Wl3, bl3, out, Ng);
}

// Round 3
// 625.222 us; speedup vs baseline: 1.0369x; 1.0259x over previous
//
#include <hip/hip_runtime.h>

typedef __attribute__((ext_vector_type(8))) short short8;
typedef __attribute__((ext_vector_type(8))) unsigned short ushort8;
typedef __attribute__((ext_vector_type(4))) float floatx4;
typedef __attribute__((ext_vector_type(2))) float floatx2;

#define NBQ  1024     // max buckets (N <= 131072 @ 128 nodes/bucket; packing needs N <= 2^17)
#define NBLK 128      // sort blocks

__device__ __forceinline__ float bf2f(unsigned short u) {
    union { unsigned u; float f; } v; v.u = ((unsigned)u) << 16; return v.f;
}
__device__ __forceinline__ float bflo(unsigned u) {
    union { unsigned u; float f; } v; v.u = u << 16; return v.f;
}
__device__ __forceinline__ float bfhi(unsigned u) {
    union { unsigned u; float f; } v; v.u = u & 0xFFFF0000u; return v.f;
}
__device__ __forceinline__ unsigned short f2bf(float f) {
    union { float f; unsigned u; } v; v.f = f;
    unsigned r = v.u + 0x7FFFu + ((v.u >> 16) & 1u);
    return (unsigned short)(r >> 16);
}
__device__ __forceinline__ unsigned pack2bf(float a, float b) {
    return (unsigned)f2bf(a) | ((unsigned)f2bf(b) << 16);
}
__device__ __forceinline__ float lrelu(float x, float s) { return x >= 0.f ? x : s * x; }

// fp8 e4m3 (OCP) hardware converts. The old/word builtin args must be INTEGER CONSTANT
// EXPRESSIONS -> macros with literals (an inline-function bool param fails to compile).
#define PK_FP8_LO(a, b, old) __builtin_amdgcn_cvt_pk_fp8_f32((a), (b), (old), false)
#define PK_FP8_HI(a, b, old) __builtin_amdgcn_cvt_pk_fp8_f32((a), (b), (old), true)
#define UPK_FP8_LO(u)        __builtin_amdgcn_cvt_pk_f32_fp8((int)(u), false)
#define UPK_FP8_HI(u)        __builtin_amdgcn_cvt_pk_f32_fp8((int)(u), true)

// fp32 -> bf16 pairs, pre-scaled by dinv[node] (D^-1/2 absorbed into features)
__global__ __launch_bounds__(256) void cast_scale(const float* __restrict__ in, const float* __restrict__ dinv,
                                                  unsigned* __restrict__ outp, int npairs) {
    int i = blockIdx.x * 256 + threadIdx.x;
    if (i < npairs) {
        float s = dinv[i >> 6];
        float2 v = *(const float2*)(in + 2 * (size_t)i);
        outp[i] = pack2bf(v.x * s, v.y * s);
    }
}

// fp32 -> fp8 e4m3 quads (4 feats / thread), pre-scaled by dinv[node] (128 feats = 32 uints/node)
__global__ __launch_bounds__(256) void cast_scale8(const float* __restrict__ in, const float* __restrict__ dinv,
                                                   unsigned* __restrict__ outp, int nquads) {
    int i = blockIdx.x * 256 + threadIdx.x;
    if (i < nquads) {
        float s = dinv[i >> 5];
        float4 v = *(const float4*)(in + 4 * (size_t)i);
        int w = PK_FP8_LO(v.x * s, v.y * s, 0);
        w = PK_FP8_HI(v.z * s, v.w * s, w);
        outp[i] = (unsigned)w;
    }
}

// one-shot fp32 -> bf16 cast of 5 weight matrices into one packed buffer
__global__ __launch_bounds__(256) void wcast(const float* __restrict__ w0, const float* __restrict__ w1,
                                             const float* __restrict__ w2, const float* __restrict__ w3,
                                             const float* __restrict__ w4, unsigned* __restrict__ outp,
                                             int c0, int c1, int c2, int c3, int c4) {
    int i = blockIdx.x * 256 + threadIdx.x;
    if (i >= c4) return;
    const float* src; int base;
    if      (i < c0) { src = w0; base = 0;  }
    else if (i < c1) { src = w1; base = c0; }
    else if (i < c2) { src = w2; base = c1; }
    else if (i < c3) { src = w3; base = c2; }
    else             { src = w4; base = c3; }
    float2 v = *(const float2*)(src + 2 * (size_t)(i - base));
    outp[i] = pack2bf(v.x, v.y);
}

// ---- CSR build: two-phase counting sort (bucket = 128 dst nodes), no global atomics ----
__global__ __launch_bounds__(256) void hist_k(const int* __restrict__ dst, int* __restrict__ cnt,
                                              int e, int et, int nb) {
    __shared__ int h[NBQ];
    for (int i = threadIdx.x; i < nb; i += 256) h[i] = 0;
    __syncthreads();
    int chunk = (et + NBLK - 1) / NBLK;
    int c0 = blockIdx.x * chunk;
    int c1 = c0 + chunk < et ? c0 + chunk : et;
    for (int i = c0 + (int)threadIdx.x; i < c1; i += 256) {
        int d = (i < e) ? dst[i] : (i - e);
        atomicAdd(&h[d >> 7], 1);
    }
    __syncthreads();
    for (int i = threadIdx.x; i < nb; i += 256) cnt[blockIdx.x * NBQ + i] = h[i];
}

__global__ __launch_bounds__(256) void btot_k(const int* __restrict__ cnt, int* __restrict__ btot, int nb) {
    int b = blockIdx.x * 256 + threadIdx.x;
    if (b >= nb) return;
    int s = 0;
    for (int blk = 0; blk < NBLK; ++blk) s += cnt[blk * NBQ + b];
    btot[b] = s;
}

__global__ __launch_bounds__(256) void bscan_k(const int* __restrict__ btot, int* __restrict__ bbase,
                                               int nb, int et) {
    __shared__ int sd[256];
    int t = threadIdx.x;
    int i0 = t * 4;
    int loc[4]; int s = 0;
    for (int j = 0; j < 4; ++j) { int i = i0 + j; loc[j] = (i < nb) ? btot[i] : 0; s += loc[j]; }
    sd[t] = s; __syncthreads();
    for (int off = 1; off < 256; off <<= 1) {
        int v = (t >= off) ? sd[t - off] : 0;
        __syncthreads();
        sd[t] += v;
        __syncthreads();
    }
    int run = sd[t] - s;
    for (int j = 0; j < 4; ++j) {
        int i = i0 + j;
        if (i < nb) { bbase[i] = run; run += loc[j]; }
    }
    if (t == 255) bbase[nb] = et;
}

__global__ __launch_bounds__(256) void scan_cnt(int* __restrict__ cnt, const int* __restrict__ bbase,
                                                int nb) {
    int b = blockIdx.x * 256 + threadIdx.x;
    if (b >= nb) return;
    int base = bbase[b];
    for (int blk = 0; blk < NBLK; ++blk) {
        int* p = &cnt[blk * NBQ + b];
        int t = *p; *p = base; base += t;
    }
}

// scatter packed entries: s (17 bits, N <= 131072) | (d&127) << 17 — 4B/edge
__global__ __launch_bounds__(256) void scatter_k(const int* __restrict__ src, const int* __restrict__ dst,
                                                 const int* __restrict__ cnt,
                                                 int* __restrict__ ebuf, int e, int et, int nb) {
    __shared__ int cur[NBQ];
    for (int i = threadIdx.x; i < nb; i += 256) cur[i] = cnt[blockIdx.x * NBQ + i];
    __syncthreads();
    int chunk = (et + NBLK - 1) / NBLK;
    int c0 = blockIdx.x * chunk;
    int c1 = c0 + chunk < et ? c0 + chunk : et;
    for (int i = c0 + (int)threadIdx.x; i < c1; i += 256) {
        int s, d;
        if (i < e) { s = src[i]; d = dst[i]; }
        else       { s = d = i - e; }            // self loop
        int pos = atomicAdd(&cur[d >> 7], 1);
        ebuf[pos] = s | ((d & 127) << 17);
    }
}

// fused: per-bucket degree count + scan -> offsets/dinv, then node-granular CSR
// placement with LDS cursors (ebuf segment stays L2-hot between the two passes)
__global__ __launch_bounds__(256) void finalize_k(const int* __restrict__ ebuf, const int* __restrict__ bbase,
                                                  int* __restrict__ offsets, float* __restrict__ dinv,
                                                  int* __restrict__ csr_s, int n, int et) {
    __shared__ int ldeg[128];
    __shared__ int lscan[128];
    __shared__ int cur[128];
    int b = blockIdx.x;
    int n0 = b << 7;
    if (threadIdx.x < 128) ldeg[threadIdx.x] = 0;
    __syncthreads();
    int e0 = bbase[b], e1 = bbase[b + 1];
    for (int i = e0 + (int)threadIdx.x; i < e1; i += 256)
        atomicAdd(&ldeg[(ebuf[i] >> 17) & 127], 1);
    __syncthreads();
    if (threadIdx.x < 128) lscan[threadIdx.x] = ldeg[threadIdx.x];
    __syncthreads();
    for (int off = 1; off < 128; off <<= 1) {
        int v = 0;
        if (threadIdx.x < 128 && (int)threadIdx.x >= off) v = lscan[threadIdx.x - off];
        __syncthreads();
        if (threadIdx.x < 128) lscan[threadIdx.x] += v;
        __syncthreads();
    }
    if (threadIdx.x < 128) {
        int base = e0 + lscan[threadIdx.x] - ldeg[threadIdx.x];   // exclusive
        cur[threadIdx.x] = base;
        int node = n0 + threadIdx.x;
        if (node < n) {
            offsets[node] = base;
            dinv[node] = rsqrtf((float)ldeg[threadIdx.x]);         // deg >= 1 (self loop)
        }
    }
    if (b == 0 && threadIdx.x == 0) offsets[n] = et;
    __syncthreads();
    for (int i = e0 + (int)threadIdx.x; i < e1; i += 256) {
        int ent = ebuf[i];
        int pos = atomicAdd(&cur[(ent >> 17) & 127], 1);
        csr_s[pos] = ent & 0x1FFFF;
    }
}

// ---------------- propagation (bf16 table): out[d] = scale(d) * sum_{s in N(d)} x[s] ----------------
// 4 slots x 16 lanes, uint4/lane (256B row), 4-deep per slot (16 rows in flight/wave).

#define ACC8(u) { a0 += bflo((u).x); a1 += bfhi((u).x); a2 += bflo((u).y); a3 += bfhi((u).y); \
                  a4 += bflo((u).z); a5 += bfhi((u).z); a6 += bflo((u).w); a7 += bfhi((u).w); }

__global__ __launch_bounds__(256) void prop_kernel(const uint4* __restrict__ xin, const int* __restrict__ offs,
                                                   const int* __restrict__ csr_s, const float* __restrict__ dinv,
                                                   int sq, uint4* __restrict__ out, int n) {
    int node = blockIdx.x * 4 + (threadIdx.x >> 6);
    if (node >= n) return;
    int lane = threadIdx.x & 63;
    int slot = lane >> 4;      // 0..3 (edge phase)
    int li   = lane & 15;      // uint4 index within 16-uint4 row
    int beg = offs[node], end = offs[node + 1];
    float a0=0.f,a1=0.f,a2=0.f,a3=0.f,a4=0.f,a5=0.f,a6=0.f,a7=0.f;
    int i = beg + slot;
    for (; i + 12 < end; i += 16) {
        int s0 = csr_s[i];
        int s1 = csr_s[i + 4];
        int s2 = csr_s[i + 8];
        int s3 = csr_s[i + 12];
        uint4 u0 = xin[(size_t)s0 * 16 + li];
        uint4 u1 = xin[(size_t)s1 * 16 + li];
        uint4 u2 = xin[(size_t)s2 * 16 + li];
        uint4 u3 = xin[(size_t)s3 * 16 + li];
        ACC8(u0); ACC8(u1); ACC8(u2); ACC8(u3);
    }
    for (; i < end; i += 4) {
        int s = csr_s[i];
        uint4 u = xin[(size_t)s * 16 + li];
        ACC8(u);
    }
    a0 += __shfl_xor(a0, 16, 64); a0 += __shfl_xor(a0, 32, 64);
    a1 += __shfl_xor(a1, 16, 64); a1 += __shfl_xor(a1, 32, 64);
    a2 += __shfl_xor(a2, 16, 64); a2 += __shfl_xor(a2, 32, 64);
    a3 += __shfl_xor(a3, 16, 64); a3 += __shfl_xor(a3, 32, 64);
    a4 += __shfl_xor(a4, 16, 64); a4 += __shfl_xor(a4, 32, 64);
    a5 += __shfl_xor(a5, 16, 64); a5 += __shfl_xor(a5, 32, 64);
    a6 += __shfl_xor(a6, 16, 64); a6 += __shfl_xor(a6, 32, 64);
    a7 += __shfl_xor(a7, 16, 64); a7 += __shfl_xor(a7, 32, 64);
    if (slot == 0) {
        float f = dinv[node];
        if (sq) f *= f;
        uint4 o;
        o.x = pack2bf(a0 * f, a1 * f); o.y = pack2bf(a2 * f, a3 * f);
        o.z = pack2bf(a4 * f, a5 * f); o.w = pack2bf(a6 * f, a7 * f);
        out[(size_t)node * 16 + li] = o;
    }
}

// ---------------- propagation (fp8 e4m3 table): rows are 128B = 16 uint2 ----------------
// Same decomposition; f32 accumulate (only storage is quantized). out8f: 1 -> write fp8
// table (for the next hop's gather), 0 -> write bf16 rows (for the MFMA GEMM).

#define ACC8F(u) { floatx2 f0_ = UPK_FP8_LO((u).x), f1_ = UPK_FP8_HI((u).x); \
                   floatx2 f2_ = UPK_FP8_LO((u).y), f3_ = UPK_FP8_HI((u).y); \
                   a0 += f0_.x; a1 += f0_.y; a2 += f1_.x; a3 += f1_.y; \
                   a4 += f2_.x; a5 += f2_.y; a6 += f3_.x; a7 += f3_.y; }

__global__ __launch_bounds__(256) void prop8_kernel(const uint2* __restrict__ xin, const int* __restrict__ offs,
                                                    const int* __restrict__ csr_s, const float* __restrict__ dinv,
                                                    int sq, int out8f, uint2* __restrict__ out8,
                                                    uint4* __restrict__ out16, int n) {
    int node = blockIdx.x * 4 + (threadIdx.x >> 6);
    if (node >= n) return;
    int lane = threadIdx.x & 63;
    int slot = lane >> 4;      // 0..3 (edge phase)
    int li   = lane & 15;      // uint2 index within 16-uint2 (128B) row
    int beg = offs[node], end = offs[node + 1];
    float a0=0.f,a1=0.f,a2=0.f,a3=0.f,a4=0.f,a5=0.f,a6=0.f,a7=0.f;
    int i = beg + slot;
    for (; i + 12 < end; i += 16) {
        int s0 = csr_s[i];
        int s1 = csr_s[i + 4];
        int s2 = csr_s[i + 8];
        int s3 = csr_s[i + 12];
        uint2 u0 = xin[(size_t)s0 * 16 + li];
        uint2 u1 = xin[(size_t)s1 * 16 + li];
        uint2 u2 = xin[(size_t)s2 * 16 + li];
        uint2 u3 = xin[(size_t)s3 * 16 + li];
        ACC8F(u0); ACC8F(u1); ACC8F(u2); ACC8F(u3);
    }
    for (; i < end; i += 4) {
        int s = csr_s[i];
        uint2 u = xin[(size_t)s * 16 + li];
        ACC8F(u);
    }
    a0 += __shfl_xor(a0, 16, 64); a0 += __shfl_xor(a0, 32, 64);
    a1 += __shfl_xor(a1, 16, 64); a1 += __shfl_xor(a1, 32, 64);
    a2 += __shfl_xor(a2, 16, 64); a2 += __shfl_xor(a2, 32, 64);
    a3 += __shfl_xor(a3, 16, 64); a3 += __shfl_xor(a3, 32, 64);
    a4 += __shfl_xor(a4, 16, 64); a4 += __shfl_xor(a4, 32, 64);
    a5 += __shfl_xor(a5, 16, 64); a5 += __shfl_xor(a5, 32, 64);
    a6 += __shfl_xor(a6, 16, 64); a6 += __shfl_xor(a6, 32, 64);
    a7 += __shfl_xor(a7, 16, 64); a7 += __shfl_xor(a7, 32, 64);
    if (slot == 0) {
        float f = dinv[node];
        if (sq) f *= f;
        if (out8f) {
            int w0 = PK_FP8_LO(a0 * f, a1 * f, 0);
            w0 = PK_FP8_HI(a2 * f, a3 * f, w0);
            int w1 = PK_FP8_LO(a4 * f, a5 * f, 0);
            w1 = PK_FP8_HI(a6 * f, a7 * f, w1);
            uint2 o; o.x = (unsigned)w0; o.y = (unsigned)w1;
            out8[(size_t)node * 16 + li] = o;
        } else {
            uint4 o;
            o.x = pack2bf(a0 * f, a1 * f); o.y = pack2bf(a2 * f, a3 * f);
            o.z = pack2bf(a4 * f, a5 * f); o.w = pack2bf(a6 * f, a7 * f);
            out16[(size_t)node * 16 + li] = o;
        }
    }
}

// ---------------- MFMA GEMM: C[M,Nc] = act(A[M,K] @ B[K,Nc] + bias) [* oscale] ----------------
// 64x64 tile, blockIdx.y = 64-col B tile. Software prefetch: next k-tile staged to regs
// after the first barrier, overlapping the frag reads + MFMAs.

__global__ __launch_bounds__(256) void gemm_mfma(const unsigned short* __restrict__ A,
                                                 const unsigned short* __restrict__ Bw,
                                                 const float* __restrict__ bias, unsigned short* __restrict__ C,
                                                 const float* __restrict__ oscale,
                                                 const float* __restrict__ attS, const float* __restrict__ attD,
                                                 float* __restrict__ oas, float* __restrict__ oad,
                                                 int M, int K, int Nc, float slope, int act) {
    __shared__ __align__(16) unsigned short As[64 * 40];
    __shared__ __align__(16) unsigned short Bs[64 * 40];
    const int tid  = threadIdx.x;
    const int wave = tid >> 6;
    const int lane = tid & 63;
    const int q    = lane >> 4;
    const int r16  = lane & 15;
    const int m0 = blockIdx.x * 64;
    const int n0 = blockIdx.y * 64;

    floatx4 acc0 = {0.f,0.f,0.f,0.f}, acc1 = acc0, acc2 = acc0, acc3 = acc0;

    const int am = tid >> 2;         // 0..63 (tile row)
    const int ak = (tid & 3) * 8;    // 0..24
    const int bk = tid >> 3;         // 0..31 (k within step)
    const int bn = (tid & 7) * 8;    // 0..56
    const int gm = m0 + am;

    ushort8 sva, svb;
    if (gm < M) sva = *(const ushort8*)(A + (size_t)gm * K + ak);
    else        for (int j = 0; j < 8; ++j) sva[j] = 0;
    svb = *(const ushort8*)(Bw + (size_t)bk * Nc + n0 + bn);

    for (int k0 = 0; k0 < K; k0 += 32) {
        *(ushort8*)(&As[am * 40 + ak]) = sva;
        for (int j = 0; j < 8; ++j) Bs[(bn + j) * 40 + bk] = svb[j];
        __syncthreads();
        if (k0 + 32 < K) {
            if (gm < M) sva = *(const ushort8*)(A + (size_t)gm * K + k0 + 32 + ak);
            svb = *(const ushort8*)(Bw + (size_t)(k0 + 32 + bk) * Nc + n0 + bn);
        }
        short8 bfrag = *(const short8*)(&Bs[(wave * 16 + r16) * 40 + q * 8]);
        short8 a0 = *(const short8*)(&As[(r16) * 40 + q * 8]);
        short8 a1 = *(const short8*)(&As[(16 + r16) * 40 + q * 8]);
        short8 a2 = *(const short8*)(&As[(32 + r16) * 40 + q * 8]);
        short8 a3 = *(const short8*)(&As[(48 + r16) * 40 + q * 8]);
        acc0 = __builtin_amdgcn_mfma_f32_16x16x32_bf16(a0, bfrag, acc0, 0, 0, 0);
        acc1 = __builtin_amdgcn_mfma_f32_16x16x32_bf16(a1, bfrag, acc1, 0, 0, 0);
        acc2 = __builtin_amdgcn_mfma_f32_16x16x32_bf16(a2, bfrag, acc2, 0, 0, 0);
        acc3 = __builtin_amdgcn_mfma_f32_16x16x32_bf16(a3, bfrag, acc3, 0, 0, 0);
        __syncthreads();
    }
    // epilogue: C/D layout col=lane&15, row=(lane>>4)*4+reg
    int cn = n0 + wave * 16 + r16;
    float bv = bias ? bias[cn] : 0.f;
    floatx4 aa[4] = {acc0, acc1, acc2, acc3};
    float ps[16], pd[16];
    float avs = attS ? attS[cn] : 0.f;
    float avd = attS ? attD[cn] : 0.f;
    for (int ms = 0; ms < 4; ++ms)
        for (int rr = 0; rr < 4; ++rr) {
            int cm = m0 + ms * 16 + q * 4 + rr;
            float v = aa[ms][rr] + bv;
            if (act) v = lrelu(v, slope);
            if (oscale && cm < M) v *= oscale[cm];
            if (cm < M) C[(size_t)cm * Nc + cn] = f2bf(v);
            ps[ms * 4 + rr] = v * avs;
            pd[ms * 4 + rr] = v * avd;
        }
    if (attS) {
        // reduce over the 16 cols held by this wave's q-group (lanes aligned 16)
        for (int off = 1; off < 16; off <<= 1)
#pragma unroll
            for (int i = 0; i < 16; ++i) {
                ps[i] += __shfl_xor(ps[i], off, 64);
                pd[i] += __shfl_xor(pd[i], off, 64);
            }
        // cross-wave combine in LDS (reuse As; all LDS reads done before last barrier)
        float* sd = (float*)As;
        if (tid < 128) sd[tid] = 0.f;
        __syncthreads();
        if (r16 == 0) {
#pragma unroll
            for (int i = 0; i < 16; ++i) {
                int row = (i >> 2) * 16 + q * 4 + (i & 3);
                atomicAdd(&sd[row], ps[i]);
                atomicAdd(&sd[64 + row], pd[i]);
            }
        }
        __syncthreads();
        if (tid < 64 && m0 + tid < M) {
            oas[m0 + tid] = sd[tid];
            oad[m0 + tid] = sd[64 + tid];
        }
    }
}

// ---------------- GAT ----------------
// 8 edges in flight per t-step x 2-deep unroll = 16 gather loads in flight/wave.
// No segment-max pass: e = lrelu(a_s+a_d) is O(1..10) << 88, exp(e) fp32-safe; shift cancels.
__global__ __launch_bounds__(256) void gat_agg(const uint4* __restrict__ hg, const float* __restrict__ a_s,
                                               const float* __restrict__ a_d, const int* __restrict__ offs,
                                               const int* __restrict__ csr_s, const float* __restrict__ bg,
                                               uint4* __restrict__ out, int n) {
    int node = blockIdx.x * 4 + (threadIdx.x >> 6);
    if (node >= n) return;
    int lane = threadIdx.x & 63;
    int slot = lane >> 3;      // 0..7
    int li   = lane & 7;       // uint4 index within row
    int beg = offs[node], end = offs[node + 1];
    float ad = a_d[node];
    float a0=0.f,a1=0.f,a2=0.f,a3=0.f,a4=0.f,a5=0.f,a6=0.f,a7=0.f, ssum=0.f;
    for (int base = beg; base < end; base += 64) {
        int cnt = end - base; if (cnt > 64) cnt = 64;
        int sj = 0; float wj = 0.f;
        if (lane < cnt) {
            sj = csr_s[base + lane];
            float e = a_s[sj] + ad;
            e = e < 0.f ? 0.2f * e : e;
            wj = __expf(e);
        }
        for (int t = 0; t < cnt; t += 16) {
            int idx0 = t + slot, idx1 = t + 8 + slot;
            int c0 = idx0 < cnt ? idx0 : 0;
            int c1 = idx1 < cnt ? idx1 : 0;
            int   s0 = __shfl(sj, c0, 64);
            float w0 = __shfl(wj, c0, 64);
            int   s1 = __shfl(sj, c1, 64);
            float w1 = __shfl(wj, c1, 64);
            if (idx0 >= cnt) w0 = 0.f;
            if (idx1 >= cnt) w1 = 0.f;
            uint4 u0 = hg[(size_t)s0 * 8 + li];
            uint4 u1 = hg[(size_t)s1 * 8 + li];
            ssum += w0 + w1;
            a0 = fmaf(w0, bflo(u0.x), a0); a1 = fmaf(w0, bfhi(u0.x), a1);
            a2 = fmaf(w0, bflo(u0.y), a2); a3 = fmaf(w0, bfhi(u0.y), a3);
            a4 = fmaf(w0, bflo(u0.z), a4); a5 = fmaf(w0, bfhi(u0.z), a5);
            a6 = fmaf(w0, bflo(u0.w), a6); a7 = fmaf(w0, bfhi(u0.w), a7);
            a0 = fmaf(w1, bflo(u1.x), a0); a1 = fmaf(w1, bfhi(u1.x), a1);
            a2 = fmaf(w1, bflo(u1.y), a2); a3 = fmaf(w1, bfhi(u1.y), a3);
            a4 = fmaf(w1, bflo(u1.z), a4); a5 = fmaf(w1, bfhi(u1.z), a5);
            a6 = fmaf(w1, bflo(u1.w), a6); a7 = fmaf(w1, bfhi(u1.w), a7);
        }
    }
    for (int off = 8; off <= 32; off <<= 1) {
        a0 += __shfl_xor(a0, off, 64); a1 += __shfl_xor(a1, off, 64);
        a2 += __shfl_xor(a2, off, 64); a3 += __shfl_xor(a3, off, 64);
        a4 += __shfl_xor(a4, off, 64); a5 += __shfl_xor(a5, off, 64);
        a6 += __shfl_xor(a6, off, 64); a7 += __shfl_xor(a7, off, 64);
        ssum += __shfl_xor(ssum, off, 64);
    }
    if (slot == 0) {
        float inv = 1.0f / ssum;
        int f0 = li * 8;
        uint4 o;
        o.x = pack2bf(lrelu(a0 * inv + bg[f0 + 0], 0.1f), lrelu(a1 * inv + bg[f0 + 1], 0.1f));
        o.y = pack2bf(lrelu(a2 * inv + bg[f0 + 2], 0.1f), lrelu(a3 * inv + bg[f0 + 3], 0.1f));
        o.z = pack2bf(lrelu(a4 * inv + bg[f0 + 4], 0.1f), lrelu(a5 * inv + bg[f0 + 5], 0.1f));
        o.w = pack2bf(lrelu(a6 * inv + bg[f0 + 6], 0.1f), lrelu(a7 * inv + bg[f0 + 7], 0.1f));
        out[(size_t)node * 8 + li] = o;
    }
}

// ---------------- final small GEMM [Ng,256]@[256,8] + bias -> fp32 ----------------

__global__ __launch_bounds__(256) void final_gemm(const unsigned short* __restrict__ m2, const float* __restrict__ W3,
                                                  const float* __restrict__ b3,
                                                  float* __restrict__ out, int ng) {
    int idx = blockIdx.x * 256 + threadIdx.x;
    if (idx >= ng * 8) return;
    int r = idx >> 3, c = idx & 7;
    float acc = b3[c];
    const unsigned short* row = m2 + (size_t)r * 256;
    for (int k = 0; k < 256; ++k) acc = fmaf(bf2f(row[k]), W3[k * 8 + c], acc);
    out[idx] = acc;
}

// ---------------- launch ----------------

extern "C" void kernel_launch(void* const* d_in, const int* in_sizes, int n_in,
                              void* d_out, int out_size, void* d_ws, size_t ws_size,
                              hipStream_t stream) {
    const int N  = in_sizes[0] / 128;
    const int E  = in_sizes[1] / 2;
    const int ET = E + N;
    const int Ng = N / 10;
    const int NB = (N + 127) / 128;   // dst buckets (<= NBQ)

    const float* x    = (const float*)d_in[0];
    const int*   src  = (const int*)d_in[1];
    const int*   dst  = src + E;
    const float* W1   = (const float*)d_in[2];
    const float* b1   = (const float*)d_in[3];
    const float* W2   = (const float*)d_in[4];
    const float* b2   = (const float*)d_in[5];
    const float* Wg   = (const float*)d_in[6];
    const float* atts = (const float*)d_in[7];
    const float* attd = (const float*)d_in[8];
    const float* bg   = (const float*)d_in[9];
    const float* Wl1  = (const float*)d_in[10];
    const float* bl1  = (const float*)d_in[11];
    const float* Wl2  = (const float*)d_in[12];
    const float* bl2  = (const float*)d_in[13];
    const float* Wl3  = (const float*)d_in[14];
    const float* bl3  = (const float*)d_in[15];
    float* out = (float*)d_out;

    // bf16 weight buffer segment sizes (pairs)
    const int p1 = in_sizes[2] / 2;    // W1
    const int p2 = in_sizes[4] / 2;    // W2
    const int p3 = in_sizes[6] / 2;    // Wg
    const int p4 = in_sizes[10] / 2;   // Wl1
    const int p5 = in_sizes[12] / 2;   // Wl2
    const int c0 = p1, c1 = c0 + p2, c2 = c1 + p3, c3 = c2 + p4, c4 = c3 + p5;

    // workspace carve (all feature buffers bf16, 16B-aligned rows)
    char* p = (char*)d_ws;
    auto alloc = [&](size_t bytes) { char* r = p; p += (bytes + 255) & ~(size_t)255; return r; };
    unsigned short* xb = (unsigned short*)alloc((size_t)N * 128 * 2);
    unsigned short* A  = (unsigned short*)alloc((size_t)N * 128 * 2);
    unsigned short* Bb = (unsigned short*)alloc((size_t)N * 128 * 2);
    int*   csr_s   = (int*)  alloc((size_t)ET * 4);
    int*   cnt     = (int*)  alloc((size_t)NBLK * NBQ * 4);
    int*   btot    = (int*)  alloc((size_t)(NBQ + 1) * 4);
    int*   bbase   = (int*)  alloc((size_t)(NBQ + 1) * 4);
    float* dinv    = (float*)alloc((size_t)N * 4);
    int*   offsets = (int*)  alloc((size_t)(N + 1) * 4);
    float* a_s     = (float*)alloc((size_t)N * 4);
    float* a_d     = (float*)alloc((size_t)N * 4);
    unsigned short* wb = (unsigned short*)alloc((size_t)c4 * 4);  // packed bf16 weights
    // ebuf (packed src|dlow, ET*4 bytes) aliases Bb; lifetime ends before Bb's first write.
    int*   ebuf    = (int*)Bb;
    // fp8 tables for conv1 both live inside xb (each N*128 bytes = half of xb)
    unsigned* x8 = (unsigned*)xb;                       // quantized input features
    uint2*    a8 = (uint2*)(xb + (size_t)N * 64);       // hop-1 output, fp8

    const unsigned short* W1b  = wb;
    const unsigned short* W2b  = wb + 2 * (size_t)c0;
    const unsigned short* Wgb  = wb + 2 * (size_t)c1;
    const unsigned short* Wl1b = wb + 2 * (size_t)c2;
    const unsigned short* Wl2b = wb + 2 * (size_t)c3;

    const int pg = (N + 3) / 4;

    hist_k    <<<NBLK, 256, 0, stream>>>(dst, cnt, E, ET, NB);
    btot_k    <<<(NB + 255) / 256, 256, 0, stream>>>(cnt, btot, NB);
    bscan_k   <<<1, 256, 0, stream>>>(btot, bbase, NB, ET);
    scan_cnt  <<<(NB + 255) / 256, 256, 0, stream>>>(cnt, bbase, NB);
    scatter_k <<<NBLK, 256, 0, stream>>>(src, dst, cnt, ebuf, E, ET, NB);
    finalize_k<<<NB, 256, 0, stream>>>(ebuf, bbase, offsets, dinv, csr_s, N, ET);
    wcast     <<<(c4 + 255) / 256, 256, 0, stream>>>(W1, W2, Wg, Wl1, Wl2, (unsigned*)wb, c0, c1, c2, c3, c4);
    cast_scale8<<<(N * 32 + 255) / 256, 256, 0, stream>>>(x, dinv, x8, N * 32);

    // conv1 (fp8 gather table): u = D^-1/2 x (quantized) ; a8 = D^-1 A u (fp8) ;
    // Bb = D^-1/2 A a8 = P^2 x (bf16) ; h1' = lrelu(Bb@W1+b1)*dinv
    prop8_kernel<<<pg, 256, 0, stream>>>((const uint2*)x8, offsets, csr_s, dinv, 1, 1, a8, nullptr, N);
    prop8_kernel<<<pg, 256, 0, stream>>>(a8, offsets, csr_s, dinv, 0, 0, nullptr, (uint4*)Bb, N);
    dim3 g1((N + 63) / 64, 2);
    gemm_mfma<<<g1, 256, 0, stream>>>(Bb, W1b, b1, A, dinv, nullptr, nullptr, nullptr, nullptr,
                                      N, 128, 128, 0.1f, 1);
    // conv2 (bf16 gather table, control passes; input already dinv-prescaled by gemm1 epilogue)
    prop_kernel<<<pg, 256, 0, stream>>>((const uint4*)A,  offsets, csr_s, dinv, 1, (uint4*)Bb, N);
    prop_kernel<<<pg, 256, 0, stream>>>((const uint4*)Bb, offsets, csr_s, dinv, 0, (uint4*)A,  N);
    gemm_mfma<<<g1, 256, 0, stream>>>(A, W2b, b2, Bb, nullptr, nullptr, nullptr, nullptr, nullptr,
                                      N, 128, 128, 0.1f, 1);
    // GAT: hg = h2 @ Wg with fused a_s/a_d row-dots, then attention aggregate
    dim3 g2((N + 63) / 64, 1);
    gemm_mfma<<<g2, 256, 0, stream>>>(Bb, Wgb, nullptr, A, nullptr, atts, attd, a_s, a_d,
                                      N, 128, 64, 0.f, 0);
    gat_agg <<<pg, 256, 0, stream>>>((const uint4*)A, a_s, a_d, offsets, csr_s, bg, (uint4*)Bb, N);
    // MLP: Bb viewed as [Ng, 640] bf16
    dim3 g3((Ng + 63) / 64, 8);
    gemm_mfma<<<g3, 256, 0, stream>>>(Bb, Wl1b, bl1, A, nullptr, nullptr, nullptr, nullptr, nullptr,
                                      Ng, 640, 512, 0.1f, 1);
    dim3 g4((Ng + 63) / 64, 4);
    gemm_mfma<<<g4, 256, 0, stream>>>(A, Wl2b, bl2, Bb, nullptr, nullptr, nullptr, nullptr, nullptr,
                                      Ng, 512, 256, 0.1f, 1);
    final_gemm<<<(Ng * 8 + 255) / 256, 256, 0, stream>>>(Bb, Wl3, bl3, out, Ng);
}

// Round 4
// 607.018 us; speedup vs baseline: 1.0680x; 1.0300x over previous
//
#include <hip/hip_runtime.h>

typedef __attribute__((ext_vector_type(8))) short short8;
typedef __attribute__((ext_vector_type(8))) unsigned short ushort8;
typedef __attribute__((ext_vector_type(4))) float floatx4;
typedef __attribute__((ext_vector_type(2))) float floatx2;

#define NBQ  1024     // max buckets (N <= 131072 @ 128 nodes/bucket; packing needs N <= 2^17)
#define NBLK 128      // sort blocks

__device__ __forceinline__ float bf2f(unsigned short u) {
    union { unsigned u; float f; } v; v.u = ((unsigned)u) << 16; return v.f;
}
__device__ __forceinline__ float bflo(unsigned u) {
    union { unsigned u; float f; } v; v.u = u << 16; return v.f;
}
__device__ __forceinline__ float bfhi(unsigned u) {
    union { unsigned u; float f; } v; v.u = u & 0xFFFF0000u; return v.f;
}
__device__ __forceinline__ unsigned short f2bf(float f) {
    union { float f; unsigned u; } v; v.f = f;
    unsigned r = v.u + 0x7FFFu + ((v.u >> 16) & 1u);
    return (unsigned short)(r >> 16);
}
__device__ __forceinline__ unsigned pack2bf(float a, float b) {
    return (unsigned)f2bf(a) | ((unsigned)f2bf(b) << 16);
}
__device__ __forceinline__ float lrelu(float x, float s) { return x >= 0.f ? x : s * x; }

// fp8 e4m3 (OCP) hardware converts. The old/word builtin args must be INTEGER CONSTANT
// EXPRESSIONS -> macros with literals (an inline-function bool param fails to compile).
#define PK_FP8_LO(a, b, old) __builtin_amdgcn_cvt_pk_fp8_f32((a), (b), (old), false)
#define PK_FP8_HI(a, b, old) __builtin_amdgcn_cvt_pk_fp8_f32((a), (b), (old), true)
#define UPK_FP8_LO(u)        __builtin_amdgcn_cvt_pk_f32_fp8((int)(u), false)
#define UPK_FP8_HI(u)        __builtin_amdgcn_cvt_pk_f32_fp8((int)(u), true)

// fp32 -> fp8 e4m3 quads (4 feats / thread), pre-scaled by dinv[node] (128 feats = 32 uints/node)
__global__ __launch_bounds__(256) void cast_scale8(const float* __restrict__ in, const float* __restrict__ dinv,
                                                   unsigned* __restrict__ outp, int nquads) {
    int i = blockIdx.x * 256 + threadIdx.x;
    if (i < nquads) {
        float s = dinv[i >> 5];
        float4 v = *(const float4*)(in + 4 * (size_t)i);
        int w = PK_FP8_LO(v.x * s, v.y * s, 0);
        w = PK_FP8_HI(v.z * s, v.w * s, w);
        outp[i] = (unsigned)w;
    }
}

// bf16 -> fp8 e4m3 (4 feats / thread); converts h1' into a gather-friendly 128B-row table
__global__ __launch_bounds__(256) void cast_bf2fp8(const uint2* __restrict__ in, unsigned* __restrict__ outp,
                                                   int nquads) {
    int i = blockIdx.x * 256 + threadIdx.x;
    if (i < nquads) {
        uint2 v = in[i];
        int w = PK_FP8_LO(bflo(v.x), bfhi(v.x), 0);
        w = PK_FP8_HI(bflo(v.y), bfhi(v.y), w);
        outp[i] = (unsigned)w;
    }
}

// one-shot fp32 -> bf16 cast of 5 weight matrices into one packed buffer
__global__ __launch_bounds__(256) void wcast(const float* __restrict__ w0, const float* __restrict__ w1,
                                             const float* __restrict__ w2, const float* __restrict__ w3,
                                             const float* __restrict__ w4, unsigned* __restrict__ outp,
                                             int c0, int c1, int c2, int c3, int c4) {
    int i = blockIdx.x * 256 + threadIdx.x;
    if (i >= c4) return;
    const float* src; int base;
    if      (i < c0) { src = w0; base = 0;  }
    else if (i < c1) { src = w1; base = c0; }
    else if (i < c2) { src = w2; base = c1; }
    else if (i < c3) { src = w3; base = c2; }
    else             { src = w4; base = c3; }
    float2 v = *(const float2*)(src + 2 * (size_t)(i - base));
    outp[i] = pack2bf(v.x, v.y);
}

// ---- CSR build: two-phase counting sort (bucket = 128 dst nodes), no global atomics ----
__global__ __launch_bounds__(256) void hist_k(const int* __restrict__ dst, int* __restrict__ cnt,
                                              int e, int et, int nb) {
    __shared__ int h[NBQ];
    for (int i = threadIdx.x; i < nb; i += 256) h[i] = 0;
    __syncthreads();
    int chunk = (et + NBLK - 1) / NBLK;
    int c0 = blockIdx.x * chunk;
    int c1 = c0 + chunk < et ? c0 + chunk : et;
    for (int i = c0 + (int)threadIdx.x; i < c1; i += 256) {
        int d = (i < e) ? dst[i] : (i - e);
        atomicAdd(&h[d >> 7], 1);
    }
    __syncthreads();
    for (int i = threadIdx.x; i < nb; i += 256) cnt[blockIdx.x * NBQ + i] = h[i];
}

__global__ __launch_bounds__(256) void btot_k(const int* __restrict__ cnt, int* __restrict__ btot, int nb) {
    int b = blockIdx.x * 256 + threadIdx.x;
    if (b >= nb) return;
    int s = 0;
    for (int blk = 0; blk < NBLK; ++blk) s += cnt[blk * NBQ + b];
    btot[b] = s;
}

__global__ __launch_bounds__(256) void bscan_k(const int* __restrict__ btot, int* __restrict__ bbase,
                                               int nb, int et) {
    __shared__ int sd[256];
    int t = threadIdx.x;
    int i0 = t * 4;
    int loc[4]; int s = 0;
    for (int j = 0; j < 4; ++j) { int i = i0 + j; loc[j] = (i < nb) ? btot[i] : 0; s += loc[j]; }
    sd[t] = s; __syncthreads();
    for (int off = 1; off < 256; off <<= 1) {
        int v = (t >= off) ? sd[t - off] : 0;
        __syncthreads();
        sd[t] += v;
        __syncthreads();
    }
    int run = sd[t] - s;
    for (int j = 0; j < 4; ++j) {
        int i = i0 + j;
        if (i < nb) { bbase[i] = run; run += loc[j]; }
    }
    if (t == 255) bbase[nb] = et;
}

__global__ __launch_bounds__(256) void scan_cnt(int* __restrict__ cnt, const int* __restrict__ bbase,
                                                int nb) {
    int b = blockIdx.x * 256 + threadIdx.x;
    if (b >= nb) return;
    int base = bbase[b];
    for (int blk = 0; blk < NBLK; ++blk) {
        int* p = &cnt[blk * NBQ + b];
        int t = *p; *p = base; base += t;
    }
}

// scatter packed entries: s (17 bits, N <= 131072) | (d&127) << 17 — 4B/edge
__global__ __launch_bounds__(256) void scatter_k(const int* __restrict__ src, const int* __restrict__ dst,
                                                 const int* __restrict__ cnt,
                                                 int* __restrict__ ebuf, int e, int et, int nb) {
    __shared__ int cur[NBQ];
    for (int i = threadIdx.x; i < nb; i += 256) cur[i] = cnt[blockIdx.x * NBQ + i];
    __syncthreads();
    int chunk = (et + NBLK - 1) / NBLK;
    int c0 = blockIdx.x * chunk;
    int c1 = c0 + chunk < et ? c0 + chunk : et;
    for (int i = c0 + (int)threadIdx.x; i < c1; i += 256) {
        int s, d;
        if (i < e) { s = src[i]; d = dst[i]; }
        else       { s = d = i - e; }            // self loop
        int pos = atomicAdd(&cur[d >> 7], 1);
        ebuf[pos] = s | ((d & 127) << 17);
    }
}

// fused: per-bucket degree count + scan -> offsets/dinv, then node-granular CSR
// placement with LDS cursors (ebuf segment stays L2-hot between the two passes)
__global__ __launch_bounds__(256) void finalize_k(const int* __restrict__ ebuf, const int* __restrict__ bbase,
                                                  int* __restrict__ offsets, float* __restrict__ dinv,
                                                  int* __restrict__ csr_s, int n, int et) {
    __shared__ int ldeg[128];
    __shared__ int lscan[128];
    __shared__ int cur[128];
    int b = blockIdx.x;
    int n0 = b << 7;
    if (threadIdx.x < 128) ldeg[threadIdx.x] = 0;
    __syncthreads();
    int e0 = bbase[b], e1 = bbase[b + 1];
    for (int i = e0 + (int)threadIdx.x; i < e1; i += 256)
        atomicAdd(&ldeg[(ebuf[i] >> 17) & 127], 1);
    __syncthreads();
    if (threadIdx.x < 128) lscan[threadIdx.x] = ldeg[threadIdx.x];
    __syncthreads();
    for (int off = 1; off < 128; off <<= 1) {
        int v = 0;
        if (threadIdx.x < 128 && (int)threadIdx.x >= off) v = lscan[threadIdx.x - off];
        __syncthreads();
        if (threadIdx.x < 128) lscan[threadIdx.x] += v;
        __syncthreads();
    }
    if (threadIdx.x < 128) {
        int base = e0 + lscan[threadIdx.x] - ldeg[threadIdx.x];   // exclusive
        cur[threadIdx.x] = base;
        int node = n0 + threadIdx.x;
        if (node < n) {
            offsets[node] = base;
            dinv[node] = rsqrtf((float)ldeg[threadIdx.x]);         // deg >= 1 (self loop)
        }
    }
    if (b == 0 && threadIdx.x == 0) offsets[n] = et;
    __syncthreads();
    for (int i = e0 + (int)threadIdx.x; i < e1; i += 256) {
        int ent = ebuf[i];
        int pos = atomicAdd(&cur[(ent >> 17) & 127], 1);
        csr_s[pos] = ent & 0x1FFFF;
    }
}

// ---------------- propagation (fp8 e4m3 table, 128B rows = 8 x uint4) ----------------
// out[d] = scale(d) * sum_{s in N(d)} x[s]; f32 accumulate (only storage is quantized).
// Request-rate-optimized: 8 slots x 8 lanes, dwordx4/lane -> 8 lane-requests per edge
// (vs 16 for the bf16/uint2 layouts). 2-deep per slot = 16 gathers in flight / wave.
// out8f: 1 -> write fp8 table (next hop's gather), 0 -> write bf16 rows (MFMA GEMM input).

#define ACC16F(u) { floatx2 t0_ = UPK_FP8_LO((u).x), t1_ = UPK_FP8_HI((u).x); \
                    a[0] += t0_.x; a[1] += t0_.y; a[2] += t1_.x; a[3] += t1_.y; \
                    t0_ = UPK_FP8_LO((u).y); t1_ = UPK_FP8_HI((u).y); \
                    a[4] += t0_.x; a[5] += t0_.y; a[6] += t1_.x; a[7] += t1_.y; \
                    t0_ = UPK_FP8_LO((u).z); t1_ = UPK_FP8_HI((u).z); \
                    a[8] += t0_.x; a[9] += t0_.y; a[10] += t1_.x; a[11] += t1_.y; \
                    t0_ = UPK_FP8_LO((u).w); t1_ = UPK_FP8_HI((u).w); \
                    a[12] += t0_.x; a[13] += t0_.y; a[14] += t1_.x; a[15] += t1_.y; }

__global__ __launch_bounds__(256) void prop8_kernel(const uint4* __restrict__ xin, const int* __restrict__ offs,
                                                    const int* __restrict__ csr_s, const float* __restrict__ dinv,
                                                    int sq, int out8f, uint4* __restrict__ out8,
                                                    uint4* __restrict__ out16, int n) {
    int node = blockIdx.x * 4 + (threadIdx.x >> 6);
    if (node >= n) return;
    int lane = threadIdx.x & 63;
    int slot = lane >> 3;      // 0..7 (edge phase)
    int li   = lane & 7;       // uint4 index within 8-uint4 (128B) fp8 row; feats li*16..+15
    int beg = offs[node], end = offs[node + 1];
    float a[16];
#pragma unroll
    for (int j = 0; j < 16; ++j) a[j] = 0.f;
    int i = beg + slot;
    for (; i + 8 < end; i += 16) {
        int s0 = csr_s[i];
        int s1 = csr_s[i + 8];
        uint4 u0 = xin[(size_t)s0 * 8 + li];
        uint4 u1 = xin[(size_t)s1 * 8 + li];
        ACC16F(u0); ACC16F(u1);
    }
    for (; i < end; i += 8) {
        int s = csr_s[i];
        uint4 u = xin[(size_t)s * 8 + li];
        ACC16F(u);
    }
    // combine the 8 slot partials (lanes differing in bits 3,4,5 hold the same features)
#pragma unroll
    for (int j = 0; j < 16; ++j) {
        a[j] += __shfl_xor(a[j], 8, 64);
        a[j] += __shfl_xor(a[j], 16, 64);
        a[j] += __shfl_xor(a[j], 32, 64);
    }
    if (slot == 0) {
        float f = dinv[node];
        if (sq) f *= f;
        if (out8f) {
            int w0 = PK_FP8_LO(a[0] * f, a[1] * f, 0);  w0 = PK_FP8_HI(a[2] * f, a[3] * f, w0);
            int w1 = PK_FP8_LO(a[4] * f, a[5] * f, 0);  w1 = PK_FP8_HI(a[6] * f, a[7] * f, w1);
            int w2 = PK_FP8_LO(a[8] * f, a[9] * f, 0);  w2 = PK_FP8_HI(a[10] * f, a[11] * f, w2);
            int w3 = PK_FP8_LO(a[12] * f, a[13] * f, 0); w3 = PK_FP8_HI(a[14] * f, a[15] * f, w3);
            uint4 o; o.x = (unsigned)w0; o.y = (unsigned)w1; o.z = (unsigned)w2; o.w = (unsigned)w3;
            out8[(size_t)node * 8 + li] = o;
        } else {
            uint4 o1, o2;
            o1.x = pack2bf(a[0] * f, a[1] * f);   o1.y = pack2bf(a[2] * f, a[3] * f);
            o1.z = pack2bf(a[4] * f, a[5] * f);   o1.w = pack2bf(a[6] * f, a[7] * f);
            o2.x = pack2bf(a[8] * f, a[9] * f);   o2.y = pack2bf(a[10] * f, a[11] * f);
            o2.z = pack2bf(a[12] * f, a[13] * f); o2.w = pack2bf(a[14] * f, a[15] * f);
            out16[(size_t)node * 16 + li * 2]     = o1;
            out16[(size_t)node * 16 + li * 2 + 1] = o2;
        }
    }
}

// ---------------- MFMA GEMM: C[M,Nc] = act(A[M,K] @ B[K,Nc] + bias) [* oscale] ----------------
// 64x64 tile, blockIdx.y = 64-col B tile. Software prefetch: next k-tile staged to regs
// after the first barrier, overlapping the frag reads + MFMAs.

__global__ __launch_bounds__(256) void gemm_mfma(const unsigned short* __restrict__ A,
                                                 const unsigned short* __restrict__ Bw,
                                                 const float* __restrict__ bias, unsigned short* __restrict__ C,
                                                 const float* __restrict__ oscale,
                                                 const float* __restrict__ attS, const float* __restrict__ attD,
                                                 float* __restrict__ oas, float* __restrict__ oad,
                                                 int M, int K, int Nc, float slope, int act) {
    __shared__ __align__(16) unsigned short As[64 * 40];
    __shared__ __align__(16) unsigned short Bs[64 * 40];
    const int tid  = threadIdx.x;
    const int wave = tid >> 6;
    const int lane = tid & 63;
    const int q    = lane >> 4;
    const int r16  = lane & 15;
    const int m0 = blockIdx.x * 64;
    const int n0 = blockIdx.y * 64;

    floatx4 acc0 = {0.f,0.f,0.f,0.f}, acc1 = acc0, acc2 = acc0, acc3 = acc0;

    const int am = tid >> 2;         // 0..63 (tile row)
    const int ak = (tid & 3) * 8;    // 0..24
    const int bk = tid >> 3;         // 0..31 (k within step)
    const int bn = (tid & 7) * 8;    // 0..56
    const int gm = m0 + am;

    ushort8 sva, svb;
    if (gm < M) sva = *(const ushort8*)(A + (size_t)gm * K + ak);
    else        for (int j = 0; j < 8; ++j) sva[j] = 0;
    svb = *(const ushort8*)(Bw + (size_t)bk * Nc + n0 + bn);

    for (int k0 = 0; k0 < K; k0 += 32) {
        *(ushort8*)(&As[am * 40 + ak]) = sva;
        for (int j = 0; j < 8; ++j) Bs[(bn + j) * 40 + bk] = svb[j];
        __syncthreads();
        if (k0 + 32 < K) {
            if (gm < M) sva = *(const ushort8*)(A + (size_t)gm * K + k0 + 32 + ak);
            svb = *(const ushort8*)(Bw + (size_t)(k0 + 32 + bk) * Nc + n0 + bn);
        }
        short8 bfrag = *(const short8*)(&Bs[(wave * 16 + r16) * 40 + q * 8]);
        short8 a0 = *(const short8*)(&As[(r16) * 40 + q * 8]);
        short8 a1 = *(const short8*)(&As[(16 + r16) * 40 + q * 8]);
        short8 a2 = *(const short8*)(&As[(32 + r16) * 40 + q * 8]);
        short8 a3 = *(const short8*)(&As[(48 + r16) * 40 + q * 8]);
        acc0 = __builtin_amdgcn_mfma_f32_16x16x32_bf16(a0, bfrag, acc0, 0, 0, 0);
        acc1 = __builtin_amdgcn_mfma_f32_16x16x32_bf16(a1, bfrag, acc1, 0, 0, 0);
        acc2 = __builtin_amdgcn_mfma_f32_16x16x32_bf16(a2, bfrag, acc2, 0, 0, 0);
        acc3 = __builtin_amdgcn_mfma_f32_16x16x32_bf16(a3, bfrag, acc3, 0, 0, 0);
        __syncthreads();
    }
    // epilogue: C/D layout col=lane&15, row=(lane>>4)*4+reg
    int cn = n0 + wave * 16 + r16;
    float bv = bias ? bias[cn] : 0.f;
    floatx4 aa[4] = {acc0, acc1, acc2, acc3};
    float ps[16], pd[16];
    float avs = attS ? attS[cn] : 0.f;
    float avd = attS ? attD[cn] : 0.f;
    for (int ms = 0; ms < 4; ++ms)
        for (int rr = 0; rr < 4; ++rr) {
            int cm = m0 + ms * 16 + q * 4 + rr;
            float v = aa[ms][rr] + bv;
            if (act) v = lrelu(v, slope);
            if (oscale && cm < M) v *= oscale[cm];
            if (cm < M) C[(size_t)cm * Nc + cn] = f2bf(v);
            ps[ms * 4 + rr] = v * avs;
            pd[ms * 4 + rr] = v * avd;
        }
    if (attS) {
        // reduce over the 16 cols held by this wave's q-group (lanes aligned 16)
        for (int off = 1; off < 16; off <<= 1)
#pragma unroll
            for (int i = 0; i < 16; ++i) {
                ps[i] += __shfl_xor(ps[i], off, 64);
                pd[i] += __shfl_xor(pd[i], off, 64);
            }
        // cross-wave combine in LDS (reuse As; all LDS reads done before last barrier)
        float* sd = (float*)As;
        if (tid < 128) sd[tid] = 0.f;
        __syncthreads();
        if (r16 == 0) {
#pragma unroll
            for (int i = 0; i < 16; ++i) {
                int row = (i >> 2) * 16 + q * 4 + (i & 3);
                atomicAdd(&sd[row], ps[i]);
                atomicAdd(&sd[64 + row], pd[i]);
            }
        }
        __syncthreads();
        if (tid < 64 && m0 + tid < M) {
            oas[m0 + tid] = sd[tid];
            oad[m0 + tid] = sd[64 + tid];
        }
    }
}

// ---------------- GAT ----------------
// 8 edges in flight per t-step x 2-deep unroll = 16 gather loads in flight/wave.
// No segment-max pass: e = lrelu(a_s+a_d) is O(1..10) << 88, exp(e) fp32-safe; shift cancels.
__global__ __launch_bounds__(256) void gat_agg(const uint4* __restrict__ hg, const float* __restrict__ a_s,
                                               const float* __restrict__ a_d, const int* __restrict__ offs,
                                               const int* __restrict__ csr_s, const float* __restrict__ bg,
                                               uint4* __restrict__ out, int n) {
    int node = blockIdx.x * 4 + (threadIdx.x >> 6);
    if (node >= n) return;
    int lane = threadIdx.x & 63;
    int slot = lane >> 3;      // 0..7
    int li   = lane & 7;       // uint4 index within row
    int beg = offs[node], end = offs[node + 1];
    float ad = a_d[node];
    float a0=0.f,a1=0.f,a2=0.f,a3=0.f,a4=0.f,a5=0.f,a6=0.f,a7=0.f, ssum=0.f;
    for (int base = beg; base < end; base += 64) {
        int cnt = end - base; if (cnt > 64) cnt = 64;
        int sj = 0; float wj = 0.f;
        if (lane < cnt) {
            sj = csr_s[base + lane];
            float e = a_s[sj] + ad;
            e = e < 0.f ? 0.2f * e : e;
            wj = __expf(e);
        }
        for (int t = 0; t < cnt; t += 16) {
            int idx0 = t + slot, idx1 = t + 8 + slot;
            int c0 = idx0 < cnt ? idx0 : 0;
            int c1 = idx1 < cnt ? idx1 : 0;
            int   s0 = __shfl(sj, c0, 64);
            float w0 = __shfl(wj, c0, 64);
            int   s1 = __shfl(sj, c1, 64);
            float w1 = __shfl(wj, c1, 64);
            if (idx0 >= cnt) w0 = 0.f;
            if (idx1 >= cnt) w1 = 0.f;
            uint4 u0 = hg[(size_t)s0 * 8 + li];
            uint4 u1 = hg[(size_t)s1 * 8 + li];
            ssum += w0 + w1;
            a0 = fmaf(w0, bflo(u0.x), a0); a1 = fmaf(w0, bfhi(u0.x), a1);
            a2 = fmaf(w0, bflo(u0.y), a2); a3 = fmaf(w0, bfhi(u0.y), a3);
            a4 = fmaf(w0, bflo(u0.z), a4); a5 = fmaf(w0, bfhi(u0.z), a5);
            a6 = fmaf(w0, bflo(u0.w), a6); a7 = fmaf(w0, bfhi(u0.w), a7);
            a0 = fmaf(w1, bflo(u1.x), a0); a1 = fmaf(w1, bfhi(u1.x), a1);
            a2 = fmaf(w1, bflo(u1.y), a2); a3 = fmaf(w1, bfhi(u1.y), a3);
            a4 = fmaf(w1, bflo(u1.z), a4); a5 = fmaf(w1, bfhi(u1.z), a5);
            a6 = fmaf(w1, bflo(u1.w), a6); a7 = fmaf(w1, bfhi(u1.w), a7);
        }
    }
    for (int off = 8; off <= 32; off <<= 1) {
        a0 += __shfl_xor(a0, off, 64); a1 += __shfl_xor(a1, off, 64);
        a2 += __shfl_xor(a2, off, 64); a3 += __shfl_xor(a3, off, 64);
        a4 += __shfl_xor(a4, off, 64); a5 += __shfl_xor(a5, off, 64);
        a6 += __shfl_xor(a6, off, 64); a7 += __shfl_xor(a7, off, 64);
        ssum += __shfl_xor(ssum, off, 64);
    }
    if (slot == 0) {
        float inv = 1.0f / ssum;
        int f0 = li * 8;
        uint4 o;
        o.x = pack2bf(lrelu(a0 * inv + bg[f0 + 0], 0.1f), lrelu(a1 * inv + bg[f0 + 1], 0.1f));
        o.y = pack2bf(lrelu(a2 * inv + bg[f0 + 2], 0.1f), lrelu(a3 * inv + bg[f0 + 3], 0.1f));
        o.z = pack2bf(lrelu(a4 * inv + bg[f0 + 4], 0.1f), lrelu(a5 * inv + bg[f0 + 5], 0.1f));
        o.w = pack2bf(lrelu(a6 * inv + bg[f0 + 6], 0.1f), lrelu(a7 * inv + bg[f0 + 7], 0.1f));
        out[(size_t)node * 8 + li] = o;
    }
}

// ---------------- final small GEMM [Ng,256]@[256,8] + bias -> fp32 ----------------

__global__ __launch_bounds__(256) void final_gemm(const unsigned short* __restrict__ m2, const float* __restrict__ W3,
                                                  const float* __restrict__ b3,
                                                  float* __restrict__ out, int ng) {
    int idx = blockIdx.x * 256 + threadIdx.x;
    if (idx >= ng * 8) return;
    int r = idx >> 3, c = idx & 7;
    float acc = b3[c];
    const unsigned short* row = m2 + (size_t)r * 256;
    for (int k = 0; k < 256; ++k) acc = fmaf(bf2f(row[k]), W3[k * 8 + c], acc);
    out[idx] = acc;
}

// ---------------- launch ----------------

extern "C" void kernel_launch(void* const* d_in, const int* in_sizes, int n_in,
                              void* d_out, int out_size, void* d_ws, size_t ws_size,
                              hipStream_t stream) {
    const int N  = in_sizes[0] / 128;
    const int E  = in_sizes[1] / 2;
    const int ET = E + N;
    const int Ng = N / 10;
    const int NB = (N + 127) / 128;   // dst buckets (<= NBQ)

    const float* x    = (const float*)d_in[0];
    const int*   src  = (const int*)d_in[1];
    const int*   dst  = src + E;
    const float* W1   = (const float*)d_in[2];
    const float* b1   = (const float*)d_in[3];
    const float* W2   = (const float*)d_in[4];
    const float* b2   = (const float*)d_in[5];
    const float* Wg   = (const float*)d_in[6];
    const float* atts = (const float*)d_in[7];
    const float* attd = (const float*)d_in[8];
    const float* bg   = (const float*)d_in[9];
    const float* Wl1  = (const float*)d_in[10];
    const float* bl1  = (const float*)d_in[11];
    const float* Wl2  = (const float*)d_in[12];
    const float* bl2  = (const float*)d_in[13];
    const float* Wl3  = (const float*)d_in[14];
    const float* bl3  = (const float*)d_in[15];
    float* out = (float*)d_out;

    // bf16 weight buffer segment sizes (pairs)
    const int p1 = in_sizes[2] / 2;    // W1
    const int p2 = in_sizes[4] / 2;    // W2
    const int p3 = in_sizes[6] / 2;    // Wg
    const int p4 = in_sizes[10] / 2;   // Wl1
    const int p5 = in_sizes[12] / 2;   // Wl2
    const int c0 = p1, c1 = c0 + p2, c2 = c1 + p3, c3 = c2 + p4, c4 = c3 + p5;

    // workspace carve (all feature buffers bf16, 16B-aligned rows)
    char* p = (char*)d_ws;
    auto alloc = [&](size_t bytes) { char* r = p; p += (bytes + 255) & ~(size_t)255; return r; };
    unsigned short* xb = (unsigned short*)alloc((size_t)N * 128 * 2);
    unsigned short* A  = (unsigned short*)alloc((size_t)N * 128 * 2);
    unsigned short* Bb = (unsigned short*)alloc((size_t)N * 128 * 2);
    int*   csr_s   = (int*)  alloc((size_t)ET * 4);
    int*   cnt     = (int*)  alloc((size_t)NBLK * NBQ * 4);
    int*   btot    = (int*)  alloc((size_t)(NBQ + 1) * 4);
    int*   bbase   = (int*)  alloc((size_t)(NBQ + 1) * 4);
    float* dinv    = (float*)alloc((size_t)N * 4);
    int*   offsets = (int*)  alloc((size_t)(N + 1) * 4);
    float* a_s     = (float*)alloc((size_t)N * 4);
    float* a_d     = (float*)alloc((size_t)N * 4);
    unsigned short* wb = (unsigned short*)alloc((size_t)c4 * 4);  // packed bf16 weights
    // ebuf (packed src|dlow, ET*4 bytes) aliases Bb; lifetime ends before Bb's first write.
    int*   ebuf    = (int*)Bb;
    // fp8 tables (each N*128 bytes = half of xb); reused by conv1 then conv2
    unsigned* x8 = (unsigned*)xb;                       // quantized gather input table
    uint4*    a8 = (uint4*)(xb + (size_t)N * 64);       // hop-1 output, fp8

    const unsigned short* W1b  = wb;
    const unsigned short* W2b  = wb + 2 * (size_t)c0;
    const unsigned short* Wgb  = wb + 2 * (size_t)c1;
    const unsigned short* Wl1b = wb + 2 * (size_t)c2;
    const unsigned short* Wl2b = wb + 2 * (size_t)c3;

    const int pg = (N + 3) / 4;

    hist_k    <<<NBLK, 256, 0, stream>>>(dst, cnt, E, ET, NB);
    btot_k    <<<(NB + 255) / 256, 256, 0, stream>>>(cnt, btot, NB);
    bscan_k   <<<1, 256, 0, stream>>>(btot, bbase, NB, ET);
    scan_cnt  <<<(NB + 255) / 256, 256, 0, stream>>>(cnt, bbase, NB);
    scatter_k <<<NBLK, 256, 0, stream>>>(src, dst, cnt, ebuf, E, ET, NB);
    finalize_k<<<NB, 256, 0, stream>>>(ebuf, bbase, offsets, dinv, csr_s, N, ET);
    wcast     <<<(c4 + 255) / 256, 256, 0, stream>>>(W1, W2, Wg, Wl1, Wl2, (unsigned*)wb, c0, c1, c2, c3, c4);
    cast_scale8<<<(N * 32 + 255) / 256, 256, 0, stream>>>(x, dinv, x8, N * 32);

    // conv1 (fp8 gather tables): u = D^-1/2 x (quantized) ; a8 = D^-1 A u (fp8) ;
    // Bb = D^-1/2 A a8 = P^2 x (bf16) ; A = h1' = lrelu(Bb@W1+b1)*dinv
    prop8_kernel<<<pg, 256, 0, stream>>>((const uint4*)x8, offsets, csr_s, dinv, 1, 1, a8, nullptr, N);
    prop8_kernel<<<pg, 256, 0, stream>>>(a8, offsets, csr_s, dinv, 0, 0, nullptr, (uint4*)Bb, N);
    dim3 g1((N + 63) / 64, 2);
    gemm_mfma<<<g1, 256, 0, stream>>>(Bb, W1b, b1, A, dinv, nullptr, nullptr, nullptr, nullptr,
                                      N, 128, 128, 0.1f, 1);
    // conv2 (fp8 gather tables): quantize h1' then the same two-hop pipeline
    cast_bf2fp8<<<(N * 32 + 255) / 256, 256, 0, stream>>>((const uint2*)A, x8, N * 32);
    prop8_kernel<<<pg, 256, 0, stream>>>((const uint4*)x8, offsets, csr_s, dinv, 1, 1, a8, nullptr, N);
    prop8_kernel<<<pg, 256, 0, stream>>>(a8, offsets, csr_s, dinv, 0, 0, nullptr, (uint4*)A, N);
    gemm_mfma<<<g1, 256, 0, stream>>>(A, W2b, b2, Bb, nullptr, nullptr, nullptr, nullptr, nullptr,
                                      N, 128, 128, 0.1f, 1);
    // GAT: hg = h2 @ Wg with fused a_s/a_d row-dots, then attention aggregate
    dim3 g2((N + 63) / 64, 1);
    gemm_mfma<<<g2, 256, 0, stream>>>(Bb, Wgb, nullptr, A, nullptr, atts, attd, a_s, a_d,
                                      N, 128, 64, 0.f, 0);
    gat_agg <<<pg, 256, 0, stream>>>((const uint4*)A, a_s, a_d, offsets, csr_s, bg, (uint4*)Bb, N);
    // MLP: Bb viewed as [Ng, 640] bf16
    dim3 g3((Ng + 63) / 64, 8);
    gemm_mfma<<<g3, 256, 0, stream>>>(Bb, Wl1b, bl1, A, nullptr, nullptr, nullptr, nullptr, nullptr,
                                      Ng, 640, 512, 0.1f, 1);
    dim3 g4((Ng + 63) / 64, 4);
    gemm_mfma<<<g4, 256, 0, stream>>>(A, Wl2b, bl2, Bb, nullptr, nullptr, nullptr, nullptr, nullptr,
                                      Ng, 512, 256, 0.1f, 1);
    final_gemm<<<(Ng * 8 + 255) / 256, 256, 0, stream>>>(Bb, Wl3, bl3, out, Ng);
}

// Round 5
// 518.554 us; speedup vs baseline: 1.2502x; 1.1706x over previous
//
#include <hip/hip_runtime.h>

typedef __attribute__((ext_vector_type(8))) short short8;
typedef __attribute__((ext_vector_type(8))) unsigned short ushort8;
typedef __attribute__((ext_vector_type(4))) float floatx4;
typedef __attribute__((ext_vector_type(2))) float floatx2;

#define NBQ  1024     // max buckets (N <= 131072 @ 128 nodes/bucket; packing needs N <= 2^17)
#define NBLK 128      // sort blocks

__device__ __forceinline__ float bf2f(unsigned short u) {
    union { unsigned u; float f; } v; v.u = ((unsigned)u) << 16; return v.f;
}
__device__ __forceinline__ float bflo(unsigned u) {
    union { unsigned u; float f; } v; v.u = u << 16; return v.f;
}
__device__ __forceinline__ float bfhi(unsigned u) {
    union { unsigned u; float f; } v; v.u = u & 0xFFFF0000u; return v.f;
}
__device__ __forceinline__ unsigned short f2bf(float f) {
    union { float f; unsigned u; } v; v.f = f;
    unsigned r = v.u + 0x7FFFu + ((v.u >> 16) & 1u);
    return (unsigned short)(r >> 16);
}
__device__ __forceinline__ unsigned pack2bf(float a, float b) {
    return (unsigned)f2bf(a) | ((unsigned)f2bf(b) << 16);
}
__device__ __forceinline__ float lrelu(float x, float s) { return x >= 0.f ? x : s * x; }

// fp8 e4m3 (OCP) hardware converts. The old/word builtin args must be INTEGER CONSTANT
// EXPRESSIONS -> macros with literals (an inline-function bool param fails to compile).
#define PK_FP8_LO(a, b, old) __builtin_amdgcn_cvt_pk_fp8_f32((a), (b), (old), false)
#define PK_FP8_HI(a, b, old) __builtin_amdgcn_cvt_pk_fp8_f32((a), (b), (old), true)
#define UPK_FP8_LO(u)        __builtin_amdgcn_cvt_pk_f32_fp8((int)(u), false)
#define UPK_FP8_HI(u)        __builtin_amdgcn_cvt_pk_f32_fp8((int)(u), true)

// fp32 -> fp8 e4m3 quads (4 feats / thread), pre-scaled by dinv[node] (128 feats = 32 uints/node)
__global__ __launch_bounds__(256) void cast_scale8(const float* __restrict__ in, const float* __restrict__ dinv,
                                                   unsigned* __restrict__ outp, int nquads) {
    int i = blockIdx.x * 256 + threadIdx.x;
    if (i < nquads) {
        float s = dinv[i >> 5];
        float4 v = *(const float4*)(in + 4 * (size_t)i);
        int w = PK_FP8_LO(v.x * s, v.y * s, 0);
        w = PK_FP8_HI(v.z * s, v.w * s, w);
        outp[i] = (unsigned)w;
    }
}

// bf16 -> fp8 e4m3 (4 feats / thread); converts h1' into a gather-friendly 128B-row table
__global__ __launch_bounds__(256) void cast_bf2fp8(const uint2* __restrict__ in, unsigned* __restrict__ outp,
                                                   int nquads) {
    int i = blockIdx.x * 256 + threadIdx.x;
    if (i < nquads) {
        uint2 v = in[i];
        int w = PK_FP8_LO(bflo(v.x), bfhi(v.x), 0);
        w = PK_FP8_HI(bflo(v.y), bfhi(v.y), w);
        outp[i] = (unsigned)w;
    }
}

// one-shot fp32 -> bf16 cast of 5 weight matrices into one packed buffer
__global__ __launch_bounds__(256) void wcast(const float* __restrict__ w0, const float* __restrict__ w1,
                                             const float* __restrict__ w2, const float* __restrict__ w3,
                                             const float* __restrict__ w4, unsigned* __restrict__ outp,
                                             int c0, int c1, int c2, int c3, int c4) {
    int i = blockIdx.x * 256 + threadIdx.x;
    if (i >= c4) return;
    const float* src; int base;
    if      (i < c0) { src = w0; base = 0;  }
    else if (i < c1) { src = w1; base = c0; }
    else if (i < c2) { src = w2; base = c1; }
    else if (i < c3) { src = w3; base = c2; }
    else             { src = w4; base = c3; }
    float2 v = *(const float2*)(src + 2 * (size_t)(i - base));
    outp[i] = pack2bf(v.x, v.y);
}

// ---- CSR build: two-phase counting sort (bucket = 128 dst nodes), no global atomics ----
__global__ __launch_bounds__(256) void hist_k(const int* __restrict__ dst, int* __restrict__ cnt,
                                              int e, int et, int nb) {
    __shared__ int h[NBQ];
    for (int i = threadIdx.x; i < nb; i += 256) h[i] = 0;
    __syncthreads();
    int chunk = (et + NBLK - 1) / NBLK;
    int c0 = blockIdx.x * chunk;
    int c1 = c0 + chunk < et ? c0 + chunk : et;
    for (int i = c0 + (int)threadIdx.x; i < c1; i += 256) {
        int d = (i < e) ? dst[i] : (i - e);
        atomicAdd(&h[d >> 7], 1);
    }
    __syncthreads();
    for (int i = threadIdx.x; i < nb; i += 256) cnt[blockIdx.x * NBQ + i] = h[i];
}

__global__ __launch_bounds__(256) void btot_k(const int* __restrict__ cnt, int* __restrict__ btot, int nb) {
    int b = blockIdx.x * 256 + threadIdx.x;
    if (b >= nb) return;
    int s = 0;
    for (int blk = 0; blk < NBLK; ++blk) s += cnt[blk * NBQ + b];
    btot[b] = s;
}

__global__ __launch_bounds__(256) void bscan_k(const int* __restrict__ btot, int* __restrict__ bbase,
                                               int nb, int et) {
    __shared__ int sd[256];
    int t = threadIdx.x;
    int i0 = t * 4;
    int loc[4]; int s = 0;
    for (int j = 0; j < 4; ++j) { int i = i0 + j; loc[j] = (i < nb) ? btot[i] : 0; s += loc[j]; }
    sd[t] = s; __syncthreads();
    for (int off = 1; off < 256; off <<= 1) {
        int v = (t >= off) ? sd[t - off] : 0;
        __syncthreads();
        sd[t] += v;
        __syncthreads();
    }
    int run = sd[t] - s;
    for (int j = 0; j < 4; ++j) {
        int i = i0 + j;
        if (i < nb) { bbase[i] = run; run += loc[j]; }
    }
    if (t == 255) bbase[nb] = et;
}

__global__ __launch_bounds__(256) void scan_cnt(int* __restrict__ cnt, const int* __restrict__ bbase,
                                                int nb) {
    int b = blockIdx.x * 256 + threadIdx.x;
    if (b >= nb) return;
    int base = bbase[b];
    for (int blk = 0; blk < NBLK; ++blk) {
        int* p = &cnt[blk * NBQ + b];
        int t = *p; *p = base; base += t;
    }
}

// scatter packed entries: s (17 bits, N <= 131072) | (d&127) << 17 — 4B/edge
__global__ __launch_bounds__(256) void scatter_k(const int* __restrict__ src, const int* __restrict__ dst,
                                                 const int* __restrict__ cnt,
                                                 int* __restrict__ ebuf, int e, int et, int nb) {
    __shared__ int cur[NBQ];
    for (int i = threadIdx.x; i < nb; i += 256) cur[i] = cnt[blockIdx.x * NBQ + i];
    __syncthreads();
    int chunk = (et + NBLK - 1) / NBLK;
    int c0 = blockIdx.x * chunk;
    int c1 = c0 + chunk < et ? c0 + chunk : et;
    for (int i = c0 + (int)threadIdx.x; i < c1; i += 256) {
        int s, d;
        if (i < e) { s = src[i]; d = dst[i]; }
        else       { s = d = i - e; }            // self loop
        int pos = atomicAdd(&cur[d >> 7], 1);
        ebuf[pos] = s | ((d & 127) << 17);
    }
}

// fused: per-bucket degree count + scan -> offsets/dinv, then node-granular CSR
// placement with LDS cursors (ebuf segment stays L2-hot between the two passes)
__global__ __launch_bounds__(256) void finalize_k(const int* __restrict__ ebuf, const int* __restrict__ bbase,
                                                  int* __restrict__ offsets, float* __restrict__ dinv,
                                                  int* __restrict__ csr_s, int n, int et) {
    __shared__ int ldeg[128];
    __shared__ int lscan[128];
    __shared__ int cur[128];
    int b = blockIdx.x;
    int n0 = b << 7;
    if (threadIdx.x < 128) ldeg[threadIdx.x] = 0;
    __syncthreads();
    int e0 = bbase[b], e1 = bbase[b + 1];
    for (int i = e0 + (int)threadIdx.x; i < e1; i += 256)
        atomicAdd(&ldeg[(ebuf[i] >> 17) & 127], 1);
    __syncthreads();
    if (threadIdx.x < 128) lscan[threadIdx.x] = ldeg[threadIdx.x];
    __syncthreads();
    for (int off = 1; off < 128; off <<= 1) {
        int v = 0;
        if (threadIdx.x < 128 && (int)threadIdx.x >= off) v = lscan[threadIdx.x - off];
        __syncthreads();
        if (threadIdx.x < 128) lscan[threadIdx.x] += v;
        __syncthreads();
    }
    if (threadIdx.x < 128) {
        int base = e0 + lscan[threadIdx.x] - ldeg[threadIdx.x];   // exclusive
        cur[threadIdx.x] = base;
        int node = n0 + threadIdx.x;
        if (node < n) {
            offsets[node] = base;
            dinv[node] = rsqrtf((float)ldeg[threadIdx.x]);         // deg >= 1 (self loop)
        }
    }
    if (b == 0 && threadIdx.x == 0) offsets[n] = et;
    __syncthreads();
    for (int i = e0 + (int)threadIdx.x; i < e1; i += 256) {
        int ent = ebuf[i];
        int pos = atomicAdd(&cur[(ent >> 17) & 127], 1);
        csr_s[pos] = ent & 0x1FFFF;
    }
}

// ---------------- propagation (fp8 e4m3 table, 128B rows = 8 x uint4) ----------------
// out[d] = scale(d) * sum_{s in N(d)} x[s]; f32 accumulate (only storage is quantized).
// Lane-group-per-node: 8 lanes own one node's full row (16 feats/lane as f32 accs),
// iterate its edge list sequentially (2-deep unroll). NO cross-lane reduce epilogue
// (the 48-shfl reduce dominated per-node cost at avg degree ~17). 8 nodes/wave.
// out8f: 1 -> write fp8 table (next hop's gather), 0 -> write bf16 rows (MFMA GEMM input).

#define ACC16F(u) { floatx2 t0_ = UPK_FP8_LO((u).x), t1_ = UPK_FP8_HI((u).x); \
                    a[0] += t0_.x; a[1] += t0_.y; a[2] += t1_.x; a[3] += t1_.y; \
                    t0_ = UPK_FP8_LO((u).y); t1_ = UPK_FP8_HI((u).y); \
                    a[4] += t0_.x; a[5] += t0_.y; a[6] += t1_.x; a[7] += t1_.y; \
                    t0_ = UPK_FP8_LO((u).z); t1_ = UPK_FP8_HI((u).z); \
                    a[8] += t0_.x; a[9] += t0_.y; a[10] += t1_.x; a[11] += t1_.y; \
                    t0_ = UPK_FP8_LO((u).w); t1_ = UPK_FP8_HI((u).w); \
                    a[12] += t0_.x; a[13] += t0_.y; a[14] += t1_.x; a[15] += t1_.y; }

__global__ __launch_bounds__(256) void prop8_kernel(const uint4* __restrict__ xin, const int* __restrict__ offs,
                                                    const int* __restrict__ csr_s, const float* __restrict__ dinv,
                                                    int sq, int out8f, uint4* __restrict__ out8,
                                                    uint4* __restrict__ out16, int n) {
    int node = blockIdx.x * 32 + (threadIdx.x >> 3);
    if (node >= n) return;
    int li = threadIdx.x & 7;      // uint4 index within 8-uint4 (128B) fp8 row; feats li*16..+15
    int beg = offs[node], end = offs[node + 1];
    float a[16];
#pragma unroll
    for (int j = 0; j < 16; ++j) a[j] = 0.f;
    int e = beg;
    for (; e + 1 < end; e += 2) {
        int s0 = csr_s[e];
        int s1 = csr_s[e + 1];
        uint4 u0 = xin[(size_t)s0 * 8 + li];
        uint4 u1 = xin[(size_t)s1 * 8 + li];
        ACC16F(u0); ACC16F(u1);
    }
    if (e < end) {
        int s = csr_s[e];
        uint4 u = xin[(size_t)s * 8 + li];
        ACC16F(u);
    }
    float f = dinv[node];
    if (sq) f *= f;
    if (out8f) {
        int w0 = PK_FP8_LO(a[0] * f, a[1] * f, 0);   w0 = PK_FP8_HI(a[2] * f, a[3] * f, w0);
        int w1 = PK_FP8_LO(a[4] * f, a[5] * f, 0);   w1 = PK_FP8_HI(a[6] * f, a[7] * f, w1);
        int w2 = PK_FP8_LO(a[8] * f, a[9] * f, 0);   w2 = PK_FP8_HI(a[10] * f, a[11] * f, w2);
        int w3 = PK_FP8_LO(a[12] * f, a[13] * f, 0); w3 = PK_FP8_HI(a[14] * f, a[15] * f, w3);
        uint4 o; o.x = (unsigned)w0; o.y = (unsigned)w1; o.z = (unsigned)w2; o.w = (unsigned)w3;
        out8[(size_t)node * 8 + li] = o;
    } else {
        uint4 o1, o2;
        o1.x = pack2bf(a[0] * f, a[1] * f);   o1.y = pack2bf(a[2] * f, a[3] * f);
        o1.z = pack2bf(a[4] * f, a[5] * f);   o1.w = pack2bf(a[6] * f, a[7] * f);
        o2.x = pack2bf(a[8] * f, a[9] * f);   o2.y = pack2bf(a[10] * f, a[11] * f);
        o2.z = pack2bf(a[12] * f, a[13] * f); o2.w = pack2bf(a[14] * f, a[15] * f);
        out16[(size_t)node * 16 + li * 2]     = o1;
        out16[(size_t)node * 16 + li * 2 + 1] = o2;
    }
}

// ---------------- MFMA GEMM: C[M,Nc] = act(A[M,K] @ B[K,Nc] + bias) [* oscale] ----------------
// 64x64 tile, blockIdx.y = 64-col B tile. Software prefetch: next k-tile staged to regs
// after the first barrier, overlapping the frag reads + MFMAs.

__global__ __launch_bounds__(256) void gemm_mfma(const unsigned short* __restrict__ A,
                                                 const unsigned short* __restrict__ Bw,
                                                 const float* __restrict__ bias, unsigned short* __restrict__ C,
                                                 const float* __restrict__ oscale,
                                                 const float* __restrict__ attS, const float* __restrict__ attD,
                                                 float* __restrict__ oas, float* __restrict__ oad,
                                                 int M, int K, int Nc, float slope, int act) {
    __shared__ __align__(16) unsigned short As[64 * 40];
    __shared__ __align__(16) unsigned short Bs[64 * 40];
    const int tid  = threadIdx.x;
    const int wave = tid >> 6;
    const int lane = tid & 63;
    const int q    = lane >> 4;
    const int r16  = lane & 15;
    const int m0 = blockIdx.x * 64;
    const int n0 = blockIdx.y * 64;

    floatx4 acc0 = {0.f,0.f,0.f,0.f}, acc1 = acc0, acc2 = acc0, acc3 = acc0;

    const int am = tid >> 2;         // 0..63 (tile row)
    const int ak = (tid & 3) * 8;    // 0..24
    const int bk = tid >> 3;         // 0..31 (k within step)
    const int bn = (tid & 7) * 8;    // 0..56
    const int gm = m0 + am;

    ushort8 sva, svb;
    if (gm < M) sva = *(const ushort8*)(A + (size_t)gm * K + ak);
    else        for (int j = 0; j < 8; ++j) sva[j] = 0;
    svb = *(const ushort8*)(Bw + (size_t)bk * Nc + n0 + bn);

    for (int k0 = 0; k0 < K; k0 += 32) {
        *(ushort8*)(&As[am * 40 + ak]) = sva;
        for (int j = 0; j < 8; ++j) Bs[(bn + j) * 40 + bk] = svb[j];
        __syncthreads();
        if (k0 + 32 < K) {
            if (gm < M) sva = *(const ushort8*)(A + (size_t)gm * K + k0 + 32 + ak);
            svb = *(const ushort8*)(Bw + (size_t)(k0 + 32 + bk) * Nc + n0 + bn);
        }
        short8 bfrag = *(const short8*)(&Bs[(wave * 16 + r16) * 40 + q * 8]);
        short8 a0 = *(const short8*)(&As[(r16) * 40 + q * 8]);
        short8 a1 = *(const short8*)(&As[(16 + r16) * 40 + q * 8]);
        short8 a2 = *(const short8*)(&As[(32 + r16) * 40 + q * 8]);
        short8 a3 = *(const short8*)(&As[(48 + r16) * 40 + q * 8]);
        acc0 = __builtin_amdgcn_mfma_f32_16x16x32_bf16(a0, bfrag, acc0, 0, 0, 0);
        acc1 = __builtin_amdgcn_mfma_f32_16x16x32_bf16(a1, bfrag, acc1, 0, 0, 0);
        acc2 = __builtin_amdgcn_mfma_f32_16x16x32_bf16(a2, bfrag, acc2, 0, 0, 0);
        acc3 = __builtin_amdgcn_mfma_f32_16x16x32_bf16(a3, bfrag, acc3, 0, 0, 0);
        __syncthreads();
    }
    // epilogue: C/D layout col=lane&15, row=(lane>>4)*4+reg
    int cn = n0 + wave * 16 + r16;
    float bv = bias ? bias[cn] : 0.f;
    floatx4 aa[4] = {acc0, acc1, acc2, acc3};
    float ps[16], pd[16];
    float avs = attS ? attS[cn] : 0.f;
    float avd = attS ? attD[cn] : 0.f;
    for (int ms = 0; ms < 4; ++ms)
        for (int rr = 0; rr < 4; ++rr) {
            int cm = m0 + ms * 16 + q * 4 + rr;
            float v = aa[ms][rr] + bv;
            if (act) v = lrelu(v, slope);
            if (oscale && cm < M) v *= oscale[cm];
            if (cm < M) C[(size_t)cm * Nc + cn] = f2bf(v);
            ps[ms * 4 + rr] = v * avs;
            pd[ms * 4 + rr] = v * avd;
        }
    if (attS) {
        // reduce over the 16 cols held by this wave's q-group (lanes aligned 16)
        for (int off = 1; off < 16; off <<= 1)
#pragma unroll
            for (int i = 0; i < 16; ++i) {
                ps[i] += __shfl_xor(ps[i], off, 64);
                pd[i] += __shfl_xor(pd[i], off, 64);
            }
        // cross-wave combine in LDS (reuse As; all LDS reads done before last barrier)
        float* sd = (float*)As;
        if (tid < 128) sd[tid] = 0.f;
        __syncthreads();
        if (r16 == 0) {
#pragma unroll
            for (int i = 0; i < 16; ++i) {
                int row = (i >> 2) * 16 + q * 4 + (i & 3);
                atomicAdd(&sd[row], ps[i]);
                atomicAdd(&sd[64 + row], pd[i]);
            }
        }
        __syncthreads();
        if (tid < 64 && m0 + tid < M) {
            oas[m0 + tid] = sd[tid];
            oad[m0 + tid] = sd[64 + tid];
        }
    }
}

// ---------------- GAT ----------------
// Lane-group-per-node: 8 lanes own one node's 64-feat bf16 row (8 feats/lane).
// Per edge: group-uniform csr/a_s loads (HW broadcast), redundant exp per lane,
// FMA into lane-local accs. No shuffles at all. 8 nodes/wave, 2-deep unroll.
// No segment-max pass: e = lrelu(a_s+a_d) is O(1..10) << 88, exp(e) fp32-safe; shift cancels.
__global__ __launch_bounds__(256) void gat_agg(const uint4* __restrict__ hg, const float* __restrict__ a_s,
                                               const float* __restrict__ a_d, const int* __restrict__ offs,
                                               const int* __restrict__ csr_s, const float* __restrict__ bg,
                                               uint4* __restrict__ out, int n) {
    int node = blockIdx.x * 32 + (threadIdx.x >> 3);
    if (node >= n) return;
    int li = threadIdx.x & 7;      // uint4 index within 8-uint4 (128B) bf16 row
    int beg = offs[node], end = offs[node + 1];
    float ad = a_d[node];
    float a0=0.f,a1=0.f,a2=0.f,a3=0.f,a4=0.f,a5=0.f,a6=0.f,a7=0.f, ssum=0.f;
    int e = beg;
    for (; e + 1 < end; e += 2) {
        int s0 = csr_s[e];
        int s1 = csr_s[e + 1];
        float t0 = a_s[s0] + ad;
        float t1 = a_s[s1] + ad;
        uint4 u0 = hg[(size_t)s0 * 8 + li];
        uint4 u1 = hg[(size_t)s1 * 8 + li];
        t0 = t0 < 0.f ? 0.2f * t0 : t0;
        t1 = t1 < 0.f ? 0.2f * t1 : t1;
        float w0 = __expf(t0);
        float w1 = __expf(t1);
        ssum += w0 + w1;
        a0 = fmaf(w0, bflo(u0.x), a0); a1 = fmaf(w0, bfhi(u0.x), a1);
        a2 = fmaf(w0, bflo(u0.y), a2); a3 = fmaf(w0, bfhi(u0.y), a3);
        a4 = fmaf(w0, bflo(u0.z), a4); a5 = fmaf(w0, bfhi(u0.z), a5);
        a6 = fmaf(w0, bflo(u0.w), a6); a7 = fmaf(w0, bfhi(u0.w), a7);
        a0 = fmaf(w1, bflo(u1.x), a0); a1 = fmaf(w1, bfhi(u1.x), a1);
        a2 = fmaf(w1, bflo(u1.y), a2); a3 = fmaf(w1, bfhi(u1.y), a3);
        a4 = fmaf(w1, bflo(u1.z), a4); a5 = fmaf(w1, bfhi(u1.z), a5);
        a6 = fmaf(w1, bflo(u1.w), a6); a7 = fmaf(w1, bfhi(u1.w), a7);
    }
    if (e < end) {
        int s0 = csr_s[e];
        float t0 = a_s[s0] + ad;
        uint4 u0 = hg[(size_t)s0 * 8 + li];
        t0 = t0 < 0.f ? 0.2f * t0 : t0;
        float w0 = __expf(t0);
        ssum += w0;
        a0 = fmaf(w0, bflo(u0.x), a0); a1 = fmaf(w0, bfhi(u0.x), a1);
        a2 = fmaf(w0, bflo(u0.y), a2); a3 = fmaf(w0, bfhi(u0.y), a3);
        a4 = fmaf(w0, bflo(u0.z), a4); a5 = fmaf(w0, bfhi(u0.z), a5);
        a6 = fmaf(w0, bflo(u0.w), a6); a7 = fmaf(w0, bfhi(u0.w), a7);
    }
    float inv = 1.0f / ssum;
    int f0 = li * 8;
    uint4 o;
    o.x = pack2bf(lrelu(a0 * inv + bg[f0 + 0], 0.1f), lrelu(a1 * inv + bg[f0 + 1], 0.1f));
    o.y = pack2bf(lrelu(a2 * inv + bg[f0 + 2], 0.1f), lrelu(a3 * inv + bg[f0 + 3], 0.1f));
    o.z = pack2bf(lrelu(a4 * inv + bg[f0 + 4], 0.1f), lrelu(a5 * inv + bg[f0 + 5], 0.1f));
    o.w = pack2bf(lrelu(a6 * inv + bg[f0 + 6], 0.1f), lrelu(a7 * inv + bg[f0 + 7], 0.1f));
    out[(size_t)node * 8 + li] = o;
}

// ---------------- final small GEMM [Ng,256]@[256,8] + bias -> fp32 ----------------

__global__ __launch_bounds__(256) void final_gemm(const unsigned short* __restrict__ m2, const float* __restrict__ W3,
                                                  const float* __restrict__ b3,
                                                  float* __restrict__ out, int ng) {
    int idx = blockIdx.x * 256 + threadIdx.x;
    if (idx >= ng * 8) return;
    int r = idx >> 3, c = idx & 7;
    float acc = b3[c];
    const unsigned short* row = m2 + (size_t)r * 256;
    for (int k = 0; k < 256; ++k) acc = fmaf(bf2f(row[k]), W3[k * 8 + c], acc);
    out[idx] = acc;
}

// ---------------- launch ----------------

extern "C" void kernel_launch(void* const* d_in, const int* in_sizes, int n_in,
                              void* d_out, int out_size, void* d_ws, size_t ws_size,
                              hipStream_t stream) {
    const int N  = in_sizes[0] / 128;
    const int E  = in_sizes[1] / 2;
    const int ET = E + N;
    const int Ng = N / 10;
    const int NB = (N + 127) / 128;   // dst buckets (<= NBQ)

    const float* x    = (const float*)d_in[0];
    const int*   src  = (const int*)d_in[1];
    const int*   dst  = src + E;
    const float* W1   = (const float*)d_in[2];
    const float* b1   = (const float*)d_in[3];
    const float* W2   = (const float*)d_in[4];
    const float* b2   = (const float*)d_in[5];
    const float* Wg   = (const float*)d_in[6];
    const float* atts = (const float*)d_in[7];
    const float* attd = (const float*)d_in[8];
    const float* bg   = (const float*)d_in[9];
    const float* Wl1  = (const float*)d_in[10];
    const float* bl1  = (const float*)d_in[11];
    const float* Wl2  = (const float*)d_in[12];
    const float* bl2  = (const float*)d_in[13];
    const float* Wl3  = (const float*)d_in[14];
    const float* bl3  = (const float*)d_in[15];
    float* out = (float*)d_out;

    // bf16 weight buffer segment sizes (pairs)
    const int p1 = in_sizes[2] / 2;    // W1
    const int p2 = in_sizes[4] / 2;    // W2
    const int p3 = in_sizes[6] / 2;    // Wg
    const int p4 = in_sizes[10] / 2;   // Wl1
    const int p5 = in_sizes[12] / 2;   // Wl2
    const int c0 = p1, c1 = c0 + p2, c2 = c1 + p3, c3 = c2 + p4, c4 = c3 + p5;

    // workspace carve (all feature buffers bf16, 16B-aligned rows)
    char* p = (char*)d_ws;
    auto alloc = [&](size_t bytes) { char* r = p; p += (bytes + 255) & ~(size_t)255; return r; };
    unsigned short* xb = (unsigned short*)alloc((size_t)N * 128 * 2);
    unsigned short* A  = (unsigned short*)alloc((size_t)N * 128 * 2);
    unsigned short* Bb = (unsigned short*)alloc((size_t)N * 128 * 2);
    int*   csr_s   = (int*)  alloc((size_t)ET * 4);
    int*   cnt     = (int*)  alloc((size_t)NBLK * NBQ * 4);
    int*   btot    = (int*)  alloc((size_t)(NBQ + 1) * 4);
    int*   bbase   = (int*)  alloc((size_t)(NBQ + 1) * 4);
    float* dinv    = (float*)alloc((size_t)N * 4);
    int*   offsets = (int*)  alloc((size_t)(N + 1) * 4);
    float* a_s     = (float*)alloc((size_t)N * 4);
    float* a_d     = (float*)alloc((size_t)N * 4);
    unsigned short* wb = (unsigned short*)alloc((size_t)c4 * 4);  // packed bf16 weights
    // ebuf (packed src|dlow, ET*4 bytes) aliases Bb; lifetime ends before Bb's first write.
    int*   ebuf    = (int*)Bb;
    // fp8 tables (each N*128 bytes = half of xb); reused by conv1 then conv2
    unsigned* x8 = (unsigned*)xb;                       // quantized gather input table
    uint4*    a8 = (uint4*)(xb + (size_t)N * 64);       // hop-1 output, fp8

    const unsigned short* W1b  = wb;
    const unsigned short* W2b  = wb + 2 * (size_t)c0;
    const unsigned short* Wgb  = wb + 2 * (size_t)c1;
    const unsigned short* Wl1b = wb + 2 * (size_t)c2;
    const unsigned short* Wl2b = wb + 2 * (size_t)c3;

    const int pgp = (N + 31) / 32;    // lane-group kernels: 8 nodes/wave, 32/block

    hist_k    <<<NBLK, 256, 0, stream>>>(dst, cnt, E, ET, NB);
    btot_k    <<<(NB + 255) / 256, 256, 0, stream>>>(cnt, btot, NB);
    bscan_k   <<<1, 256, 0, stream>>>(btot, bbase, NB, ET);
    scan_cnt  <<<(NB + 255) / 256, 256, 0, stream>>>(cnt, bbase, NB);
    scatter_k <<<NBLK, 256, 0, stream>>>(src, dst, cnt, ebuf, E, ET, NB);
    finalize_k<<<NB, 256, 0, stream>>>(ebuf, bbase, offsets, dinv, csr_s, N, ET);
    wcast     <<<(c4 + 255) / 256, 256, 0, stream>>>(W1, W2, Wg, Wl1, Wl2, (unsigned*)wb, c0, c1, c2, c3, c4);
    cast_scale8<<<(N * 32 + 255) / 256, 256, 0, stream>>>(x, dinv, x8, N * 32);

    // conv1 (fp8 gather tables): u = D^-1/2 x (quantized) ; a8 = D^-1 A u (fp8) ;
    // Bb = D^-1/2 A a8 = P^2 x (bf16) ; A = h1' = lrelu(Bb@W1+b1)*dinv
    prop8_kernel<<<pgp, 256, 0, stream>>>((const uint4*)x8, offsets, csr_s, dinv, 1, 1, a8, nullptr, N);
    prop8_kernel<<<pgp, 256, 0, stream>>>(a8, offsets, csr_s, dinv, 0, 0, nullptr, (uint4*)Bb, N);
    dim3 g1((N + 63) / 64, 2);
    gemm_mfma<<<g1, 256, 0, stream>>>(Bb, W1b, b1, A, dinv, nullptr, nullptr, nullptr, nullptr,
                                      N, 128, 128, 0.1f, 1);
    // conv2 (fp8 gather tables): quantize h1' then the same two-hop pipeline
    cast_bf2fp8<<<(N * 32 + 255) / 256, 256, 0, stream>>>((const uint2*)A, x8, N * 32);
    prop8_kernel<<<pgp, 256, 0, stream>>>((const uint4*)x8, offsets, csr_s, dinv, 1, 1, a8, nullptr, N);
    prop8_kernel<<<pgp, 256, 0, stream>>>(a8, offsets, csr_s, dinv, 0, 0, nullptr, (uint4*)A, N);
    gemm_mfma<<<g1, 256, 0, stream>>>(A, W2b, b2, Bb, nullptr, nullptr, nullptr, nullptr, nullptr,
                                      N, 128, 128, 0.1f, 1);
    // GAT: hg = h2 @ Wg with fused a_s/a_d row-dots, then attention aggregate
    dim3 g2((N + 63) / 64, 1);
    gemm_mfma<<<g2, 256, 0, stream>>>(Bb, Wgb, nullptr, A, nullptr, atts, attd, a_s, a_d,
                                      N, 128, 64, 0.f, 0);
    gat_agg <<<pgp, 256, 0, stream>>>((const uint4*)A, a_s, a_d, offsets, csr_s, bg, (uint4*)Bb, N);
    // MLP: Bb viewed as [Ng, 640] bf16
    dim3 g3((Ng + 63) / 64, 8);
    gemm_mfma<<<g3, 256, 0, stream>>>(Bb, Wl1b, bl1, A, nullptr, nullptr, nullptr, nullptr, nullptr,
                                      Ng, 640, 512, 0.1f, 1);
    dim3 g4((Ng + 63) / 64, 4);
    gemm_mfma<<<g4, 256, 0, stream>>>(A, Wl2b, bl2, Bb, nullptr, nullptr, nullptr, nullptr, nullptr,
                                      Ng, 512, 256, 0.1f, 1);
    final_gemm<<<(Ng * 8 + 255) / 256, 256, 0, stream>>>(Bb, Wl3, bl3, out, Ng);
}

// Round 7
// 475.683 us; speedup vs baseline: 1.3629x; 1.0901x over previous
//
#include <hip/hip_runtime.h>

typedef __attribute__((ext_vector_type(8))) short short8;
typedef __attribute__((ext_vector_type(8))) unsigned short ushort8;
typedef __attribute__((ext_vector_type(4))) float floatx4;
typedef __attribute__((ext_vector_type(2))) float floatx2;

#define NBQ  1024     // max buckets (N <= 131072 @ 128 nodes/bucket; packing needs N <= 2^17)
#define NBLK 128      // sort blocks

__device__ __forceinline__ float bf2f(unsigned short u) {
    union { unsigned u; float f; } v; v.u = ((unsigned)u) << 16; return v.f;
}
__device__ __forceinline__ float bflo(unsigned u) {
    union { unsigned u; float f; } v; v.u = u << 16; return v.f;
}
__device__ __forceinline__ float bfhi(unsigned u) {
    union { unsigned u; float f; } v; v.u = u & 0xFFFF0000u; return v.f;
}
__device__ __forceinline__ unsigned short f2bf(float f) {
    union { float f; unsigned u; } v; v.f = f;
    unsigned r = v.u + 0x7FFFu + ((v.u >> 16) & 1u);
    return (unsigned short)(r >> 16);
}
__device__ __forceinline__ unsigned pack2bf(float a, float b) {
    return (unsigned)f2bf(a) | ((unsigned)f2bf(b) << 16);
}
__device__ __forceinline__ float lrelu(float x, float s) { return x >= 0.f ? x : s * x; }

// fp8 e4m3 (OCP) hardware converts. The old/word builtin args must be INTEGER CONSTANT
// EXPRESSIONS -> macros with literals (an inline-function bool param fails to compile).
#define PK_FP8_LO(a, b, old) __builtin_amdgcn_cvt_pk_fp8_f32((a), (b), (old), false)
#define PK_FP8_HI(a, b, old) __builtin_amdgcn_cvt_pk_fp8_f32((a), (b), (old), true)
#define UPK_FP8_LO(u)        __builtin_amdgcn_cvt_pk_f32_fp8((int)(u), false)
#define UPK_FP8_HI(u)        __builtin_amdgcn_cvt_pk_f32_fp8((int)(u), true)

// fp32 -> fp8 e4m3 quads (4 feats / thread), pre-scaled by dinv[node] (128 feats = 32 uints/node)
__global__ __launch_bounds__(256) void cast_scale8(const float* __restrict__ in, const float* __restrict__ dinv,
                                                   unsigned* __restrict__ outp, int nquads) {
    int i = blockIdx.x * 256 + threadIdx.x;
    if (i < nquads) {
        float s = dinv[i >> 5];
        float4 v = *(const float4*)(in + 4 * (size_t)i);
        int w = PK_FP8_LO(v.x * s, v.y * s, 0);
        w = PK_FP8_HI(v.z * s, v.w * s, w);
        outp[i] = (unsigned)w;
    }
}

// bf16 -> fp8 e4m3 (4 feats / thread); converts h1' into a gather-friendly 128B-row table
__global__ __launch_bounds__(256) void cast_bf2fp8(const uint2* __restrict__ in, unsigned* __restrict__ outp,
                                                   int nquads) {
    int i = blockIdx.x * 256 + threadIdx.x;
    if (i < nquads) {
        uint2 v = in[i];
        int w = PK_FP8_LO(bflo(v.x), bfhi(v.x), 0);
        w = PK_FP8_HI(bflo(v.y), bfhi(v.y), w);
        outp[i] = (unsigned)w;
    }
}

// fp32 weights -> bf16 in MFMA FRAGMENT ORDER. Fragment f of a K x Nc matrix holds
// o[j] = W[kt*32 + q*8 + j][ntile*64 + wave*16 + r16], f = ((ntile*(K/32)+kt)*4+wave)*64+lane.
// The GEMM then loads each lane's B fragment with ONE coalesced ushort8 global read
// (L2-resident weights) -- no LDS staging, no transpose bank conflicts.
__global__ __launch_bounds__(256) void wcast_frag(const float* __restrict__ w0, const float* __restrict__ w1,
                                                  const float* __restrict__ w2, const float* __restrict__ w3,
                                                  const float* __restrict__ w4, unsigned short* __restrict__ outp,
                                                  int f1, int f2, int f3, int f4, int f5,
                                                  int e1, int e2, int e3, int e4,
                                                  int k1, int k2, int k3, int k4, int k5,
                                                  int n1, int n2, int n3, int n4, int n5) {
    int i = blockIdx.x * 256 + threadIdx.x;
    if (i >= f5) return;
    const float* W; int fb, eb, K, Nc;
    if      (i < f1) { W = w0; fb = 0;  eb = 0;  K = k1; Nc = n1; }
    else if (i < f2) { W = w1; fb = f1; eb = e1; K = k2; Nc = n2; }
    else if (i < f3) { W = w2; fb = f2; eb = e2; K = k3; Nc = n3; }
    else if (i < f4) { W = w3; fb = f3; eb = e3; K = k4; Nc = n4; }
    else             { W = w4; fb = f4; eb = e4; K = k5; Nc = n5; }
    int f = i - fb;
    int lane = f & 63;
    int wave = (f >> 6) & 3;
    int rest = f >> 8;
    int ks = K >> 5;
    int kt = rest % ks;
    int ntile = rest / ks;
    int q = lane >> 4, r16 = lane & 15;
    int n = ntile * 64 + wave * 16 + r16;
    int kb = kt * 32 + q * 8;
    ushort8 o;
#pragma unroll
    for (int j = 0; j < 8; ++j) o[j] = f2bf(W[(size_t)(kb + j) * Nc + n]);
    *(ushort8*)(outp + (size_t)eb + (size_t)f * 8) = o;
}

// ---- CSR build: two-phase counting sort (bucket = 128 dst nodes), no global atomics ----
__global__ __launch_bounds__(256) void hist_k(const int* __restrict__ dst, int* __restrict__ cnt,
                                              int e, int et, int nb) {
    __shared__ int h[NBQ];
    for (int i = threadIdx.x; i < nb; i += 256) h[i] = 0;
    __syncthreads();
    int chunk = (et + NBLK - 1) / NBLK;
    int c0 = blockIdx.x * chunk;
    int c1 = c0 + chunk < et ? c0 + chunk : et;
    for (int i = c0 + (int)threadIdx.x; i < c1; i += 256) {
        int d = (i < e) ? dst[i] : (i - e);
        atomicAdd(&h[d >> 7], 1);
    }
    __syncthreads();
    for (int i = threadIdx.x; i < nb; i += 256) cnt[blockIdx.x * NBQ + i] = h[i];
}

__global__ __launch_bounds__(256) void btot_k(const int* __restrict__ cnt, int* __restrict__ btot, int nb) {
    int b = blockIdx.x * 256 + threadIdx.x;
    if (b >= nb) return;
    int s = 0;
    for (int blk = 0; blk < NBLK; ++blk) s += cnt[blk * NBQ + b];
    btot[b] = s;
}

__global__ __launch_bounds__(256) void bscan_k(const int* __restrict__ btot, int* __restrict__ bbase,
                                               int nb, int et) {
    __shared__ int sd[256];
    int t = threadIdx.x;
    int i0 = t * 4;
    int loc[4]; int s = 0;
    for (int j = 0; j < 4; ++j) { int i = i0 + j; loc[j] = (i < nb) ? btot[i] : 0; s += loc[j]; }
    sd[t] = s; __syncthreads();
    for (int off = 1; off < 256; off <<= 1) {
        int v = (t >= off) ? sd[t - off] : 0;
        __syncthreads();
        sd[t] += v;
        __syncthreads();
    }
    int run = sd[t] - s;
    for (int j = 0; j < 4; ++j) {
        int i = i0 + j;
        if (i < nb) { bbase[i] = run; run += loc[j]; }
    }
    if (t == 255) bbase[nb] = et;
}

__global__ __launch_bounds__(256) void scan_cnt(int* __restrict__ cnt, const int* __restrict__ bbase,
                                                int nb) {
    int b = blockIdx.x * 256 + threadIdx.x;
    if (b >= nb) return;
    int base = bbase[b];
    for (int blk = 0; blk < NBLK; ++blk) {
        int* p = &cnt[blk * NBQ + b];
        int t = *p; *p = base; base += t;
    }
}

// scatter packed entries: s (17 bits, N <= 131072) | (d&127) << 17 — 4B/edge
__global__ __launch_bounds__(256) void scatter_k(const int* __restrict__ src, const int* __restrict__ dst,
                                                 const int* __restrict__ cnt,
                                                 int* __restrict__ ebuf, int e, int et, int nb) {
    __shared__ int cur[NBQ];
    for (int i = threadIdx.x; i < nb; i += 256) cur[i] = cnt[blockIdx.x * NBQ + i];
    __syncthreads();
    int chunk = (et + NBLK - 1) / NBLK;
    int c0 = blockIdx.x * chunk;
    int c1 = c0 + chunk < et ? c0 + chunk : et;
    for (int i = c0 + (int)threadIdx.x; i < c1; i += 256) {
        int s, d;
        if (i < e) { s = src[i]; d = dst[i]; }
        else       { s = d = i - e; }            // self loop
        int pos = atomicAdd(&cur[d >> 7], 1);
        ebuf[pos] = s | ((d & 127) << 17);
    }
}

// fused: per-bucket degree count + scan -> offsets/dinv, then node-granular CSR
// placement with LDS cursors (ebuf segment stays L2-hot between the two passes)
__global__ __launch_bounds__(256) void finalize_k(const int* __restrict__ ebuf, const int* __restrict__ bbase,
                                                  int* __restrict__ offsets, float* __restrict__ dinv,
                                                  int* __restrict__ csr_s, int n, int et) {
    __shared__ int ldeg[128];
    __shared__ int lscan[128];
    __shared__ int cur[128];
    int b = blockIdx.x;
    int n0 = b << 7;
    if (threadIdx.x < 128) ldeg[threadIdx.x] = 0;
    __syncthreads();
    int e0 = bbase[b], e1 = bbase[b + 1];
    for (int i = e0 + (int)threadIdx.x; i < e1; i += 256)
        atomicAdd(&ldeg[(ebuf[i] >> 17) & 127], 1);
    __syncthreads();
    if (threadIdx.x < 128) lscan[threadIdx.x] = ldeg[threadIdx.x];
    __syncthreads();
    for (int off = 1; off < 128; off <<= 1) {
        int v = 0;
        if (threadIdx.x < 128 && (int)threadIdx.x >= off) v = lscan[threadIdx.x - off];
        __syncthreads();
        if (threadIdx.x < 128) lscan[threadIdx.x] += v;
        __syncthreads();
    }
    if (threadIdx.x < 128) {
        int base = e0 + lscan[threadIdx.x] - ldeg[threadIdx.x];   // exclusive
        cur[threadIdx.x] = base;
        int node = n0 + threadIdx.x;
        if (node < n) {
            offsets[node] = base;
            dinv[node] = rsqrtf((float)ldeg[threadIdx.x]);         // deg >= 1 (self loop)
        }
    }
    if (b == 0 && threadIdx.x == 0) offsets[n] = et;
    __syncthreads();
    for (int i = e0 + (int)threadIdx.x; i < e1; i += 256) {
        int ent = ebuf[i];
        int pos = atomicAdd(&cur[(ent >> 17) & 127], 1);
        csr_s[pos] = ent & 0x1FFFF;
    }
}

// ---------------- propagation (fp8 e4m3 table, 128B rows = 8 x uint4) ----------------
// out[d] = scale(d) * sum_{s in N(d)} x[s]; f32 accumulate (only storage is quantized).
// Lane-group-per-node: 8 lanes own one node's full row (16 feats/lane as f32 accs),
// iterate its edge list sequentially (2-deep unroll). No cross-lane reduce epilogue.
// out8f: 1 -> write fp8 table (next hop's gather), 0 -> write bf16 rows (MFMA GEMM input).

#define ACC16F(u) { floatx2 t0_ = UPK_FP8_LO((u).x), t1_ = UPK_FP8_HI((u).x); \
                    a[0] += t0_.x; a[1] += t0_.y; a[2] += t1_.x; a[3] += t1_.y; \
                    t0_ = UPK_FP8_LO((u).y); t1_ = UPK_FP8_HI((u).y); \
                    a[4] += t0_.x; a[5] += t0_.y; a[6] += t1_.x; a[7] += t1_.y; \
                    t0_ = UPK_FP8_LO((u).z); t1_ = UPK_FP8_HI((u).z); \
                    a[8] += t0_.x; a[9] += t0_.y; a[10] += t1_.x; a[11] += t1_.y; \
                    t0_ = UPK_FP8_LO((u).w); t1_ = UPK_FP8_HI((u).w); \
                    a[12] += t0_.x; a[13] += t0_.y; a[14] += t1_.x; a[15] += t1_.y; }

__global__ __launch_bounds__(256) void prop8_kernel(const uint4* __restrict__ xin, const int* __restrict__ offs,
                                                    const int* __restrict__ csr_s, const float* __restrict__ dinv,
                                                    int sq, int out8f, uint4* __restrict__ out8,
                                                    uint4* __restrict__ out16, int n) {
    int node = blockIdx.x * 32 + (threadIdx.x >> 3);
    if (node >= n) return;
    int li = threadIdx.x & 7;      // uint4 index within 8-uint4 (128B) fp8 row; feats li*16..+15
    int beg = offs[node], end = offs[node + 1];
    float a[16];
#pragma unroll
    for (int j = 0; j < 16; ++j) a[j] = 0.f;
    int e = beg;
    for (; e + 1 < end; e += 2) {
        int s0 = csr_s[e];
        int s1 = csr_s[e + 1];
        uint4 u0 = xin[(size_t)s0 * 8 + li];
        uint4 u1 = xin[(size_t)s1 * 8 + li];
        ACC16F(u0); ACC16F(u1);
    }
    if (e < end) {
        int s = csr_s[e];
        uint4 u = xin[(size_t)s * 8 + li];
        ACC16F(u);
    }
    float f = dinv[node];
    if (sq) f *= f;
    if (out8f) {
        int w0 = PK_FP8_LO(a[0] * f, a[1] * f, 0);   w0 = PK_FP8_HI(a[2] * f, a[3] * f, w0);
        int w1 = PK_FP8_LO(a[4] * f, a[5] * f, 0);   w1 = PK_FP8_HI(a[6] * f, a[7] * f, w1);
        int w2 = PK_FP8_LO(a[8] * f, a[9] * f, 0);   w2 = PK_FP8_HI(a[10] * f, a[11] * f, w2);
        int w3 = PK_FP8_LO(a[12] * f, a[13] * f, 0); w3 = PK_FP8_HI(a[14] * f, a[15] * f, w3);
        uint4 o; o.x = (unsigned)w0; o.y = (unsigned)w1; o.z = (unsigned)w2; o.w = (unsigned)w3;
        out8[(size_t)node * 8 + li] = o;
    } else {
        uint4 o1, o2;
        o1.x = pack2bf(a[0] * f, a[1] * f);   o1.y = pack2bf(a[2] * f, a[3] * f);
        o1.z = pack2bf(a[4] * f, a[5] * f);   o1.w = pack2bf(a[6] * f, a[7] * f);
        o2.x = pack2bf(a[8] * f, a[9] * f);   o2.y = pack2bf(a[10] * f, a[11] * f);
        o2.z = pack2bf(a[12] * f, a[13] * f); o2.w = pack2bf(a[14] * f, a[15] * f);
        out16[(size_t)node * 16 + li * 2]     = o1;
        out16[(size_t)node * 16 + li * 2 + 1] = o2;
    }
}

// ---------------- MFMA GEMM: C[M,Nc] = act(A[M,K] @ Bfrag + bias) [* oscale] ----------------
// NT = 64-col tiles per block (compile-time). B is pre-swizzled fragment-major (wcast_frag):
// each lane's B operand is ONE coalesced ushort8 global load (L2-hot weights) -- no B LDS,
// no transpose bank conflicts. A tile double-buffered in LDS -> single barrier per k-step.
// Optional fused per-row att dots only in the NT==1 instantiation (Nc==64, gridDim.y==1).

template<int NT>
__global__ __launch_bounds__(256) void gemm_mfma(const unsigned short* __restrict__ A,
                                                 const unsigned short* __restrict__ Bf,
                                                 const float* __restrict__ bias, unsigned short* __restrict__ C,
                                                 const float* __restrict__ oscale,
                                                 const float* __restrict__ attS, const float* __restrict__ attD,
                                                 float* __restrict__ oas, float* __restrict__ oad,
                                                 int M, int K, int Nc, float slope, int act) {
    __shared__ __align__(16) unsigned short As[2][64 * 40];
    const int tid  = threadIdx.x;
    const int wave = tid >> 6;
    const int lane = tid & 63;
    const int q    = lane >> 4;
    const int r16  = lane & 15;
    const int m0 = blockIdx.x * 64;
    const int ksteps = K >> 5;

    floatx4 acc[NT][4];
#pragma unroll
    for (int nt = 0; nt < NT; ++nt)
#pragma unroll
        for (int ms = 0; ms < 4; ++ms) acc[nt][ms] = floatx4{0.f, 0.f, 0.f, 0.f};

    const int am = tid >> 2;         // 0..63 (tile row)
    const int ak = (tid & 3) * 8;    // 0..24
    const int gm = m0 + am;

    ushort8 sva;
    if (gm < M) sva = *(const ushort8*)(A + (size_t)gm * K + ak);
    else        for (int j = 0; j < 8; ++j) sva[j] = 0;

    const unsigned short* bbase = Bf + ((size_t)wave * 64 + lane) * 8;

    for (int kt = 0; kt < ksteps; ++kt) {
        unsigned short* as = As[kt & 1];
        *(ushort8*)(&as[am * 40 + ak]) = sva;
        __syncthreads();
        if (kt + 1 < ksteps) {
            if (gm < M) sva = *(const ushort8*)(A + (size_t)gm * K + (kt + 1) * 32 + ak);
        }
        short8 bf[NT];
#pragma unroll
        for (int nt = 0; nt < NT; ++nt) {
            int ntg = blockIdx.y * NT + nt;
            bf[nt] = *(const short8*)(bbase + (size_t)(ntg * ksteps + kt) * 2048);
        }
        short8 a0 = *(const short8*)(&as[(r16) * 40 + q * 8]);
        short8 a1 = *(const short8*)(&as[(16 + r16) * 40 + q * 8]);
        short8 a2 = *(const short8*)(&as[(32 + r16) * 40 + q * 8]);
        short8 a3 = *(const short8*)(&as[(48 + r16) * 40 + q * 8]);
#pragma unroll
        for (int nt = 0; nt < NT; ++nt) {
            acc[nt][0] = __builtin_amdgcn_mfma_f32_16x16x32_bf16(a0, bf[nt], acc[nt][0], 0, 0, 0);
            acc[nt][1] = __builtin_amdgcn_mfma_f32_16x16x32_bf16(a1, bf[nt], acc[nt][1], 0, 0, 0);
            acc[nt][2] = __builtin_amdgcn_mfma_f32_16x16x32_bf16(a2, bf[nt], acc[nt][2], 0, 0, 0);
            acc[nt][3] = __builtin_amdgcn_mfma_f32_16x16x32_bf16(a3, bf[nt], acc[nt][3], 0, 0, 0);
        }
        // no trailing barrier: next iteration writes the OTHER As buffer; its barrier
        // orders this iteration's reads before the overwrite two steps later.
    }
    // epilogue: C/D layout col=lane&15, row=(lane>>4)*4+reg
    if constexpr (NT == 1) {
        int cn = blockIdx.y * 64 + wave * 16 + r16;
        float bv = bias ? bias[cn] : 0.f;
        float ps[16], pd[16];
        float avs = attS ? attS[cn] : 0.f;
        float avd = attS ? attD[cn] : 0.f;
        for (int ms = 0; ms < 4; ++ms)
            for (int rr = 0; rr < 4; ++rr) {
                int cm = m0 + ms * 16 + q * 4 + rr;
                float v = acc[0][ms][rr] + bv;
                if (act) v = lrelu(v, slope);
                if (oscale && cm < M) v *= oscale[cm];
                if (cm < M) C[(size_t)cm * Nc + cn] = f2bf(v);
                ps[ms * 4 + rr] = v * avs;
                pd[ms * 4 + rr] = v * avd;
            }
        if (attS) {
            // reduce over the 16 cols held by this wave's q-group (lanes aligned 16)
            for (int off = 1; off < 16; off <<= 1)
#pragma unroll
                for (int i = 0; i < 16; ++i) {
                    ps[i] += __shfl_xor(ps[i], off, 64);
                    pd[i] += __shfl_xor(pd[i], off, 64);
                }
            __syncthreads();                      // all main-loop LDS reads done
            float* sd = (float*)As[0];
            if (tid < 128) sd[tid] = 0.f;
            __syncthreads();
            if (r16 == 0) {
#pragma unroll
                for (int i = 0; i < 16; ++i) {
                    int row = (i >> 2) * 16 + q * 4 + (i & 3);
                    atomicAdd(&sd[row], ps[i]);
                    atomicAdd(&sd[64 + row], pd[i]);
                }
            }
            __syncthreads();
            if (tid < 64 && m0 + tid < M) {
                oas[m0 + tid] = sd[tid];
                oad[m0 + tid] = sd[64 + tid];
            }
        }
    } else {
#pragma unroll
        for (int nt = 0; nt < NT; ++nt) {
            int cn = blockIdx.y * (NT * 64) + nt * 64 + wave * 16 + r16;
            float bv = bias ? bias[cn] : 0.f;
#pragma unroll
            for (int ms = 0; ms < 4; ++ms)
#pragma unroll
                for (int rr = 0; rr < 4; ++rr) {
                    int cm = m0 + ms * 16 + q * 4 + rr;
                    float v = acc[nt][ms][rr] + bv;
                    if (act) v = lrelu(v, slope);
                    if (oscale && cm < M) v *= oscale[cm];
                    if (cm < M) C[(size_t)cm * Nc + cn] = f2bf(v);
                }
        }
    }
}

// ---------------- GAT ----------------
// Lane-group-per-node: 8 lanes own one node's 64-feat bf16 row (8 feats/lane).
// Per edge: group-uniform csr/a_s loads (HW broadcast), redundant exp per lane,
// FMA into lane-local accs. No shuffles at all. 8 nodes/wave, 2-deep unroll.
// No segment-max pass: e = lrelu(a_s+a_d) is O(1..10) << 88, exp(e) fp32-safe; shift cancels.
__global__ __launch_bounds__(256) void gat_agg(const uint4* __restrict__ hg, const float* __restrict__ a_s,
                                               const float* __restrict__ a_d, const int* __restrict__ offs,
                                               const int* __restrict__ csr_s, const float* __restrict__ bg,
                                               uint4* __restrict__ out, int n) {
    int node = blockIdx.x * 32 + (threadIdx.x >> 3);
    if (node >= n) return;
    int li = threadIdx.x & 7;      // uint4 index within 8-uint4 (128B) bf16 row
    int beg = offs[node], end = offs[node + 1];
    float ad = a_d[node];
    float a0=0.f,a1=0.f,a2=0.f,a3=0.f,a4=0.f,a5=0.f,a6=0.f,a7=0.f, ssum=0.f;
    int e = beg;
    for (; e + 1 < end; e += 2) {
        int s0 = csr_s[e];
        int s1 = csr_s[e + 1];
        float t0 = a_s[s0] + ad;
        float t1 = a_s[s1] + ad;
        uint4 u0 = hg[(size_t)s0 * 8 + li];
        uint4 u1 = hg[(size_t)s1 * 8 + li];
        t0 = t0 < 0.f ? 0.2f * t0 : t0;
        t1 = t1 < 0.f ? 0.2f * t1 : t1;
        float w0 = __expf(t0);
        float w1 = __expf(t1);
        ssum += w0 + w1;
        a0 = fmaf(w0, bflo(u0.x), a0); a1 = fmaf(w0, bfhi(u0.x), a1);
        a2 = fmaf(w0, bflo(u0.y), a2); a3 = fmaf(w0, bfhi(u0.y), a3);
        a4 = fmaf(w0, bflo(u0.z), a4); a5 = fmaf(w0, bfhi(u0.z), a5);
        a6 = fmaf(w0, bflo(u0.w), a6); a7 = fmaf(w0, bfhi(u0.w), a7);
        a0 = fmaf(w1, bflo(u1.x), a0); a1 = fmaf(w1, bfhi(u1.x), a1);
        a2 = fmaf(w1, bflo(u1.y), a2); a3 = fmaf(w1, bfhi(u1.y), a3);
        a4 = fmaf(w1, bflo(u1.z), a4); a5 = fmaf(w1, bfhi(u1.z), a5);
        a6 = fmaf(w1, bflo(u1.w), a6); a7 = fmaf(w1, bfhi(u1.w), a7);
    }
    if (e < end) {
        int s0 = csr_s[e];
        float t0 = a_s[s0] + ad;
        uint4 u0 = hg[(size_t)s0 * 8 + li];
        t0 = t0 < 0.f ? 0.2f * t0 : t0;
        float w0 = __expf(t0);
        ssum += w0;
        a0 = fmaf(w0, bflo(u0.x), a0); a1 = fmaf(w0, bfhi(u0.x), a1);
        a2 = fmaf(w0, bflo(u0.y), a2); a3 = fmaf(w0, bfhi(u0.y), a3);
        a4 = fmaf(w0, bflo(u0.z), a4); a5 = fmaf(w0, bfhi(u0.z), a5);
        a6 = fmaf(w0, bflo(u0.w), a6); a7 = fmaf(w0, bfhi(u0.w), a7);
    }
    float inv = 1.0f / ssum;
    int f0 = li * 8;
    uint4 o;
    o.x = pack2bf(lrelu(a0 * inv + bg[f0 + 0], 0.1f), lrelu(a1 * inv + bg[f0 + 1], 0.1f));
    o.y = pack2bf(lrelu(a2 * inv + bg[f0 + 2], 0.1f), lrelu(a3 * inv + bg[f0 + 3], 0.1f));
    o.z = pack2bf(lrelu(a4 * inv + bg[f0 + 4], 0.1f), lrelu(a5 * inv + bg[f0 + 5], 0.1f));
    o.w = pack2bf(lrelu(a6 * inv + bg[f0 + 6], 0.1f), lrelu(a7 * inv + bg[f0 + 7], 0.1f));
    out[(size_t)node * 8 + li] = o;
}

// ---------------- final small GEMM [Ng,256]@[256,8] + bias -> fp32 ----------------

__global__ __launch_bounds__(256) void final_gemm(const unsigned short* __restrict__ m2, const float* __restrict__ W3,
                                                  const float* __restrict__ b3,
                                                  float* __restrict__ out, int ng) {
    int idx = blockIdx.x * 256 + threadIdx.x;
    if (idx >= ng * 8) return;
    int r = idx >> 3, c = idx & 7;
    float acc = b3[c];
    const unsigned short* row = m2 + (size_t)r * 256;
    for (int k = 0; k < 256; ++k) acc = fmaf(bf2f(row[k]), W3[k * 8 + c], acc);
    out[idx] = acc;
}

// ---------------- launch ----------------

extern "C" void kernel_launch(void* const* d_in, const int* in_sizes, int n_in,
                              void* d_out, int out_size, void* d_ws, size_t ws_size,
                              hipStream_t stream) {
    const int N  = in_sizes[0] / 128;
    const int E  = in_sizes[1] / 2;
    const int ET = E + N;
    const int Ng = N / 10;
    const int NB = (N + 127) / 128;   // dst buckets (<= NBQ)

    const float* x    = (const float*)d_in[0];
    const int*   src  = (const int*)d_in[1];
    const int*   dst  = src + E;
    const float* W1   = (const float*)d_in[2];
    const float* b1   = (const float*)d_in[3];
    const float* W2   = (const float*)d_in[4];
    const float* b2   = (const float*)d_in[5];
    const float* Wg   = (const float*)d_in[6];
    const float* atts = (const float*)d_in[7];
    const float* attd = (const float*)d_in[8];
    const float* bg   = (const float*)d_in[9];
    const float* Wl1  = (const float*)d_in[10];
    const float* bl1  = (const float*)d_in[11];
    const float* Wl2  = (const float*)d_in[12];
    const float* bl2  = (const float*)d_in[13];
    const float* Wl3  = (const float*)d_in[14];
    const float* bl3  = (const float*)d_in[15];
    float* out = (float*)d_out;

    // weight dims — in_sizes are ELEMENT counts (fp32 elems), NOT bytes
    const int K1 = 128,     N1 = in_sizes[2]  / K1;   // 128
    const int K2 = N1,      N2 = in_sizes[4]  / K2;   // 128
    const int K3 = N2,      N3 = in_sizes[6]  / K3;   // 64
    const int K4 = 10 * N3, N4 = in_sizes[10] / K4;   // 512
    const int K5 = N4,      N5 = in_sizes[12] / K5;   // 256
    // fragment-count prefix (8 elems / fragment) and elem offsets into wb
    const int F1 = K1 * N1 / 8,      F2 = F1 + K2 * N2 / 8, F3 = F2 + K3 * N3 / 8;
    const int F4 = F3 + K4 * N4 / 8, F5 = F4 + K5 * N5 / 8;
    const int E1 = K1 * N1, E2 = E1 + K2 * N2, E3 = E2 + K3 * N3, E4 = E3 + K4 * N4;
    const int ET5 = E4 + K5 * N5;   // total bf16 elems

    // workspace carve (all feature buffers bf16, 16B-aligned rows)
    char* p = (char*)d_ws;
    auto alloc = [&](size_t bytes) { char* r = p; p += (bytes + 255) & ~(size_t)255; return r; };
    unsigned short* xb = (unsigned short*)alloc((size_t)N * 128 * 2);
    unsigned short* A  = (unsigned short*)alloc((size_t)N * 128 * 2);
    unsigned short* Bb = (unsigned short*)alloc((size_t)N * 128 * 2);
    int*   csr_s   = (int*)  alloc((size_t)ET * 4);
    int*   cnt     = (int*)  alloc((size_t)NBLK * NBQ * 4);
    int*   btot    = (int*)  alloc((size_t)(NBQ + 1) * 4);
    int*   bbase   = (int*)  alloc((size_t)(NBQ + 1) * 4);
    float* dinv    = (float*)alloc((size_t)N * 4);
    int*   offsets = (int*)  alloc((size_t)(N + 1) * 4);
    float* a_s     = (float*)alloc((size_t)N * 4);
    float* a_d     = (float*)alloc((size_t)N * 4);
    unsigned short* wb = (unsigned short*)alloc((size_t)ET5 * 2);  // fragment-major bf16 weights
    // ebuf (packed src|dlow, ET*4 bytes) aliases Bb; lifetime ends before Bb's first write.
    int*   ebuf    = (int*)Bb;
    // fp8 tables (each N*128 bytes = half of xb); reused by conv1 then conv2
    unsigned* x8 = (unsigned*)xb;                       // quantized gather input table
    uint4*    a8 = (uint4*)(xb + (size_t)N * 64);       // hop-1 output, fp8

    const unsigned short* W1b  = wb;
    const unsigned short* W2b  = wb + E1;
    const unsigned short* Wgb  = wb + E2;
    const unsigned short* Wl1b = wb + E3;
    const unsigned short* Wl2b = wb + E4;

    const int pgp = (N + 31) / 32;    // lane-group kernels: 8 nodes/wave, 32/block

    hist_k    <<<NBLK, 256, 0, stream>>>(dst, cnt, E, ET, NB);
    btot_k    <<<(NB + 255) / 256, 256, 0, stream>>>(cnt, btot, NB);
    bscan_k   <<<1, 256, 0, stream>>>(btot, bbase, NB, ET);
    scan_cnt  <<<(NB + 255) / 256, 256, 0, stream>>>(cnt, bbase, NB);
    scatter_k <<<NBLK, 256, 0, stream>>>(src, dst, cnt, ebuf, E, ET, NB);
    finalize_k<<<NB, 256, 0, stream>>>(ebuf, bbase, offsets, dinv, csr_s, N, ET);
    wcast_frag<<<(F5 + 255) / 256, 256, 0, stream>>>(W1, W2, Wg, Wl1, Wl2, wb,
                                                     F1, F2, F3, F4, F5, E1, E2, E3, E4,
                                                     K1, K2, K3, K4, K5, N1, N2, N3, N4, N5);
    cast_scale8<<<(N * 32 + 255) / 256, 256, 0, stream>>>(x, dinv, x8, N * 32);

    // conv1 (fp8 gather tables): u = D^-1/2 x (quantized) ; a8 = D^-1 A u (fp8) ;
    // Bb = D^-1/2 A a8 = P^2 x (bf16) ; A = h1' = lrelu(Bb@W1+b1)*dinv
    prop8_kernel<<<pgp, 256, 0, stream>>>((const uint4*)x8, offsets, csr_s, dinv, 1, 1, a8, nullptr, N);
    prop8_kernel<<<pgp, 256, 0, stream>>>(a8, offsets, csr_s, dinv, 0, 0, nullptr, (uint4*)Bb, N);
    dim3 g1((N + 63) / 64, 1);
    gemm_mfma<2><<<g1, 256, 0, stream>>>(Bb, W1b, b1, A, dinv, nullptr, nullptr, nullptr, nullptr,
                                         N, 128, 128, 0.1f, 1);
    // conv2 (fp8 gather tables): quantize h1' then the same two-hop pipeline
    cast_bf2fp8<<<(N * 32 + 255) / 256, 256, 0, stream>>>((const uint2*)A, x8, N * 32);
    prop8_kernel<<<pgp, 256, 0, stream>>>((const uint4*)x8, offsets, csr_s, dinv, 1, 1, a8, nullptr, N);
    prop8_kernel<<<pgp, 256, 0, stream>>>(a8, offsets, csr_s, dinv, 0, 0, nullptr, (uint4*)A, N);
    gemm_mfma<2><<<g1, 256, 0, stream>>>(A, W2b, b2, Bb, nullptr, nullptr, nullptr, nullptr, nullptr,
                                         N, 128, 128, 0.1f, 1);
    // GAT: hg = h2 @ Wg with fused a_s/a_d row-dots, then attention aggregate
    dim3 g2((N + 63) / 64, 1);
    gemm_mfma<1><<<g2, 256, 0, stream>>>(Bb, Wgb, nullptr, A, nullptr, atts, attd, a_s, a_d,
                                         N, 128, 64, 0.f, 0);
    gat_agg <<<pgp, 256, 0, stream>>>((const uint4*)A, a_s, a_d, offsets, csr_s, bg, (uint4*)Bb, N);
    // MLP: Bb viewed as [Ng, 640] bf16
    dim3 g3((Ng + 63) / 64, 4);
    gemm_mfma<2><<<g3, 256, 0, stream>>>(Bb, Wl1b, bl1, A, nullptr, nullptr, nullptr, nullptr, nullptr,
                                         Ng, 640, 512, 0.1f, 1);
    dim3 g4((Ng + 63) / 64, 2);
    gemm_mfma<2><<<g4, 256, 0, stream>>>(A, Wl2b, bl2, Bb, nullptr, nullptr, nullptr, nullptr, nullptr,
                                         Ng, 512, 256, 0.1f, 1);
    final_gemm<<<(Ng * 8 + 255) / 256, 256, 0, stream>>>(Bb, Wl3, bl3, out, Ng);
}

// Round 9
// 473.171 us; speedup vs baseline: 1.3701x; 1.0053x over previous
//
#include <hip/hip_runtime.h>

typedef __attribute__((ext_vector_type(8))) short short8;
typedef __attribute__((ext_vector_type(8))) unsigned short ushort8;
typedef __attribute__((ext_vector_type(4))) float floatx4;
typedef __attribute__((ext_vector_type(2))) float floatx2;

#define NBQ  1024     // max buckets (N <= 131072 @ 128 nodes/bucket; packing needs N <= 2^17)
#define NBLK 128      // sort blocks

__device__ __forceinline__ float bf2f(unsigned short u) {
    union { unsigned u; float f; } v; v.u = ((unsigned)u) << 16; return v.f;
}
__device__ __forceinline__ float bflo(unsigned u) {
    union { unsigned u; float f; } v; v.u = u << 16; return v.f;
}
__device__ __forceinline__ float bfhi(unsigned u) {
    union { unsigned u; float f; } v; v.u = u & 0xFFFF0000u; return v.f;
}
__device__ __forceinline__ unsigned short f2bf(float f) {
    union { float f; unsigned u; } v; v.f = f;
    unsigned r = v.u + 0x7FFFu + ((v.u >> 16) & 1u);
    return (unsigned short)(r >> 16);
}
__device__ __forceinline__ unsigned pack2bf(float a, float b) {
    return (unsigned)f2bf(a) | ((unsigned)f2bf(b) << 16);
}
__device__ __forceinline__ float lrelu(float x, float s) { return x >= 0.f ? x : s * x; }

// fp8 e4m3 (OCP) hardware converts. The old/word builtin args must be INTEGER CONSTANT
// EXPRESSIONS -> macros with literals (an inline-function bool param fails to compile).
#define PK_FP8_LO(a, b, old) __builtin_amdgcn_cvt_pk_fp8_f32((a), (b), (old), false)
#define PK_FP8_HI(a, b, old) __builtin_amdgcn_cvt_pk_fp8_f32((a), (b), (old), true)
#define UPK_FP8_LO(u)        __builtin_amdgcn_cvt_pk_f32_fp8((int)(u), false)
#define UPK_FP8_HI(u)        __builtin_amdgcn_cvt_pk_f32_fp8((int)(u), true)

// fp32 -> fp8 e4m3 quads (4 feats / thread), pre-scaled by dinv[node] (128 feats = 32 uints/node)
__global__ __launch_bounds__(256) void cast_scale8(const float* __restrict__ in, const float* __restrict__ dinv,
                                                   unsigned* __restrict__ outp, int nquads) {
    int i = blockIdx.x * 256 + threadIdx.x;
    if (i < nquads) {
        float s = dinv[i >> 5];
        float4 v = *(const float4*)(in + 4 * (size_t)i);
        int w = PK_FP8_LO(v.x * s, v.y * s, 0);
        w = PK_FP8_HI(v.z * s, v.w * s, w);
        outp[i] = (unsigned)w;
    }
}

// bf16 -> fp8 e4m3 (4 feats / thread); converts h1' into a gather-friendly 128B-row table
__global__ __launch_bounds__(256) void cast_bf2fp8(const uint2* __restrict__ in, unsigned* __restrict__ outp,
                                                   int nquads) {
    int i = blockIdx.x * 256 + threadIdx.x;
    if (i < nquads) {
        uint2 v = in[i];
        int w = PK_FP8_LO(bflo(v.x), bfhi(v.x), 0);
        w = PK_FP8_HI(bflo(v.y), bfhi(v.y), w);
        outp[i] = (unsigned)w;
    }
}

// fp32 weights -> bf16 in MFMA FRAGMENT ORDER. Fragment f of a K x Nc matrix holds
// o[j] = W[kt*32 + q*8 + j][ntile*64 + wave*16 + r16], f = ((ntile*(K/32)+kt)*4+wave)*64+lane.
// The GEMM then loads each lane's B fragment with ONE coalesced ushort8 global read
// (L2-resident weights) -- no LDS staging, no transpose bank conflicts.
__global__ __launch_bounds__(256) void wcast_frag(const float* __restrict__ w0, const float* __restrict__ w1,
                                                  const float* __restrict__ w2, const float* __restrict__ w3,
                                                  const float* __restrict__ w4, unsigned short* __restrict__ outp,
                                                  int f1, int f2, int f3, int f4, int f5,
                                                  int e1, int e2, int e3, int e4,
                                                  int k1, int k2, int k3, int k4, int k5,
                                                  int n1, int n2, int n3, int n4, int n5) {
    int i = blockIdx.x * 256 + threadIdx.x;
    if (i >= f5) return;
    const float* W; int fb, eb, K, Nc;
    if      (i < f1) { W = w0; fb = 0;  eb = 0;  K = k1; Nc = n1; }
    else if (i < f2) { W = w1; fb = f1; eb = e1; K = k2; Nc = n2; }
    else if (i < f3) { W = w2; fb = f2; eb = e2; K = k3; Nc = n3; }
    else if (i < f4) { W = w3; fb = f3; eb = e3; K = k4; Nc = n4; }
    else             { W = w4; fb = f4; eb = e4; K = k5; Nc = n5; }
    int f = i - fb;
    int lane = f & 63;
    int wave = (f >> 6) & 3;
    int rest = f >> 8;
    int ks = K >> 5;
    int kt = rest % ks;
    int ntile = rest / ks;
    int q = lane >> 4, r16 = lane & 15;
    int n = ntile * 64 + wave * 16 + r16;
    int kb = kt * 32 + q * 8;
    ushort8 o;
#pragma unroll
    for (int j = 0; j < 8; ++j) o[j] = f2bf(W[(size_t)(kb + j) * Nc + n]);
    *(ushort8*)(outp + (size_t)eb + (size_t)f * 8) = o;
}

// ---- CSR build: two-phase counting sort (bucket = 128 dst nodes), no global atomics ----
__global__ __launch_bounds__(256) void hist_k(const int* __restrict__ dst, int* __restrict__ cnt,
                                              int e, int et, int nb) {
    __shared__ int h[NBQ];
    for (int i = threadIdx.x; i < nb; i += 256) h[i] = 0;
    __syncthreads();
    int chunk = (et + NBLK - 1) / NBLK;
    int c0 = blockIdx.x * chunk;
    int c1 = c0 + chunk < et ? c0 + chunk : et;
    for (int i = c0 + (int)threadIdx.x; i < c1; i += 256) {
        int d = (i < e) ? dst[i] : (i - e);
        atomicAdd(&h[d >> 7], 1);
    }
    __syncthreads();
    for (int i = threadIdx.x; i < nb; i += 256) cnt[blockIdx.x * NBQ + i] = h[i];
}

__global__ __launch_bounds__(256) void btot_k(const int* __restrict__ cnt, int* __restrict__ btot, int nb) {
    int b = blockIdx.x * 256 + threadIdx.x;
    if (b >= nb) return;
    int s = 0;
    for (int blk = 0; blk < NBLK; ++blk) s += cnt[blk * NBQ + b];
    btot[b] = s;
}

__global__ __launch_bounds__(256) void bscan_k(const int* __restrict__ btot, int* __restrict__ bbase,
                                               int nb, int et) {
    __shared__ int sd[256];
    int t = threadIdx.x;
    int i0 = t * 4;
    int loc[4]; int s = 0;
    for (int j = 0; j < 4; ++j) { int i = i0 + j; loc[j] = (i < nb) ? btot[i] : 0; s += loc[j]; }
    sd[t] = s; __syncthreads();
    for (int off = 1; off < 256; off <<= 1) {
        int v = (t >= off) ? sd[t - off] : 0;
        __syncthreads();
        sd[t] += v;
        __syncthreads();
    }
    int run = sd[t] - s;
    for (int j = 0; j < 4; ++j) {
        int i = i0 + j;
        if (i < nb) { bbase[i] = run; run += loc[j]; }
    }
    if (t == 255) bbase[nb] = et;
}

__global__ __launch_bounds__(256) void scan_cnt(int* __restrict__ cnt, const int* __restrict__ bbase,
                                                int nb) {
    int b = blockIdx.x * 256 + threadIdx.x;
    if (b >= nb) return;
    int base = bbase[b];
    for (int blk = 0; blk < NBLK; ++blk) {
        int* p = &cnt[blk * NBQ + b];
        int t = *p; *p = base; base += t;
    }
}

// scatter packed entries: s (17 bits, N <= 131072) | (d&127) << 17 — 4B/edge
__global__ __launch_bounds__(256) void scatter_k(const int* __restrict__ src, const int* __restrict__ dst,
                                                 const int* __restrict__ cnt,
                                                 int* __restrict__ ebuf, int e, int et, int nb) {
    __shared__ int cur[NBQ];
    for (int i = threadIdx.x; i < nb; i += 256) cur[i] = cnt[blockIdx.x * NBQ + i];
    __syncthreads();
    int chunk = (et + NBLK - 1) / NBLK;
    int c0 = blockIdx.x * chunk;
    int c1 = c0 + chunk < et ? c0 + chunk : et;
    for (int i = c0 + (int)threadIdx.x; i < c1; i += 256) {
        int s, d;
        if (i < e) { s = src[i]; d = dst[i]; }
        else       { s = d = i - e; }            // self loop
        int pos = atomicAdd(&cur[d >> 7], 1);
        ebuf[pos] = s | ((d & 127) << 17);
    }
}

// fused: per-bucket degree count + scan -> offsets/dinv, then node-granular CSR
// placement with LDS cursors (ebuf segment stays L2-hot between the two passes)
__global__ __launch_bounds__(256) void finalize_k(const int* __restrict__ ebuf, const int* __restrict__ bbase,
                                                  int* __restrict__ offsets, float* __restrict__ dinv,
                                                  int* __restrict__ csr_s, int n, int et) {
    __shared__ int ldeg[128];
    __shared__ int lscan[128];
    __shared__ int cur[128];
    int b = blockIdx.x;
    int n0 = b << 7;
    if (threadIdx.x < 128) ldeg[threadIdx.x] = 0;
    __syncthreads();
    int e0 = bbase[b], e1 = bbase[b + 1];
    for (int i = e0 + (int)threadIdx.x; i < e1; i += 256)
        atomicAdd(&ldeg[(ebuf[i] >> 17) & 127], 1);
    __syncthreads();
    if (threadIdx.x < 128) lscan[threadIdx.x] = ldeg[threadIdx.x];
    __syncthreads();
    for (int off = 1; off < 128; off <<= 1) {
        int v = 0;
        if (threadIdx.x < 128 && (int)threadIdx.x >= off) v = lscan[threadIdx.x - off];
        __syncthreads();
        if (threadIdx.x < 128) lscan[threadIdx.x] += v;
        __syncthreads();
    }
    if (threadIdx.x < 128) {
        int base = e0 + lscan[threadIdx.x] - ldeg[threadIdx.x];   // exclusive
        cur[threadIdx.x] = base;
        int node = n0 + threadIdx.x;
        if (node < n) {
            offsets[node] = base;
            dinv[node] = rsqrtf((float)ldeg[threadIdx.x]);         // deg >= 1 (self loop)
        }
    }
    if (b == 0 && threadIdx.x == 0) offsets[n] = et;
    __syncthreads();
    for (int i = e0 + (int)threadIdx.x; i < e1; i += 256) {
        int ent = ebuf[i];
        int pos = atomicAdd(&cur[(ent >> 17) & 127], 1);
        csr_s[pos] = ent & 0x1FFFF;
    }
}

// ---------------- propagation (fp8 e4m3 table, 128B rows = 8 x uint4) ----------------
// out[d] = scale(d) * sum_{s in N(d)} x[s]; f32 accumulate (only storage is quantized).
// Lane-group-per-node: 8 lanes own one node's full row (16 feats/lane as f32 accs),
// iterate its edge list sequentially, 4-deep unrolled (32 gathers in flight / wave).
// No cross-lane reduce epilogue. 8 nodes/wave.
// out8f: 1 -> write fp8 table (next hop's gather), 0 -> write bf16 rows (MFMA GEMM input).

#define ACC16F(u) { floatx2 t0_ = UPK_FP8_LO((u).x), t1_ = UPK_FP8_HI((u).x); \
                    a[0] += t0_.x; a[1] += t0_.y; a[2] += t1_.x; a[3] += t1_.y; \
                    t0_ = UPK_FP8_LO((u).y); t1_ = UPK_FP8_HI((u).y); \
                    a[4] += t0_.x; a[5] += t0_.y; a[6] += t1_.x; a[7] += t1_.y; \
                    t0_ = UPK_FP8_LO((u).z); t1_ = UPK_FP8_HI((u).z); \
                    a[8] += t0_.x; a[9] += t0_.y; a[10] += t1_.x; a[11] += t1_.y; \
                    t0_ = UPK_FP8_LO((u).w); t1_ = UPK_FP8_HI((u).w); \
                    a[12] += t0_.x; a[13] += t0_.y; a[14] += t1_.x; a[15] += t1_.y; }

__global__ __launch_bounds__(256) void prop8_kernel(const uint4* __restrict__ xin, const int* __restrict__ offs,
                                                    const int* __restrict__ csr_s, const float* __restrict__ dinv,
                                                    int sq, int out8f, uint4* __restrict__ out8,
                                                    uint4* __restrict__ out16, int n) {
    int node = blockIdx.x * 32 + (threadIdx.x >> 3);
    if (node >= n) return;
    int li = threadIdx.x & 7;      // uint4 index within 8-uint4 (128B) fp8 row; feats li*16..+15
    int beg = offs[node], end = offs[node + 1];
    float a[16];
#pragma unroll
    for (int j = 0; j < 16; ++j) a[j] = 0.f;
    int e = beg;
    for (; e + 3 < end; e += 4) {
        int s0 = csr_s[e];
        int s1 = csr_s[e + 1];
        int s2 = csr_s[e + 2];
        int s3 = csr_s[e + 3];
        uint4 u0 = xin[(size_t)s0 * 8 + li];
        uint4 u1 = xin[(size_t)s1 * 8 + li];
        uint4 u2 = xin[(size_t)s2 * 8 + li];
        uint4 u3 = xin[(size_t)s3 * 8 + li];
        ACC16F(u0); ACC16F(u1); ACC16F(u2); ACC16F(u3);
    }
    for (; e + 1 < end; e += 2) {
        int s0 = csr_s[e];
        int s1 = csr_s[e + 1];
        uint4 u0 = xin[(size_t)s0 * 8 + li];
        uint4 u1 = xin[(size_t)s1 * 8 + li];
        ACC16F(u0); ACC16F(u1);
    }
    if (e < end) {
        int s = csr_s[e];
        uint4 u = xin[(size_t)s * 8 + li];
        ACC16F(u);
    }
    float f = dinv[node];
    if (sq) f *= f;
    if (out8f) {
        int w0 = PK_FP8_LO(a[0] * f, a[1] * f, 0);   w0 = PK_FP8_HI(a[2] * f, a[3] * f, w0);
        int w1 = PK_FP8_LO(a[4] * f, a[5] * f, 0);   w1 = PK_FP8_HI(a[6] * f, a[7] * f, w1);
        int w2 = PK_FP8_LO(a[8] * f, a[9] * f, 0);   w2 = PK_FP8_HI(a[10] * f, a[11] * f, w2);
        int w3 = PK_FP8_LO(a[12] * f, a[13] * f, 0); w3 = PK_FP8_HI(a[14] * f, a[15] * f, w3);
        uint4 o; o.x = (unsigned)w0; o.y = (unsigned)w1; o.z = (unsigned)w2; o.w = (unsigned)w3;
        out8[(size_t)node * 8 + li] = o;
    } else {
        uint4 o1, o2;
        o1.x = pack2bf(a[0] * f, a[1] * f);   o1.y = pack2bf(a[2] * f, a[3] * f);
        o1.z = pack2bf(a[4] * f, a[5] * f);   o1.w = pack2bf(a[6] * f, a[7] * f);
        o2.x = pack2bf(a[8] * f, a[9] * f);   o2.y = pack2bf(a[10] * f, a[11] * f);
        o2.z = pack2bf(a[12] * f, a[13] * f); o2.w = pack2bf(a[14] * f, a[15] * f);
        out16[(size_t)node * 16 + li * 2]     = o1;
        out16[(size_t)node * 16 + li * 2 + 1] = o2;
    }
}

// ---------------- MFMA GEMM: C[M,Nc] = act(A[M,K] @ Bfrag + bias) [* oscale] ----------------
// NT = 64-col tiles per block (compile-time). B is pre-swizzled fragment-major (wcast_frag):
// each lane's B operand is ONE coalesced ushort8 global load (L2-hot weights) -- no B LDS,
// no transpose bank conflicts. A tile double-buffered in LDS -> single barrier per k-step.
// Optional fused per-row att dots only in the NT==1 instantiation (Nc==64, gridDim.y==1).

template<int NT>
__global__ __launch_bounds__(256) void gemm_mfma(const unsigned short* __restrict__ A,
                                                 const unsigned short* __restrict__ Bf,
                                                 const float* __restrict__ bias, unsigned short* __restrict__ C,
                                                 const float* __restrict__ oscale,
                                                 const float* __restrict__ attS, const float* __restrict__ attD,
                                                 float* __restrict__ oas, float* __restrict__ oad,
                                                 int M, int K, int Nc, float slope, int act) {
    __shared__ __align__(16) unsigned short As[2][64 * 40];
    const int tid  = threadIdx.x;
    const int wave = tid >> 6;
    const int lane = tid & 63;
    const int q    = lane >> 4;
    const int r16  = lane & 15;
    const int m0 = blockIdx.x * 64;
    const int ksteps = K >> 5;

    floatx4 acc[NT][4];
#pragma unroll
    for (int nt = 0; nt < NT; ++nt)
#pragma unroll
        for (int ms = 0; ms < 4; ++ms) acc[nt][ms] = floatx4{0.f, 0.f, 0.f, 0.f};

    const int am = tid >> 2;         // 0..63 (tile row)
    const int ak = (tid & 3) * 8;    // 0..24
    const int gm = m0 + am;

    ushort8 sva;
    if (gm < M) sva = *(const ushort8*)(A + (size_t)gm * K + ak);
    else        for (int j = 0; j < 8; ++j) sva[j] = 0;

    const unsigned short* bbase = Bf + ((size_t)wave * 64 + lane) * 8;

    for (int kt = 0; kt < ksteps; ++kt) {
        unsigned short* as = As[kt & 1];
        *(ushort8*)(&as[am * 40 + ak]) = sva;
        __syncthreads();
        if (kt + 1 < ksteps) {
            if (gm < M) sva = *(const ushort8*)(A + (size_t)gm * K + (kt + 1) * 32 + ak);
        }
        short8 bf[NT];
#pragma unroll
        for (int nt = 0; nt < NT; ++nt) {
            int ntg = blockIdx.y * NT + nt;
            bf[nt] = *(const short8*)(bbase + (size_t)(ntg * ksteps + kt) * 2048);
        }
        short8 a0 = *(const short8*)(&as[(r16) * 40 + q * 8]);
        short8 a1 = *(const short8*)(&as[(16 + r16) * 40 + q * 8]);
        short8 a2 = *(const short8*)(&as[(32 + r16) * 40 + q * 8]);
        short8 a3 = *(const short8*)(&as[(48 + r16) * 40 + q * 8]);
#pragma unroll
        for (int nt = 0; nt < NT; ++nt) {
            acc[nt][0] = __builtin_amdgcn_mfma_f32_16x16x32_bf16(a0, bf[nt], acc[nt][0], 0, 0, 0);
            acc[nt][1] = __builtin_amdgcn_mfma_f32_16x16x32_bf16(a1, bf[nt], acc[nt][1], 0, 0, 0);
            acc[nt][2] = __builtin_amdgcn_mfma_f32_16x16x32_bf16(a2, bf[nt], acc[nt][2], 0, 0, 0);
            acc[nt][3] = __builtin_amdgcn_mfma_f32_16x16x32_bf16(a3, bf[nt], acc[nt][3], 0, 0, 0);
        }
        // no trailing barrier: next iteration writes the OTHER As buffer; its barrier
        // orders this iteration's reads before the overwrite two steps later.
    }
    // epilogue: C/D layout col=lane&15, row=(lane>>4)*4+reg
    if constexpr (NT == 1) {
        int cn = blockIdx.y * 64 + wave * 16 + r16;
        float bv = bias ? bias[cn] : 0.f;
        float ps[16], pd[16];
        float avs = attS ? attS[cn] : 0.f;
        float avd = attS ? attD[cn] : 0.f;
        for (int ms = 0; ms < 4; ++ms)
            for (int rr = 0; rr < 4; ++rr) {
                int cm = m0 + ms * 16 + q * 4 + rr;
                float v = acc[0][ms][rr] + bv;
                if (act) v = lrelu(v, slope);
                if (oscale && cm < M) v *= oscale[cm];
                if (cm < M) C[(size_t)cm * Nc + cn] = f2bf(v);
                ps[ms * 4 + rr] = v * avs;
                pd[ms * 4 + rr] = v * avd;
            }
        if (attS) {
            // reduce over the 16 cols held by this wave's q-group (lanes aligned 16)
            for (int off = 1; off < 16; off <<= 1)
#pragma unroll
                for (int i = 0; i < 16; ++i) {
                    ps[i] += __shfl_xor(ps[i], off, 64);
                    pd[i] += __shfl_xor(pd[i], off, 64);
                }
            __syncthreads();                      // all main-loop LDS reads done
            float* sd = (float*)As[0];
            if (tid < 128) sd[tid] = 0.f;
            __syncthreads();
            if (r16 == 0) {
#pragma unroll
                for (int i = 0; i < 16; ++i) {
                    int row = (i >> 2) * 16 + q * 4 + (i & 3);
                    atomicAdd(&sd[row], ps[i]);
                    atomicAdd(&sd[64 + row], pd[i]);
                }
            }
            __syncthreads();
            if (tid < 64 && m0 + tid < M) {
                oas[m0 + tid] = sd[tid];
                oad[m0 + tid] = sd[64 + tid];
            }
        }
    } else {
#pragma unroll
        for (int nt = 0; nt < NT; ++nt) {
            int cn = blockIdx.y * (NT * 64) + nt * 64 + wave * 16 + r16;
            float bv = bias ? bias[cn] : 0.f;
#pragma unroll
            for (int ms = 0; ms < 4; ++ms)
#pragma unroll
                for (int rr = 0; rr < 4; ++rr) {
                    int cm = m0 + ms * 16 + q * 4 + rr;
                    float v = acc[nt][ms][rr] + bv;
                    if (act) v = lrelu(v, slope);
                    if (oscale && cm < M) v *= oscale[cm];
                    if (cm < M) C[(size_t)cm * Nc + cn] = f2bf(v);
                }
        }
    }
}

// ---------------- GAT ----------------
// Lane-group-per-node: 8 lanes own one node's 64-feat bf16 row (8 feats/lane).
// Per edge: group-uniform csr/a_s loads (HW broadcast), redundant exp per lane,
// FMA into lane-local accs. No shuffles. 8 nodes/wave, 4-deep unrolled.
// No segment-max pass: e = lrelu(a_s+a_d) is O(1..10) << 88, exp(e) fp32-safe; shift cancels.
// NOTE: macro param must NOT be named 'w' -- it would capture the .w member access.

#define GACC(wt, u) { a0 = fmaf(wt, bflo((u).x), a0); a1 = fmaf(wt, bfhi((u).x), a1); \
                      a2 = fmaf(wt, bflo((u).y), a2); a3 = fmaf(wt, bfhi((u).y), a3); \
                      a4 = fmaf(wt, bflo((u).z), a4); a5 = fmaf(wt, bfhi((u).z), a5); \
                      a6 = fmaf(wt, bflo((u).w), a6); a7 = fmaf(wt, bfhi((u).w), a7); }

__global__ __launch_bounds__(256) void gat_agg(const uint4* __restrict__ hg, const float* __restrict__ a_s,
                                               const float* __restrict__ a_d, const int* __restrict__ offs,
                                               const int* __restrict__ csr_s, const float* __restrict__ bg,
                                               uint4* __restrict__ out, int n) {
    int node = blockIdx.x * 32 + (threadIdx.x >> 3);
    if (node >= n) return;
    int li = threadIdx.x & 7;      // uint4 index within 8-uint4 (128B) bf16 row
    int beg = offs[node], end = offs[node + 1];
    float ad = a_d[node];
    float a0=0.f,a1=0.f,a2=0.f,a3=0.f,a4=0.f,a5=0.f,a6=0.f,a7=0.f, ssum=0.f;
    int e = beg;
    for (; e + 3 < end; e += 4) {
        int s0 = csr_s[e];
        int s1 = csr_s[e + 1];
        int s2 = csr_s[e + 2];
        int s3 = csr_s[e + 3];
        float t0 = a_s[s0] + ad;
        float t1 = a_s[s1] + ad;
        float t2 = a_s[s2] + ad;
        float t3 = a_s[s3] + ad;
        uint4 u0 = hg[(size_t)s0 * 8 + li];
        uint4 u1 = hg[(size_t)s1 * 8 + li];
        uint4 u2 = hg[(size_t)s2 * 8 + li];
        uint4 u3 = hg[(size_t)s3 * 8 + li];
        t0 = t0 < 0.f ? 0.2f * t0 : t0;
        t1 = t1 < 0.f ? 0.2f * t1 : t1;
        t2 = t2 < 0.f ? 0.2f * t2 : t2;
        t3 = t3 < 0.f ? 0.2f * t3 : t3;
        float w0 = __expf(t0);
        float w1 = __expf(t1);
        float w2 = __expf(t2);
        float w3 = __expf(t3);
        ssum += (w0 + w1) + (w2 + w3);
        GACC(w0, u0); GACC(w1, u1); GACC(w2, u2); GACC(w3, u3);
    }
    for (; e < end; ++e) {
        int s0 = csr_s[e];
        float t0 = a_s[s0] + ad;
        uint4 u0 = hg[(size_t)s0 * 8 + li];
        t0 = t0 < 0.f ? 0.2f * t0 : t0;
        float w0 = __expf(t0);
        ssum += w0;
        GACC(w0, u0);
    }
    float inv = 1.0f / ssum;
    int f0 = li * 8;
    uint4 o;
    o.x = pack2bf(lrelu(a0 * inv + bg[f0 + 0], 0.1f), lrelu(a1 * inv + bg[f0 + 1], 0.1f));
    o.y = pack2bf(lrelu(a2 * inv + bg[f0 + 2], 0.1f), lrelu(a3 * inv + bg[f0 + 3], 0.1f));
    o.z = pack2bf(lrelu(a4 * inv + bg[f0 + 4], 0.1f), lrelu(a5 * inv + bg[f0 + 5], 0.1f));
    o.w = pack2bf(lrelu(a6 * inv + bg[f0 + 6], 0.1f), lrelu(a7 * inv + bg[f0 + 7], 0.1f));
    out[(size_t)node * 8 + li] = o;
}

// ---------------- final small GEMM [Ng,256]@[256,8] + bias -> fp32 ----------------

__global__ __launch_bounds__(256) void final_gemm(const unsigned short* __restrict__ m2, const float* __restrict__ W3,
                                                  const float* __restrict__ b3,
                                                  float* __restrict__ out, int ng) {
    int idx = blockIdx.x * 256 + threadIdx.x;
    if (idx >= ng * 8) return;
    int r = idx >> 3, c = idx & 7;
    float acc = b3[c];
    const unsigned short* row = m2 + (size_t)r * 256;
    for (int k = 0; k < 256; ++k) acc = fmaf(bf2f(row[k]), W3[k * 8 + c], acc);
    out[idx] = acc;
}

// ---------------- launch ----------------

extern "C" void kernel_launch(void* const* d_in, const int* in_sizes, int n_in,
                              void* d_out, int out_size, void* d_ws, size_t ws_size,
                              hipStream_t stream) {
    const int N  = in_sizes[0] / 128;
    const int E  = in_sizes[1] / 2;
    const int ET = E + N;
    const int Ng = N / 10;
    const int NB = (N + 127) / 128;   // dst buckets (<= NBQ)

    const float* x    = (const float*)d_in[0];
    const int*   src  = (const int*)d_in[1];
    const int*   dst  = src + E;
    const float* W1   = (const float*)d_in[2];
    const float* b1   = (const float*)d_in[3];
    const float* W2   = (const float*)d_in[4];
    const float* b2   = (const float*)d_in[5];
    const float* Wg   = (const float*)d_in[6];
    const float* atts = (const float*)d_in[7];
    const float* attd = (const float*)d_in[8];
    const float* bg   = (const float*)d_in[9];
    const float* Wl1  = (const float*)d_in[10];
    const float* bl1  = (const float*)d_in[11];
    const float* Wl2  = (const float*)d_in[12];
    const float* bl2  = (const float*)d_in[13];
    const float* Wl3  = (const float*)d_in[14];
    const float* bl3  = (const float*)d_in[15];
    float* out = (float*)d_out;

    // weight dims — in_sizes are ELEMENT counts (fp32 elems), NOT bytes
    const int K1 = 128,     N1 = in_sizes[2]  / K1;   // 128
    const int K2 = N1,      N2 = in_sizes[4]  / K2;   // 128
    const int K3 = N2,      N3 = in_sizes[6]  / K3;   // 64
    const int K4 = 10 * N3, N4 = in_sizes[10] / K4;   // 512
    const int K5 = N4,      N5 = in_sizes[12] / K5;   // 256
    // fragment-count prefix (8 elems / fragment) and elem offsets into wb
    const int F1 = K1 * N1 / 8,      F2 = F1 + K2 * N2 / 8, F3 = F2 + K3 * N3 / 8;
    const int F4 = F3 + K4 * N4 / 8, F5 = F4 + K5 * N5 / 8;
    const int E1 = K1 * N1, E2 = E1 + K2 * N2, E3 = E2 + K3 * N3, E4 = E3 + K4 * N4;
    const int ET5 = E4 + K5 * N5;   // total bf16 elems

    // workspace carve (all feature buffers bf16, 16B-aligned rows)
    char* p = (char*)d_ws;
    auto alloc = [&](size_t bytes) { char* r = p; p += (bytes + 255) & ~(size_t)255; return r; };
    unsigned short* xb = (unsigned short*)alloc((size_t)N * 128 * 2);
    unsigned short* A  = (unsigned short*)alloc((size_t)N * 128 * 2);
    unsigned short* Bb = (unsigned short*)alloc((size_t)N * 128 * 2);
    int*   csr_s   = (int*)  alloc((size_t)ET * 4);
    int*   cnt     = (int*)  alloc((size_t)NBLK * NBQ * 4);
    int*   btot    = (int*)  alloc((size_t)(NBQ + 1) * 4);
    int*   bbase   = (int*)  alloc((size_t)(NBQ + 1) * 4);
    float* dinv    = (float*)alloc((size_t)N * 4);
    int*   offsets = (int*)  alloc((size_t)(N + 1) * 4);
    float* a_s     = (float*)alloc((size_t)N * 4);
    float* a_d     = (float*)alloc((size_t)N * 4);
    unsigned short* wb = (unsigned short*)alloc((size_t)ET5 * 2);  // fragment-major bf16 weights
    // ebuf (packed src|dlow, ET*4 bytes) aliases Bb; lifetime ends before Bb's first write.
    int*   ebuf    = (int*)Bb;
    // fp8 tables (each N*128 bytes = half of xb); reused by conv1 then conv2
    unsigned* x8 = (unsigned*)xb;                       // quantized gather input table
    uint4*    a8 = (uint4*)(xb + (size_t)N * 64);       // hop-1 output, fp8

    const unsigned short* W1b  = wb;
    const unsigned short* W2b  = wb + E1;
    const unsigned short* Wgb  = wb + E2;
    const unsigned short* Wl1b = wb + E3;
    const unsigned short* Wl2b = wb + E4;

    const int pgp = (N + 31) / 32;    // lane-group kernels: 8 nodes/wave, 32/block

    hist_k    <<<NBLK, 256, 0, stream>>>(dst, cnt, E, ET, NB);
    btot_k    <<<(NB + 255) / 256, 256, 0, stream>>>(cnt, btot, NB);
    bscan_k   <<<1, 256, 0, stream>>>(btot, bbase, NB, ET);
    scan_cnt  <<<(NB + 255) / 256, 256, 0, stream>>>(cnt, bbase, NB);
    scatter_k <<<NBLK, 256, 0, stream>>>(src, dst, cnt, ebuf, E, ET, NB);
    finalize_k<<<NB, 256, 0, stream>>>(ebuf, bbase, offsets, dinv, csr_s, N, ET);
    wcast_frag<<<(F5 + 255) / 256, 256, 0, stream>>>(W1, W2, Wg, Wl1, Wl2, wb,
                                                     F1, F2, F3, F4, F5, E1, E2, E3, E4,
                                                     K1, K2, K3, K4, K5, N1, N2, N3, N4, N5);
    cast_scale8<<<(N * 32 + 255) / 256, 256, 0, stream>>>(x, dinv, x8, N * 32);

    // conv1 (fp8 gather tables): u = D^-1/2 x (quantized) ; a8 = D^-1 A u (fp8) ;
    // Bb = D^-1/2 A a8 = P^2 x (bf16) ; A = h1' = lrelu(Bb@W1+b1)*dinv
    prop8_kernel<<<pgp, 256, 0, stream>>>((const uint4*)x8, offsets, csr_s, dinv, 1, 1, a8, nullptr, N);
    prop8_kernel<<<pgp, 256, 0, stream>>>(a8, offsets, csr_s, dinv, 0, 0, nullptr, (uint4*)Bb, N);
    dim3 g1((N + 63) / 64, 1);
    gemm_mfma<2><<<g1, 256, 0, stream>>>(Bb, W1b, b1, A, dinv, nullptr, nullptr, nullptr, nullptr,
                                         N, 128, 128, 0.1f, 1);
    // conv2 (fp8 gather tables): quantize h1' then the same two-hop pipeline
    cast_bf2fp8<<<(N * 32 + 255) / 256, 256, 0, stream>>>((const uint2*)A, x8, N * 32);
    prop8_kernel<<<pgp, 256, 0, stream>>>((const uint4*)x8, offsets, csr_s, dinv, 1, 1, a8, nullptr, N);
    prop8_kernel<<<pgp, 256, 0, stream>>>(a8, offsets, csr_s, dinv, 0, 0, nullptr, (uint4*)A, N);
    gemm_mfma<2><<<g1, 256, 0, stream>>>(A, W2b, b2, Bb, nullptr, nullptr, nullptr, nullptr, nullptr,
                                         N, 128, 128, 0.1f, 1);
    // GAT: hg = h2 @ Wg with fused a_s/a_d row-dots, then attention aggregate
    dim3 g2((N + 63) / 64, 1);
    gemm_mfma<1><<<g2, 256, 0, stream>>>(Bb, Wgb, nullptr, A, nullptr, atts, attd, a_s, a_d,
                                         N, 128, 64, 0.f, 0);
    gat_agg <<<pgp, 256, 0, stream>>>((const uint4*)A, a_s, a_d, offsets, csr_s, bg, (uint4*)Bb, N);
    // MLP: Bb viewed as [Ng, 640] bf16
    dim3 g3((Ng + 63) / 64, 4);
    gemm_mfma<2><<<g3, 256, 0, stream>>>(Bb, Wl1b, bl1, A, nullptr, nullptr, nullptr, nullptr, nullptr,
                                         Ng, 640, 512, 0.1f, 1);
    dim3 g4((Ng + 63) / 64, 2);
    gemm_mfma<2><<<g4, 256, 0, stream>>>(A, Wl2b, bl2, Bb, nullptr, nullptr, nullptr, nullptr, nullptr,
                                         Ng, 512, 256, 0.1f, 1);
    final_gemm<<<(Ng * 8 + 255) / 256, 256, 0, stream>>>(Bb, Wl3, bl3, out, Ng);
}

// Round 10
// 459.581 us; speedup vs baseline: 1.4107x; 1.0296x over previous
//
#include <hip/hip_runtime.h>

typedef __attribute__((ext_vector_type(8))) short short8;
typedef __attribute__((ext_vector_type(8))) unsigned short ushort8;
typedef __attribute__((ext_vector_type(4))) float floatx4;
typedef __attribute__((ext_vector_type(2))) float floatx2;

#define NBQ  1024     // max buckets (N <= 131072 @ 128 nodes/bucket; packing needs N <= 2^17)
#define NBLK 128      // sort blocks

__device__ __forceinline__ float bf2f(unsigned short u) {
    union { unsigned u; float f; } v; v.u = ((unsigned)u) << 16; return v.f;
}
__device__ __forceinline__ float bflo(unsigned u) {
    union { unsigned u; float f; } v; v.u = u << 16; return v.f;
}
__device__ __forceinline__ float bfhi(unsigned u) {
    union { unsigned u; float f; } v; v.u = u & 0xFFFF0000u; return v.f;
}
__device__ __forceinline__ unsigned short f2bf(float f) {
    union { float f; unsigned u; } v; v.f = f;
    unsigned r = v.u + 0x7FFFu + ((v.u >> 16) & 1u);
    return (unsigned short)(r >> 16);
}
__device__ __forceinline__ unsigned pack2bf(float a, float b) {
    return (unsigned)f2bf(a) | ((unsigned)f2bf(b) << 16);
}
__device__ __forceinline__ float lrelu(float x, float s) { return x >= 0.f ? x : s * x; }

// fp8 e4m3 (OCP) hardware converts. The old/word builtin args must be INTEGER CONSTANT
// EXPRESSIONS -> macros with literals (an inline-function bool param fails to compile).
#define PK_FP8_LO(a, b, old) __builtin_amdgcn_cvt_pk_fp8_f32((a), (b), (old), false)
#define PK_FP8_HI(a, b, old) __builtin_amdgcn_cvt_pk_fp8_f32((a), (b), (old), true)
#define UPK_FP8_LO(u)        __builtin_amdgcn_cvt_pk_f32_fp8((int)(u), false)
#define UPK_FP8_HI(u)        __builtin_amdgcn_cvt_pk_f32_fp8((int)(u), true)

// fp32 -> fp8 e4m3 quads (4 feats / thread), pre-scaled by dinv[node] (128 feats = 32 uints/node)
__global__ __launch_bounds__(256) void cast_scale8(const float* __restrict__ in, const float* __restrict__ dinv,
                                                   unsigned* __restrict__ outp, int nquads) {
    int i = blockIdx.x * 256 + threadIdx.x;
    if (i < nquads) {
        float s = dinv[i >> 5];
        float4 v = *(const float4*)(in + 4 * (size_t)i);
        int w = PK_FP8_LO(v.x * s, v.y * s, 0);
        w = PK_FP8_HI(v.z * s, v.w * s, w);
        outp[i] = (unsigned)w;
    }
}

// fp32 weights -> bf16 in MFMA FRAGMENT ORDER. Fragment f of a K x Nc matrix holds
// o[j] = W[kt*32 + q*8 + j][ntile*64 + wave*16 + r16], f = ((ntile*(K/32)+kt)*4+wave)*64+lane.
// The GEMM then loads each lane's B fragment with ONE coalesced ushort8 global read
// (L2-resident weights) -- no LDS staging, no transpose bank conflicts.
__global__ __launch_bounds__(256) void wcast_frag(const float* __restrict__ w0, const float* __restrict__ w1,
                                                  const float* __restrict__ w2, const float* __restrict__ w3,
                                                  const float* __restrict__ w4, unsigned short* __restrict__ outp,
                                                  int f1, int f2, int f3, int f4, int f5,
                                                  int e1, int e2, int e3, int e4,
                                                  int k1, int k2, int k3, int k4, int k5,
                                                  int n1, int n2, int n3, int n4, int n5) {
    int i = blockIdx.x * 256 + threadIdx.x;
    if (i >= f5) return;
    const float* W; int fb, eb, K, Nc;
    if      (i < f1) { W = w0; fb = 0;  eb = 0;  K = k1; Nc = n1; }
    else if (i < f2) { W = w1; fb = f1; eb = e1; K = k2; Nc = n2; }
    else if (i < f3) { W = w2; fb = f2; eb = e2; K = k3; Nc = n3; }
    else if (i < f4) { W = w3; fb = f3; eb = e3; K = k4; Nc = n4; }
    else             { W = w4; fb = f4; eb = e4; K = k5; Nc = n5; }
    int f = i - fb;
    int lane = f & 63;
    int wave = (f >> 6) & 3;
    int rest = f >> 8;
    int ks = K >> 5;
    int kt = rest % ks;
    int ntile = rest / ks;
    int q = lane >> 4, r16 = lane & 15;
    int n = ntile * 64 + wave * 16 + r16;
    int kb = kt * 32 + q * 8;
    ushort8 o;
#pragma unroll
    for (int j = 0; j < 8; ++j) o[j] = f2bf(W[(size_t)(kb + j) * Nc + n]);
    *(ushort8*)(outp + (size_t)eb + (size_t)f * 8) = o;
}

// ---- CSR build: two-phase counting sort (bucket = 128 dst nodes), no global atomics ----
__global__ __launch_bounds__(256) void hist_k(const int* __restrict__ dst, int* __restrict__ cnt,
                                              int e, int et, int nb) {
    __shared__ int h[NBQ];
    for (int i = threadIdx.x; i < nb; i += 256) h[i] = 0;
    __syncthreads();
    int chunk = (et + NBLK - 1) / NBLK;
    int c0 = blockIdx.x * chunk;
    int c1 = c0 + chunk < et ? c0 + chunk : et;
    for (int i = c0 + (int)threadIdx.x; i < c1; i += 256) {
        int d = (i < e) ? dst[i] : (i - e);
        atomicAdd(&h[d >> 7], 1);
    }
    __syncthreads();
    for (int i = threadIdx.x; i < nb; i += 256) cnt[blockIdx.x * NBQ + i] = h[i];
}

__global__ __launch_bounds__(256) void btot_k(const int* __restrict__ cnt, int* __restrict__ btot, int nb) {
    int b = blockIdx.x * 256 + threadIdx.x;
    if (b >= nb) return;
    int s = 0;
    for (int blk = 0; blk < NBLK; ++blk) s += cnt[blk * NBQ + b];
    btot[b] = s;
}

__global__ __launch_bounds__(256) void bscan_k(const int* __restrict__ btot, int* __restrict__ bbase,
                                               int nb, int et) {
    __shared__ int sd[256];
    int t = threadIdx.x;
    int i0 = t * 4;
    int loc[4]; int s = 0;
    for (int j = 0; j < 4; ++j) { int i = i0 + j; loc[j] = (i < nb) ? btot[i] : 0; s += loc[j]; }
    sd[t] = s; __syncthreads();
    for (int off = 1; off < 256; off <<= 1) {
        int v = (t >= off) ? sd[t - off] : 0;
        __syncthreads();
        sd[t] += v;
        __syncthreads();
    }
    int run = sd[t] - s;
    for (int j = 0; j < 4; ++j) {
        int i = i0 + j;
        if (i < nb) { bbase[i] = run; run += loc[j]; }
    }
    if (t == 255) bbase[nb] = et;
}

__global__ __launch_bounds__(256) void scan_cnt(int* __restrict__ cnt, const int* __restrict__ bbase,
                                                int nb) {
    int b = blockIdx.x * 256 + threadIdx.x;
    if (b >= nb) return;
    int base = bbase[b];
    for (int blk = 0; blk < NBLK; ++blk) {
        int* p = &cnt[blk * NBQ + b];
        int t = *p; *p = base; base += t;
    }
}

// scatter packed entries: s (17 bits, N <= 131072) | (d&127) << 17 — 4B/edge
__global__ __launch_bounds__(256) void scatter_k(const int* __restrict__ src, const int* __restrict__ dst,
                                                 const int* __restrict__ cnt,
                                                 int* __restrict__ ebuf, int e, int et, int nb) {
    __shared__ int cur[NBQ];
    for (int i = threadIdx.x; i < nb; i += 256) cur[i] = cnt[blockIdx.x * NBQ + i];
    __syncthreads();
    int chunk = (et + NBLK - 1) / NBLK;
    int c0 = blockIdx.x * chunk;
    int c1 = c0 + chunk < et ? c0 + chunk : et;
    for (int i = c0 + (int)threadIdx.x; i < c1; i += 256) {
        int s, d;
        if (i < e) { s = src[i]; d = dst[i]; }
        else       { s = d = i - e; }            // self loop
        int pos = atomicAdd(&cur[d >> 7], 1);
        ebuf[pos] = s | ((d & 127) << 17);
    }
}

// fused: per-bucket degree count + scan -> offsets/dinv, then node-granular CSR
// placement with LDS cursors (ebuf segment stays L2-hot between the two passes)
__global__ __launch_bounds__(256) void finalize_k(const int* __restrict__ ebuf, const int* __restrict__ bbase,
                                                  int* __restrict__ offsets, float* __restrict__ dinv,
                                                  int* __restrict__ csr_s, int n, int et) {
    __shared__ int ldeg[128];
    __shared__ int lscan[128];
    __shared__ int cur[128];
    int b = blockIdx.x;
    int n0 = b << 7;
    if (threadIdx.x < 128) ldeg[threadIdx.x] = 0;
    __syncthreads();
    int e0 = bbase[b], e1 = bbase[b + 1];
    for (int i = e0 + (int)threadIdx.x; i < e1; i += 256)
        atomicAdd(&ldeg[(ebuf[i] >> 17) & 127], 1);
    __syncthreads();
    if (threadIdx.x < 128) lscan[threadIdx.x] = ldeg[threadIdx.x];
    __syncthreads();
    for (int off = 1; off < 128; off <<= 1) {
        int v = 0;
        if (threadIdx.x < 128 && (int)threadIdx.x >= off) v = lscan[threadIdx.x - off];
        __syncthreads();
        if (threadIdx.x < 128) lscan[threadIdx.x] += v;
        __syncthreads();
    }
    if (threadIdx.x < 128) {
        int base = e0 + lscan[threadIdx.x] - ldeg[threadIdx.x];   // exclusive
        cur[threadIdx.x] = base;
        int node = n0 + threadIdx.x;
        if (node < n) {
            offsets[node] = base;
            dinv[node] = rsqrtf((float)ldeg[threadIdx.x]);         // deg >= 1 (self loop)
        }
    }
    if (b == 0 && threadIdx.x == 0) offsets[n] = et;
    __syncthreads();
    for (int i = e0 + (int)threadIdx.x; i < e1; i += 256) {
        int ent = ebuf[i];
        int pos = atomicAdd(&cur[(ent >> 17) & 127], 1);
        csr_s[pos] = ent & 0x1FFFF;
    }
}

// ---------------- propagation (fp8 e4m3 table, 128B rows = 8 x uint4) ----------------
// out[d] = scale(d) * sum_{s in N(d)} x[s]; f32 accumulate (only storage is quantized).
// Lane-group-per-node: 8 lanes own one node's full row (16 feats/lane as f32 accs),
// iterate its edge list sequentially, 4-deep unrolled. No cross-lane reduce epilogue.
// 8 nodes/wave. Confirmed request-rate-floored (R1/R9 nulls): 8 lane-requests/edge
// is the minimum at 128B rows with 16B loads.
// out8f: 1 -> write fp8 table (next hop's gather), 0 -> write bf16 rows (MFMA GEMM input).

#define ACC16F(u) { floatx2 t0_ = UPK_FP8_LO((u).x), t1_ = UPK_FP8_HI((u).x); \
                    a[0] += t0_.x; a[1] += t0_.y; a[2] += t1_.x; a[3] += t1_.y; \
                    t0_ = UPK_FP8_LO((u).y); t1_ = UPK_FP8_HI((u).y); \
                    a[4] += t0_.x; a[5] += t0_.y; a[6] += t1_.x; a[7] += t1_.y; \
                    t0_ = UPK_FP8_LO((u).z); t1_ = UPK_FP8_HI((u).z); \
                    a[8] += t0_.x; a[9] += t0_.y; a[10] += t1_.x; a[11] += t1_.y; \
                    t0_ = UPK_FP8_LO((u).w); t1_ = UPK_FP8_HI((u).w); \
                    a[12] += t0_.x; a[13] += t0_.y; a[14] += t1_.x; a[15] += t1_.y; }

__global__ __launch_bounds__(256) void prop8_kernel(const uint4* __restrict__ xin, const int* __restrict__ offs,
                                                    const int* __restrict__ csr_s, const float* __restrict__ dinv,
                                                    int sq, int out8f, uint4* __restrict__ out8,
                                                    uint4* __restrict__ out16, int n) {
    int node = blockIdx.x * 32 + (threadIdx.x >> 3);
    if (node >= n) return;
    int li = threadIdx.x & 7;      // uint4 index within 8-uint4 (128B) fp8 row; feats li*16..+15
    int beg = offs[node], end = offs[node + 1];
    float a[16];
#pragma unroll
    for (int j = 0; j < 16; ++j) a[j] = 0.f;
    int e = beg;
    for (; e + 3 < end; e += 4) {
        int s0 = csr_s[e];
        int s1 = csr_s[e + 1];
        int s2 = csr_s[e + 2];
        int s3 = csr_s[e + 3];
        uint4 u0 = xin[(size_t)s0 * 8 + li];
        uint4 u1 = xin[(size_t)s1 * 8 + li];
        uint4 u2 = xin[(size_t)s2 * 8 + li];
        uint4 u3 = xin[(size_t)s3 * 8 + li];
        ACC16F(u0); ACC16F(u1); ACC16F(u2); ACC16F(u3);
    }
    for (; e + 1 < end; e += 2) {
        int s0 = csr_s[e];
        int s1 = csr_s[e + 1];
        uint4 u0 = xin[(size_t)s0 * 8 + li];
        uint4 u1 = xin[(size_t)s1 * 8 + li];
        ACC16F(u0); ACC16F(u1);
    }
    if (e < end) {
        int s = csr_s[e];
        uint4 u = xin[(size_t)s * 8 + li];
        ACC16F(u);
    }
    float f = dinv[node];
    if (sq) f *= f;
    if (out8f) {
        int w0 = PK_FP8_LO(a[0] * f, a[1] * f, 0);   w0 = PK_FP8_HI(a[2] * f, a[3] * f, w0);
        int w1 = PK_FP8_LO(a[4] * f, a[5] * f, 0);   w1 = PK_FP8_HI(a[6] * f, a[7] * f, w1);
        int w2 = PK_FP8_LO(a[8] * f, a[9] * f, 0);   w2 = PK_FP8_HI(a[10] * f, a[11] * f, w2);
        int w3 = PK_FP8_LO(a[12] * f, a[13] * f, 0); w3 = PK_FP8_HI(a[14] * f, a[15] * f, w3);
        uint4 o; o.x = (unsigned)w0; o.y = (unsigned)w1; o.z = (unsigned)w2; o.w = (unsigned)w3;
        out8[(size_t)node * 8 + li] = o;
    } else {
        uint4 o1, o2;
        o1.x = pack2bf(a[0] * f, a[1] * f);   o1.y = pack2bf(a[2] * f, a[3] * f);
        o1.z = pack2bf(a[4] * f, a[5] * f);   o1.w = pack2bf(a[6] * f, a[7] * f);
        o2.x = pack2bf(a[8] * f, a[9] * f);   o2.y = pack2bf(a[10] * f, a[11] * f);
        o2.z = pack2bf(a[12] * f, a[13] * f); o2.w = pack2bf(a[14] * f, a[15] * f);
        out16[(size_t)node * 16 + li * 2]     = o1;
        out16[(size_t)node * 16 + li * 2 + 1] = o2;
    }
}

// ---------------- MFMA GEMM: C[M,Nc] = act(A[M,K] @ Bfrag + bias) [* oscale] ----------------
// NT = 64-col tiles per block (compile-time). B is pre-swizzled fragment-major (wcast_frag):
// each lane's B operand is ONE coalesced ushort8 global load (L2-hot weights) -- no B LDS,
// no transpose bank conflicts. A tile double-buffered in LDS -> single barrier per k-step.
// C8 non-null (NT!=1 path): write the output as an fp8 e4m3 gather table directly
// (byte layout [M][Nc]) instead of bf16 C -- fuses the former cast_bf2fp8 kernel.
// Optional fused per-row att dots only in the NT==1 instantiation (Nc==64, gridDim.y==1).

template<int NT>
__global__ __launch_bounds__(256) void gemm_mfma(const unsigned short* __restrict__ A,
                                                 const unsigned short* __restrict__ Bf,
                                                 const float* __restrict__ bias, unsigned short* __restrict__ C,
                                                 unsigned char* __restrict__ C8,
                                                 const float* __restrict__ oscale,
                                                 const float* __restrict__ attS, const float* __restrict__ attD,
                                                 float* __restrict__ oas, float* __restrict__ oad,
                                                 int M, int K, int Nc, float slope, int act) {
    __shared__ __align__(16) unsigned short As[2][64 * 40];
    const int tid  = threadIdx.x;
    const int wave = tid >> 6;
    const int lane = tid & 63;
    const int q    = lane >> 4;
    const int r16  = lane & 15;
    const int m0 = blockIdx.x * 64;
    const int ksteps = K >> 5;

    floatx4 acc[NT][4];
#pragma unroll
    for (int nt = 0; nt < NT; ++nt)
#pragma unroll
        for (int ms = 0; ms < 4; ++ms) acc[nt][ms] = floatx4{0.f, 0.f, 0.f, 0.f};

    const int am = tid >> 2;         // 0..63 (tile row)
    const int ak = (tid & 3) * 8;    // 0..24
    const int gm = m0 + am;

    ushort8 sva;
    if (gm < M) sva = *(const ushort8*)(A + (size_t)gm * K + ak);
    else        for (int j = 0; j < 8; ++j) sva[j] = 0;

    const unsigned short* bbase = Bf + ((size_t)wave * 64 + lane) * 8;

    for (int kt = 0; kt < ksteps; ++kt) {
        unsigned short* as = As[kt & 1];
        *(ushort8*)(&as[am * 40 + ak]) = sva;
        __syncthreads();
        if (kt + 1 < ksteps) {
            if (gm < M) sva = *(const ushort8*)(A + (size_t)gm * K + (kt + 1) * 32 + ak);
        }
        short8 bf[NT];
#pragma unroll
        for (int nt = 0; nt < NT; ++nt) {
            int ntg = blockIdx.y * NT + nt;
            bf[nt] = *(const short8*)(bbase + (size_t)(ntg * ksteps + kt) * 2048);
        }
        short8 a0 = *(const short8*)(&as[(r16) * 40 + q * 8]);
        short8 a1 = *(const short8*)(&as[(16 + r16) * 40 + q * 8]);
        short8 a2 = *(const short8*)(&as[(32 + r16) * 40 + q * 8]);
        short8 a3 = *(const short8*)(&as[(48 + r16) * 40 + q * 8]);
#pragma unroll
        for (int nt = 0; nt < NT; ++nt) {
            acc[nt][0] = __builtin_amdgcn_mfma_f32_16x16x32_bf16(a0, bf[nt], acc[nt][0], 0, 0, 0);
            acc[nt][1] = __builtin_amdgcn_mfma_f32_16x16x32_bf16(a1, bf[nt], acc[nt][1], 0, 0, 0);
            acc[nt][2] = __builtin_amdgcn_mfma_f32_16x16x32_bf16(a2, bf[nt], acc[nt][2], 0, 0, 0);
            acc[nt][3] = __builtin_amdgcn_mfma_f32_16x16x32_bf16(a3, bf[nt], acc[nt][3], 0, 0, 0);
        }
        // no trailing barrier: next iteration writes the OTHER As buffer; its barrier
        // orders this iteration's reads before the overwrite two steps later.
    }
    // epilogue: C/D layout col=lane&15, row=(lane>>4)*4+reg
    if constexpr (NT == 1) {
        int cn = blockIdx.y * 64 + wave * 16 + r16;
        float bv = bias ? bias[cn] : 0.f;
        float ps[16], pd[16];
        float avs = attS ? attS[cn] : 0.f;
        float avd = attS ? attD[cn] : 0.f;
        for (int ms = 0; ms < 4; ++ms)
            for (int rr = 0; rr < 4; ++rr) {
                int cm = m0 + ms * 16 + q * 4 + rr;
                float v = acc[0][ms][rr] + bv;
                if (act) v = lrelu(v, slope);
                if (oscale && cm < M) v *= oscale[cm];
                if (cm < M) C[(size_t)cm * Nc + cn] = f2bf(v);
                ps[ms * 4 + rr] = v * avs;
                pd[ms * 4 + rr] = v * avd;
            }
        if (attS) {
            // reduce over the 16 cols held by this wave's q-group (lanes aligned 16)
            for (int off = 1; off < 16; off <<= 1)
#pragma unroll
                for (int i = 0; i < 16; ++i) {
                    ps[i] += __shfl_xor(ps[i], off, 64);
                    pd[i] += __shfl_xor(pd[i], off, 64);
                }
            __syncthreads();                      // all main-loop LDS reads done
            float* sd = (float*)As[0];
            if (tid < 128) sd[tid] = 0.f;
            __syncthreads();
            if (r16 == 0) {
#pragma unroll
                for (int i = 0; i < 16; ++i) {
                    int row = (i >> 2) * 16 + q * 4 + (i & 3);
                    atomicAdd(&sd[row], ps[i]);
                    atomicAdd(&sd[64 + row], pd[i]);
                }
            }
            __syncthreads();
            if (tid < 64 && m0 + tid < M) {
                oas[m0 + tid] = sd[tid];
                oad[m0 + tid] = sd[64 + tid];
            }
        }
    } else {
#pragma unroll
        for (int nt = 0; nt < NT; ++nt) {
            int cn = blockIdx.y * (NT * 64) + nt * 64 + wave * 16 + r16;
            float bv = bias ? bias[cn] : 0.f;
#pragma unroll
            for (int ms = 0; ms < 4; ++ms)
#pragma unroll
                for (int rr = 0; rr < 4; ++rr) {
                    int cm = m0 + ms * 16 + q * 4 + rr;
                    float v = acc[nt][ms][rr] + bv;
                    if (act) v = lrelu(v, slope);
                    if (oscale && cm < M) v *= oscale[cm];
                    if (cm < M) {
                        if (C8) C8[(size_t)cm * Nc + cn] = (unsigned char)(PK_FP8_LO(v, 0.f, 0) & 0xFF);
                        else    C[(size_t)cm * Nc + cn] = f2bf(v);
                    }
                }
        }
    }
}

// ---------------- GAT ----------------
// Lane-group-per-node: 8 lanes own one node's 64-feat bf16 row (8 feats/lane).
// Per edge: group-uniform csr/a_s loads (HW broadcast), redundant exp per lane,
// FMA into lane-local accs. No shuffles. 8 nodes/wave, 4-deep unrolled.
// No segment-max pass: e = lrelu(a_s+a_d) is O(1..10) << 88, exp(e) fp32-safe; shift cancels.
// NOTE: macro param must NOT be named 'w' -- it would capture the .w member access.

#define GACC(wt, u) { a0 = fmaf(wt, bflo((u).x), a0); a1 = fmaf(wt, bfhi((u).x), a1); \
                      a2 = fmaf(wt, bflo((u).y), a2); a3 = fmaf(wt, bfhi((u).y), a3); \
                      a4 = fmaf(wt, bflo((u).z), a4); a5 = fmaf(wt, bfhi((u).z), a5); \
                      a6 = fmaf(wt, bflo((u).w), a6); a7 = fmaf(wt, bfhi((u).w), a7); }

__global__ __launch_bounds__(256) void gat_agg(const uint4* __restrict__ hg, const float* __restrict__ a_s,
                                               const float* __restrict__ a_d, const int* __restrict__ offs,
                                               const int* __restrict__ csr_s, const float* __restrict__ bg,
                                               uint4* __restrict__ out, int n) {
    int node = blockIdx.x * 32 + (threadIdx.x >> 3);
    if (node >= n) return;
    int li = threadIdx.x & 7;      // uint4 index within 8-uint4 (128B) bf16 row
    int beg = offs[node], end = offs[node + 1];
    float ad = a_d[node];
    float a0=0.f,a1=0.f,a2=0.f,a3=0.f,a4=0.f,a5=0.f,a6=0.f,a7=0.f, ssum=0.f;
    int e = beg;
    for (; e + 3 < end; e += 4) {
        int s0 = csr_s[e];
        int s1 = csr_s[e + 1];
        int s2 = csr_s[e + 2];
        int s3 = csr_s[e + 3];
        float t0 = a_s[s0] + ad;
        float t1 = a_s[s1] + ad;
        float t2 = a_s[s2] + ad;
        float t3 = a_s[s3] + ad;
        uint4 u0 = hg[(size_t)s0 * 8 + li];
        uint4 u1 = hg[(size_t)s1 * 8 + li];
        uint4 u2 = hg[(size_t)s2 * 8 + li];
        uint4 u3 = hg[(size_t)s3 * 8 + li];
        t0 = t0 < 0.f ? 0.2f * t0 : t0;
        t1 = t1 < 0.f ? 0.2f * t1 : t1;
        t2 = t2 < 0.f ? 0.2f * t2 : t2;
        t3 = t3 < 0.f ? 0.2f * t3 : t3;
        float w0 = __expf(t0);
        float w1 = __expf(t1);
        float w2 = __expf(t2);
        float w3 = __expf(t3);
        ssum += (w0 + w1) + (w2 + w3);
        GACC(w0, u0); GACC(w1, u1); GACC(w2, u2); GACC(w3, u3);
    }
    for (; e < end; ++e) {
        int s0 = csr_s[e];
        float t0 = a_s[s0] + ad;
        uint4 u0 = hg[(size_t)s0 * 8 + li];
        t0 = t0 < 0.f ? 0.2f * t0 : t0;
        float w0 = __expf(t0);
        ssum += w0;
        GACC(w0, u0);
    }
    float inv = 1.0f / ssum;
    int f0 = li * 8;
    uint4 o;
    o.x = pack2bf(lrelu(a0 * inv + bg[f0 + 0], 0.1f), lrelu(a1 * inv + bg[f0 + 1], 0.1f));
    o.y = pack2bf(lrelu(a2 * inv + bg[f0 + 2], 0.1f), lrelu(a3 * inv + bg[f0 + 3], 0.1f));
    o.z = pack2bf(lrelu(a4 * inv + bg[f0 + 4], 0.1f), lrelu(a5 * inv + bg[f0 + 5], 0.1f));
    o.w = pack2bf(lrelu(a6 * inv + bg[f0 + 6], 0.1f), lrelu(a7 * inv + bg[f0 + 7], 0.1f));
    out[(size_t)node * 8 + li] = o;
}

// ---------------- final small GEMM [Ng,256]@[256,8] + bias -> fp32 ----------------
// W3 staged to LDS once per block (8KB; lanes read consecutive c -> conflict-free).
// Row read as 32 x uint4 (16B) instead of 256 scalar bf16 loads; 8 lanes share a row
// (same addresses -> broadcast). Lane c owns output col c, no reduction needed.

__global__ __launch_bounds__(256) void final_gemm(const unsigned short* __restrict__ m2, const float* __restrict__ W3,
                                                  const float* __restrict__ b3,
                                                  float* __restrict__ out, int ng) {
    __shared__ float w3s[2048];
    for (int i = threadIdx.x; i < 2048; i += 256) w3s[i] = W3[i];
    __syncthreads();
    int gid = blockIdx.x * 256 + threadIdx.x;
    int r = gid >> 3, c = gid & 7;
    if (r >= ng) return;
    const uint4* row = (const uint4*)(m2 + (size_t)r * 256);
    float acc = b3[c];
#pragma unroll 4
    for (int j = 0; j < 32; ++j) {
        uint4 u = row[j];
        int k = j * 8;
        acc += bflo(u.x) * w3s[(k + 0) * 8 + c] + bfhi(u.x) * w3s[(k + 1) * 8 + c]
             + bflo(u.y) * w3s[(k + 2) * 8 + c] + bfhi(u.y) * w3s[(k + 3) * 8 + c]
             + bflo(u.z) * w3s[(k + 4) * 8 + c] + bfhi(u.z) * w3s[(k + 5) * 8 + c]
             + bflo(u.w) * w3s[(k + 6) * 8 + c] + bfhi(u.w) * w3s[(k + 7) * 8 + c];
    }
    out[r * 8 + c] = acc;
}

// ---------------- launch ----------------

extern "C" void kernel_launch(void* const* d_in, const int* in_sizes, int n_in,
                              void* d_out, int out_size, void* d_ws, size_t ws_size,
                              hipStream_t stream) {
    const int N  = in_sizes[0] / 128;
    const int E  = in_sizes[1] / 2;
    const int ET = E + N;
    const int Ng = N / 10;
    const int NB = (N + 127) / 128;   // dst buckets (<= NBQ)

    const float* x    = (const float*)d_in[0];
    const int*   src  = (const int*)d_in[1];
    const int*   dst  = src + E;
    const float* W1   = (const float*)d_in[2];
    const float* b1   = (const float*)d_in[3];
    const float* W2   = (const float*)d_in[4];
    const float* b2   = (const float*)d_in[5];
    const float* Wg   = (const float*)d_in[6];
    const float* atts = (const float*)d_in[7];
    const float* attd = (const float*)d_in[8];
    const float* bg   = (const float*)d_in[9];
    const float* Wl1  = (const float*)d_in[10];
    const float* bl1  = (const float*)d_in[11];
    const float* Wl2  = (const float*)d_in[12];
    const float* bl2  = (const float*)d_in[13];
    const float* Wl3  = (const float*)d_in[14];
    const float* bl3  = (const float*)d_in[15];
    float* out = (float*)d_out;

    // weight dims — in_sizes are ELEMENT counts (fp32 elems), NOT bytes
    const int K1 = 128,     N1 = in_sizes[2]  / K1;   // 128
    const int K2 = N1,      N2 = in_sizes[4]  / K2;   // 128
    const int K3 = N2,      N3 = in_sizes[6]  / K3;   // 64
    const int K4 = 10 * N3, N4 = in_sizes[10] / K4;   // 512
    const int K5 = N4,      N5 = in_sizes[12] / K5;   // 256
    // fragment-count prefix (8 elems / fragment) and elem offsets into wb
    const int F1 = K1 * N1 / 8,      F2 = F1 + K2 * N2 / 8, F3 = F2 + K3 * N3 / 8;
    const int F4 = F3 + K4 * N4 / 8, F5 = F4 + K5 * N5 / 8;
    const int E1 = K1 * N1, E2 = E1 + K2 * N2, E3 = E2 + K3 * N3, E4 = E3 + K4 * N4;
    const int ET5 = E4 + K5 * N5;   // total bf16 elems

    // workspace carve (all feature buffers bf16, 16B-aligned rows)
    char* p = (char*)d_ws;
    auto alloc = [&](size_t bytes) { char* r = p; p += (bytes + 255) & ~(size_t)255; return r; };
    unsigned short* xb = (unsigned short*)alloc((size_t)N * 128 * 2);
    unsigned short* A  = (unsigned short*)alloc((size_t)N * 128 * 2);
    unsigned short* Bb = (unsigned short*)alloc((size_t)N * 128 * 2);
    int*   csr_s   = (int*)  alloc((size_t)ET * 4);
    int*   cnt     = (int*)  alloc((size_t)NBLK * NBQ * 4);
    int*   btot    = (int*)  alloc((size_t)(NBQ + 1) * 4);
    int*   bbase   = (int*)  alloc((size_t)(NBQ + 1) * 4);
    float* dinv    = (float*)alloc((size_t)N * 4);
    int*   offsets = (int*)  alloc((size_t)(N + 1) * 4);
    float* a_s     = (float*)alloc((size_t)N * 4);
    float* a_d     = (float*)alloc((size_t)N * 4);
    unsigned short* wb = (unsigned short*)alloc((size_t)ET5 * 2);  // fragment-major bf16 weights
    // ebuf (packed src|dlow, ET*4 bytes) aliases Bb; lifetime ends before Bb's first write.
    int*   ebuf    = (int*)Bb;
    // fp8 tables (each N*128 bytes = half of xb); reused by conv1 then conv2
    unsigned* x8 = (unsigned*)xb;                       // quantized gather input table
    uint4*    a8 = (uint4*)(xb + (size_t)N * 64);       // hop-1 output, fp8

    const unsigned short* W1b  = wb;
    const unsigned short* W2b  = wb + E1;
    const unsigned short* Wgb  = wb + E2;
    const unsigned short* Wl1b = wb + E3;
    const unsigned short* Wl2b = wb + E4;

    const int pgp = (N + 31) / 32;    // lane-group kernels: 8 nodes/wave, 32/block

    hist_k    <<<NBLK, 256, 0, stream>>>(dst, cnt, E, ET, NB);
    btot_k    <<<(NB + 255) / 256, 256, 0, stream>>>(cnt, btot, NB);
    bscan_k   <<<1, 256, 0, stream>>>(btot, bbase, NB, ET);
    scan_cnt  <<<(NB + 255) / 256, 256, 0, stream>>>(cnt, bbase, NB);
    scatter_k <<<NBLK, 256, 0, stream>>>(src, dst, cnt, ebuf, E, ET, NB);
    finalize_k<<<NB, 256, 0, stream>>>(ebuf, bbase, offsets, dinv, csr_s, N, ET);
    wcast_frag<<<(F5 + 255) / 256, 256, 0, stream>>>(W1, W2, Wg, Wl1, Wl2, wb,
                                                     F1, F2, F3, F4, F5, E1, E2, E3, E4,
                                                     K1, K2, K3, K4, K5, N1, N2, N3, N4, N5);
    cast_scale8<<<(N * 32 + 255) / 256, 256, 0, stream>>>(x, dinv, x8, N * 32);

    // conv1 (fp8 gather tables): u = D^-1/2 x (quantized) ; a8 = D^-1 A u (fp8) ;
    // Bb = D^-1/2 A a8 = P^2 x (bf16) ; gemm1 writes h1' = lrelu(Bb@W1+b1)*dinv
    // DIRECTLY as the fp8 table x8 (fused cast_bf2fp8).
    prop8_kernel<<<pgp, 256, 0, stream>>>((const uint4*)x8, offsets, csr_s, dinv, 1, 1, a8, nullptr, N);
    prop8_kernel<<<pgp, 256, 0, stream>>>(a8, offsets, csr_s, dinv, 0, 0, nullptr, (uint4*)Bb, N);
    dim3 g1((N + 63) / 64, 1);
    gemm_mfma<2><<<g1, 256, 0, stream>>>(Bb, W1b, b1, nullptr, (unsigned char*)x8, dinv,
                                         nullptr, nullptr, nullptr, nullptr,
                                         N, 128, 128, 0.1f, 1);
    // conv2 (fp8 gather tables): same two-hop pipeline on the quantized h1'
    prop8_kernel<<<pgp, 256, 0, stream>>>((const uint4*)x8, offsets, csr_s, dinv, 1, 1, a8, nullptr, N);
    prop8_kernel<<<pgp, 256, 0, stream>>>(a8, offsets, csr_s, dinv, 0, 0, nullptr, (uint4*)A, N);
    gemm_mfma<2><<<g1, 256, 0, stream>>>(A, W2b, b2, Bb, nullptr, nullptr,
                                         nullptr, nullptr, nullptr, nullptr,
                                         N, 128, 128, 0.1f, 1);
    // GAT: hg = h2 @ Wg with fused a_s/a_d row-dots, then attention aggregate
    dim3 g2((N + 63) / 64, 1);
    gemm_mfma<1><<<g2, 256, 0, stream>>>(Bb, Wgb, nullptr, A, nullptr, nullptr,
                                         atts, attd, a_s, a_d,
                                         N, 128, 64, 0.f, 0);
    gat_agg <<<pgp, 256, 0, stream>>>((const uint4*)A, a_s, a_d, offsets, csr_s, bg, (uint4*)Bb, N);
    // MLP: Bb viewed as [Ng, 640] bf16
    dim3 g3((Ng + 63) / 64, 4);
    gemm_mfma<2><<<g3, 256, 0, stream>>>(Bb, Wl1b, bl1, A, nullptr, nullptr,
                                         nullptr, nullptr, nullptr, nullptr,
                                         Ng, 640, 512, 0.1f, 1);
    dim3 g4((Ng + 63) / 64, 2);
    gemm_mfma<2><<<g4, 256, 0, stream>>>(A, Wl2b, bl2, Bb, nullptr, nullptr,
                                         nullptr, nullptr, nullptr, nullptr,
                                         Ng, 512, 256, 0.1f, 1);
    final_gemm<<<(Ng * 8 + 255) / 256, 256, 0, stream>>>(Bb, Wl3, bl3, out, Ng);
}